// Round 11
// baseline (26286.612 us; speedup 1.0000x reference)
//
#include <hip/hip_runtime.h>
#pragma clang fp contract(off)

#define Bn 8
#define Tn 176
#define Rn 116
#define Cn 64
#define Hn 200
#define NPAIRn 6670
#define MAXGn 176
#define TAUf 1e-4f
#define LD 176
#define LEAF 22
#define FEPS 5.9604645e-08f
#define FEPS2 3.5527137e-15f
#define FSAFMIN 1.17549435e-38f

// ---------------- f32 LAPACK helpers ----------------
static __device__ __forceinline__ float f_sign(float a, float b) {
  return (b >= 0.0f) ? fabsf(a) : -fabsf(a);
}
static __device__ __forceinline__ float f_lapy2(float x, float y) {
  float xa = fabsf(x), ya = fabsf(y);
  float w = fmaxf(xa, ya), z = fminf(xa, ya);
  if (z == 0.0f) return w;
  float q = z / w;
  return w * sqrtf(1.0f + q * q);
}
static __device__ void f_lartg(float f, float g, float* c, float* s, float* r) {
  if (g == 0.0f) { *c = 1.0f; *s = 0.0f; *r = f; }
  else if (f == 0.0f) { *c = 0.0f; *s = (g >= 0.0f) ? 1.0f : -1.0f; *r = fabsf(g); }
  else {
    float d = sqrtf(f * f + g * g);
    float rr = (f >= 0.0f) ? d : -d;
    *c = f / rr; *s = g / rr; *r = rr;
  }
}
static __device__ float f_snrm2_strided(const float* x, int n, int stride) {
  float scale = 0.0f, ssq = 1.0f;
  for (int i = 0; i < n; i++) {
    float ax = fabsf(x[i * stride]);
    if (ax != 0.0f) {
      if (scale < ax) {
        float q = scale / ax;
        ssq = 1.0f + ssq * (q * q);
        scale = ax;
      } else {
        float q = ax / scale;
        ssq = ssq + q * q;
      }
    }
  }
  return scale * sqrtf(ssq);
}
static __device__ void f_laev2(float a, float b, float c,
                               float* rt1, float* rt2, float* cs1, float* sn1) {
  float sm = a + c, df = a - c, adf = fabsf(df), tb = b + b, ab = fabsf(tb);
  float acmx, acmn;
  if (fabsf(a) > fabsf(c)) { acmx = a; acmn = c; } else { acmx = c; acmn = a; }
  float rt;
  if (adf > ab) { float q = ab / adf; rt = adf * sqrtf(1.0f + q * q); }
  else if (adf < ab) { float q = adf / ab; rt = ab * sqrtf(1.0f + q * q); }
  else rt = ab * sqrtf(2.0f);
  int sgn1;
  if (sm < 0.0f) { *rt1 = 0.5f * (sm - rt); sgn1 = -1; *rt2 = (acmx / *rt1) * acmn - (b / *rt1) * b; }
  else if (sm > 0.0f) { *rt1 = 0.5f * (sm + rt); sgn1 = 1; *rt2 = (acmx / *rt1) * acmn - (b / *rt1) * b; }
  else { *rt1 = 0.5f * rt; *rt2 = -0.5f * rt; sgn1 = 1; }
  float cs; int sgn2;
  if (df >= 0.0f) { cs = df + rt; sgn2 = 1; } else { cs = df - rt; sgn2 = -1; }
  float acs = fabsf(cs);
  if (acs > ab) { float ct = -tb / cs; *sn1 = 1.0f / sqrtf(1.0f + ct * ct); *cs1 = ct * (*sn1); }
  else {
    if (ab == 0.0f) { *cs1 = 1.0f; *sn1 = 0.0f; }
    else { float tn = -cs / tb; *cs1 = 1.0f / sqrtf(1.0f + tn * tn); *sn1 = tn * (*cs1); }
  }
  if (sgn1 == sgn2) { float tn = *cs1; *cs1 = -(*sn1); *sn1 = tn; }
}
static __device__ void f_lamrg(int n1, int n2, const float* a, int dtrd1, int dtrd2, int* index) {
  int n1sv = n1, n2sv = n2;
  int ind1 = (dtrd1 > 0) ? 0 : n1 - 1;
  int ind2 = (dtrd2 > 0) ? n1 : n1 + n2 - 1;
  int i = 0;
  while (n1sv > 0 && n2sv > 0) {
    if (a[ind1] <= a[ind2]) { index[i++] = ind1; ind1 += dtrd1; n1sv--; }
    else { index[i++] = ind2; ind2 += dtrd2; n2sv--; }
  }
  while (n2sv > 0) { index[i++] = ind2; ind2 += dtrd2; n2sv--; }
  while (n1sv > 0) { index[i++] = ind1; ind1 += dtrd1; n1sv--; }
}
static __device__ void f_laed5(int i, const float* d, const float* z, float rho,
                               float* dlam, float* u0, float* u1) {
  float del = d[1] - d[0];
  float del1, del2;
  if (i == 0) {
    float w = 1.0f + 2.0f * rho * (z[1] * z[1] - z[0] * z[0]) / del;
    if (w > 0.0f) {
      float b = del + rho * (z[0] * z[0] + z[1] * z[1]);
      float c = rho * z[0] * z[0] * del;
      float tau = 2.0f * c / (b + sqrtf(fabsf(b * b - 4.0f * c)));
      *dlam = d[0] + tau;
      del1 = -z[0] / tau; del2 = z[1] / (del - tau);
    } else {
      float b = -del + rho * (z[0] * z[0] + z[1] * z[1]);
      float c = rho * z[1] * z[1] * del;
      float tau;
      if (b > 0.0f) tau = -2.0f * c / (b + sqrtf(b * b + 4.0f * c));
      else tau = (b - sqrtf(b * b + 4.0f * c)) / 2.0f;
      *dlam = d[1] + tau;
      del1 = -z[0] / (del + tau); del2 = -z[1] / tau;
    }
  } else {
    float b = -del + rho * (z[0] * z[0] + z[1] * z[1]);
    float c = rho * z[1] * z[1] * del;
    float tau;
    if (b > 0.0f) tau = (b + sqrtf(b * b + 4.0f * c)) / 2.0f;
    else tau = 2.0f * c / (-b + sqrtf(b * b + 4.0f * c));
    *dlam = d[1] + tau;
    del1 = -z[0] / (del + tau); del2 = -z[1] / tau;
  }
  float t = sqrtf(del1 * del1 + del2 * del2);
  *u0 = del1 / t; *u1 = del2 / t;
}

// ---------------- netlib slaed6 (f32) ----------------
static __device__ void laed6_net(int kniter, bool orgati, float rho, const float* dd,
                                 const float* zz, float finit, float* tau_out) {
  const float eps = FEPS;
  float lbd, ubd;
  if (orgati) { lbd = dd[1]; ubd = dd[2]; }
  else { lbd = dd[0]; ubd = dd[1]; }
  if (finit < 0.0f) lbd = 0.0f; else ubd = 0.0f;
  float tau = 0.0f;
  if (kniter == 2) {
    float temp, a, b, c;
    if (orgati) {
      temp = (dd[2] + dd[1]) / 2.0f;
      c = rho + zz[0] / ((dd[0] - dd[1]) - temp);
      a = c * (dd[1] + dd[2]) + zz[1] + zz[2];
      b = c * dd[1] * dd[2] + zz[1] * dd[2] + zz[2] * dd[1];
    } else {
      temp = (dd[0] + dd[1]) / 2.0f;
      c = rho + zz[2] / ((dd[2] - dd[1]) - temp);
      a = c * (dd[0] + dd[1]) + zz[0] + zz[1];
      b = c * dd[0] * dd[1] + zz[0] * dd[1] + zz[1] * dd[0];
    }
    temp = fmaxf(fmaxf(fabsf(a), fabsf(b)), fabsf(c));
    a /= temp; b /= temp; c /= temp;
    if (c == 0.0f) tau = b / a;
    else if (a <= 0.0f) tau = (a - sqrtf(fabsf(a * a - 4.0f * b * c))) / (2.0f * c);
    else tau = 2.0f * b / (a + sqrtf(fabsf(a * a - 4.0f * b * c)));
    if (tau < lbd || tau > ubd) tau = (lbd + ubd) / 2.0f;
    if (dd[0] == tau || dd[1] == tau || dd[2] == tau) {
      tau = 0.0f;
    } else {
      temp = finit + tau * zz[0] / (dd[0] * (dd[0] - tau))
                   + tau * zz[1] / (dd[1] * (dd[1] - tau))
                   + tau * zz[2] / (dd[2] * (dd[2] - tau));
      if (temp <= 0.0f) lbd = tau; else ubd = tau;
      if (fabsf(finit) <= fabsf(temp)) tau = 0.0f;
    }
  }
  const float small1 = 2.2737367544323206e-13f;
  const float sminv1 = 4398046511104.0f;
  const float small2 = small1 * small1;
  const float sminv2 = sminv1 * sminv1;
  float temp;
  if (orgati) temp = fminf(fabsf(dd[1] - tau), fabsf(dd[2] - tau));
  else temp = fminf(fabsf(dd[0] - tau), fabsf(dd[1] - tau));
  bool doscale = false;
  float sclfac = 1.0f, sclinv = 1.0f;
  float dscale[3], zscale[3];
  if (temp <= small1) {
    doscale = true;
    if (temp <= small2) { sclfac = sminv2; sclinv = small2; }
    else { sclfac = sminv1; sclinv = small1; }
    for (int i = 0; i < 3; i++) { dscale[i] = dd[i] * sclfac; zscale[i] = zz[i] * sclfac; }
    tau *= sclfac; lbd *= sclfac; ubd *= sclfac;
  } else {
    for (int i = 0; i < 3; i++) { dscale[i] = dd[i]; zscale[i] = zz[i]; }
  }
  float fc = 0.0f, df = 0.0f, ddf = 0.0f;
  for (int i = 0; i < 3; i++) {
    float t1 = 1.0f / (dscale[i] - tau);
    float t2 = zscale[i] * t1;
    float t3 = t2 * t1;
    float t4 = t3 * t1;
    fc += t2 / dscale[i];
    df += t3;
    ddf += t4;
  }
  float f = finit + tau * fc;
  if (fabsf(f) > 0.0f) {
    if (f <= 0.0f) lbd = tau; else ubd = tau;
    for (int niter = 2; niter <= 40; ++niter) {
      float t1_, t2_;
      if (orgati) { t1_ = dscale[1] - tau; t2_ = dscale[2] - tau; }
      else { t1_ = dscale[0] - tau; t2_ = dscale[1] - tau; }
      float a = (t1_ + t2_) * f - t1_ * t2_ * df;
      float b = t1_ * t2_ * f;
      float c = f - (t1_ + t2_) * df + t1_ * t2_ * ddf;
      float tm = fmaxf(fmaxf(fabsf(a), fabsf(b)), fabsf(c));
      a /= tm; b /= tm; c /= tm;
      float eta;
      if (c == 0.0f) eta = b / a;
      else if (a <= 0.0f) eta = (a - sqrtf(fabsf(a * a - 4.0f * b * c))) / (2.0f * c);
      else eta = 2.0f * b / (a + sqrtf(fabsf(a * a - 4.0f * b * c)));
      if (f * eta >= 0.0f) eta = -f / df;
      tau = tau + eta;
      if (tau < lbd || tau > ubd) tau = (lbd + ubd) / 2.0f;
      fc = 0.0f; df = 0.0f; ddf = 0.0f;
      float erretm = 0.0f;
      bool hitpole = false;
      for (int i = 0; i < 3; i++) {
        float dt = dscale[i] - tau;
        if (dt != 0.0f) {
          float t1 = 1.0f / dt;
          float t2 = zscale[i] * t1;
          float t3 = t2 * t1;
          float t4 = t3 * t1;
          float t5 = t2 / dscale[i];
          fc += t5;
          erretm += fabsf(t5);
          df += t3;
          ddf += t4;
        } else { hitpole = true; break; }
      }
      if (hitpole) break;
      f = finit + tau * fc;
      erretm = 8.0f * (fabsf(finit) + fabsf(tau) * erretm) + fabsf(tau) * df;
      if (fabsf(f) <= eps * erretm) break;
      if (f <= 0.0f) lbd = tau; else ubd = tau;
    }
  }
  if (doscale) tau *= sclinv;
  *tau_out = tau;
}

// ---------------- netlib slaed4 (f32); delta strided by LD ----------------
static __device__ void laed4_net(int K, int j0, const float* d, const float* z, float rho,
                                 float* dlam, float* delta) {
#define DL(i) delta[(size_t)(i) * LD]
  const float eps = FEPS;
  float rhoinv = 1.0f / rho;
  if (j0 == K - 1) {
    int ii = K - 2;
    float midpt = rho / 2.0f;
    for (int j = 0; j < K; j++) DL(j) = (d[j] - d[K - 1]) - midpt;
    float psi = 0.0f;
    for (int j = 0; j < K - 2; j++) psi += z[j] * z[j] / DL(j);
    float c = rhoinv + psi;
    float w = c + z[ii] * z[ii] / DL(ii) + z[K - 1] * z[K - 1] / DL(K - 1);
    float dltlb, dltub, tau;
    if (w <= 0.0f) {
      float temp = z[K - 2] * z[K - 2] / (d[K - 1] - d[K - 2] + rho) + z[K - 1] * z[K - 1] / rho;
      if (c <= temp) tau = rho;
      else {
        float del = d[K - 1] - d[K - 2];
        float a = -c * del + z[K - 2] * z[K - 2] + z[K - 1] * z[K - 1];
        float b = z[K - 1] * z[K - 1] * del;
        if (a < 0.0f) tau = 2.0f * b / (sqrtf(a * a + 4.0f * b * c) - a);
        else tau = (a + sqrtf(a * a + 4.0f * b * c)) / (2.0f * c);
      }
      dltlb = midpt; dltub = rho;
    } else {
      float del = d[K - 1] - d[K - 2];
      float a = -c * del + z[K - 2] * z[K - 2] + z[K - 1] * z[K - 1];
      float b = z[K - 1] * z[K - 1] * del;
      if (a < 0.0f) tau = 2.0f * b / (sqrtf(a * a + 4.0f * b * c) - a);
      else tau = (a + sqrtf(a * a + 4.0f * b * c)) / (2.0f * c);
      dltlb = 0.0f; dltub = midpt;
    }
    for (int j = 0; j < K; j++) DL(j) = (d[j] - d[K - 1]) - tau;
    float dpsi = 0.0f, erretm = 0.0f;
    psi = 0.0f;
    for (int j = 0; j <= ii; j++) {
      float t = z[j] / DL(j);
      psi += z[j] * t; dpsi += t * t; erretm += psi;
    }
    erretm = fabsf(erretm);
    float t = z[K - 1] / DL(K - 1);
    float phi = z[K - 1] * t, dphi = t * t;
    erretm = 8.0f * (-phi - psi) + erretm - phi + rhoinv + fabsf(tau) * (dpsi + dphi);
    w = rhoinv + phi + psi;
    if (fabsf(w) <= eps * erretm) { *dlam = d[K - 1] + tau; return; }
    if (w <= 0.0f) dltlb = fmaxf(dltlb, tau); else dltub = fminf(dltub, tau);
    for (int niter = 2; niter <= 30; ++niter) {
      float c2 = w - DL(K - 2) * dpsi - DL(K - 1) * dphi;
      float a = (DL(K - 2) + DL(K - 1)) * w - DL(K - 2) * DL(K - 1) * (dpsi + dphi);
      float b = DL(K - 2) * DL(K - 1) * w;
      float eta;
      if (niter == 2) {
        if (c2 < 0.0f) c2 = fabsf(c2);
        if (c2 == 0.0f) eta = dltub - tau;
        else if (a >= 0.0f) eta = (a + sqrtf(fabsf(a * a - 4.0f * b * c2))) / (2.0f * c2);
        else eta = 2.0f * b / (a - sqrtf(fabsf(a * a - 4.0f * b * c2)));
      } else {
        if (a >= 0.0f) eta = (a + sqrtf(fabsf(a * a - 4.0f * b * c2))) / (2.0f * c2);
        else eta = 2.0f * b / (a - sqrtf(fabsf(a * a - 4.0f * b * c2)));
      }
      if (w * eta > 0.0f) eta = -w / (dpsi + dphi);
      float tmp = tau + eta;
      if (tmp > dltub || tmp < dltlb) {
        if (w < 0.0f) eta = (dltub - tau) / 2.0f;
        else eta = (dltlb - tau) / 2.0f;
      }
      for (int j = 0; j < K; j++) DL(j) -= eta;
      tau += eta;
      dpsi = 0.0f; psi = 0.0f; erretm = 0.0f;
      for (int j = 0; j <= ii; j++) {
        float tt = z[j] / DL(j);
        psi += z[j] * tt; dpsi += tt * tt; erretm += psi;
      }
      erretm = fabsf(erretm);
      t = z[K - 1] / DL(K - 1);
      phi = z[K - 1] * t; dphi = t * t;
      erretm = 8.0f * (-phi - psi) + erretm - phi + rhoinv + fabsf(tau) * (dpsi + dphi);
      w = rhoinv + phi + psi;
      if (fabsf(w) <= eps * erretm) break;
      if (w <= 0.0f) dltlb = fmaxf(dltlb, tau); else dltub = fminf(dltub, tau);
    }
    *dlam = d[K - 1] + tau;
    return;
  }
  int ip1 = j0 + 1;
  float del = d[ip1] - d[j0];
  float midpt = del / 2.0f;
  for (int j = 0; j < K; j++) DL(j) = (d[j] - d[j0]) - midpt;
  float psi = 0.0f;
  for (int j = 0; j < j0; j++) psi += z[j] * z[j] / DL(j);
  float phi = 0.0f;
  for (int j = K - 1; j >= j0 + 2; j--) phi += z[j] * z[j] / DL(j);
  float c = rhoinv + psi + phi;
  float w = c + z[j0] * z[j0] / DL(j0) + z[ip1] * z[ip1] / DL(ip1);
  bool orgati;
  float tau, dltlb, dltub;
  if (w > 0.0f) {
    orgati = true;
    float a = c * del + z[j0] * z[j0] + z[ip1] * z[ip1];
    float b = z[j0] * z[j0] * del;
    if (a > 0.0f) tau = 2.0f * b / (a + sqrtf(fabsf(a * a - 4.0f * b * c)));
    else tau = (a - sqrtf(fabsf(a * a - 4.0f * b * c))) / (2.0f * c);
    dltlb = 0.0f; dltub = midpt;
  } else {
    orgati = false;
    float a = c * del - z[j0] * z[j0] - z[ip1] * z[ip1];
    float b = z[ip1] * z[ip1] * del;
    if (a < 0.0f) tau = 2.0f * b / (a - sqrtf(fabsf(a * a + 4.0f * b * c)));
    else tau = -(a + sqrtf(fabsf(a * a + 4.0f * b * c))) / (2.0f * c);
    dltlb = -midpt; dltub = 0.0f;
  }
  int org = orgati ? j0 : ip1;
  for (int j = 0; j < K; j++) DL(j) = (d[j] - d[org]) - tau;
  int ii = org;
  int iim1 = ii - 1, iip1 = ii + 1;
  float dpsi = 0.0f, erretm = 0.0f;
  psi = 0.0f;
  for (int j = 0; j <= ii - 1; j++) {
    float t = z[j] / DL(j);
    psi += z[j] * t; dpsi += t * t; erretm += psi;
  }
  erretm = fabsf(erretm);
  float dphi = 0.0f;
  phi = 0.0f;
  for (int j = K - 1; j >= ii + 1; j--) {
    float t = z[j] / DL(j);
    phi += z[j] * t; dphi += t * t; erretm += phi;
  }
  w = rhoinv + phi + psi;
  bool swtch3 = false;
  if (orgati) { if (w < 0.0f) swtch3 = true; }
  else { if (w > 0.0f) swtch3 = true; }
  if (ii == 0 || ii == K - 1) swtch3 = false;
  float t = z[ii] / DL(ii);
  float dw = dpsi + dphi + t * t;
  t = z[ii] * t;
  w += t;
  erretm = 8.0f * (phi - psi) + erretm + 2.0f * rhoinv + 3.0f * fabsf(t) + fabsf(tau) * dw;
  if (fabsf(w) <= eps * erretm) { *dlam = d[org] + tau; return; }
  if (w <= 0.0f) dltlb = fmaxf(dltlb, tau); else dltub = fminf(dltub, tau);
  float eta;
  {
    if (!swtch3) {
      float c2, a, b;
      if (orgati) {
        float q = z[j0] / DL(j0);
        c2 = w - DL(ip1) * dw - (d[j0] - d[ip1]) * (q * q);
      } else {
        float q = z[ip1] / DL(ip1);
        c2 = w - DL(j0) * dw - (d[ip1] - d[j0]) * (q * q);
      }
      a = (DL(j0) + DL(ip1)) * w - DL(j0) * DL(ip1) * dw;
      b = DL(j0) * DL(ip1) * w;
      if (c2 == 0.0f) {
        if (a == 0.0f) {
          if (orgati) a = z[j0] * z[j0] + DL(ip1) * DL(ip1) * (dpsi + dphi);
          else a = z[ip1] * z[ip1] + DL(j0) * DL(j0) * (dpsi + dphi);
        }
        eta = b / a;
      } else if (a <= 0.0f) eta = (a - sqrtf(fabsf(a * a - 4.0f * b * c2))) / (2.0f * c2);
      else eta = 2.0f * b / (a + sqrtf(fabsf(a * a - 4.0f * b * c2)));
    } else {
      float zz3[3], dd3[3];
      float temp = rhoinv + psi + phi;
      if (orgati) {
        float t1 = z[iim1] / DL(iim1);
        t1 = t1 * t1;
        float c2 = temp - DL(iip1) * (dpsi + dphi) - (d[iim1] - d[iip1]) * t1;
        zz3[0] = z[iim1] * z[iim1];
        zz3[2] = DL(iip1) * DL(iip1) * ((dpsi - t1) + dphi);
        zz3[1] = z[ii] * z[ii];
        dd3[0] = DL(iim1); dd3[1] = DL(ii); dd3[2] = DL(iip1);
        laed6_net(2, orgati, c2, dd3, zz3, w, &eta);
      } else {
        float t1 = z[iip1] / DL(iip1);
        t1 = t1 * t1;
        float c2 = temp - DL(iim1) * (dpsi + dphi) - (d[iip1] - d[iim1]) * t1;
        zz3[0] = DL(iim1) * DL(iim1) * (dpsi + (dphi - t1));
        zz3[2] = z[iip1] * z[iip1];
        zz3[1] = z[ii] * z[ii];
        dd3[0] = DL(iim1); dd3[1] = DL(ii); dd3[2] = DL(iip1);
        laed6_net(2, orgati, c2, dd3, zz3, w, &eta);
      }
    }
    if (w * eta >= 0.0f) eta = -w / dw;
    float tmp = tau + eta;
    if (tmp > dltub || tmp < dltlb) {
      if (w < 0.0f) eta = (dltub - tau) / 2.0f;
      else eta = (dltlb - tau) / 2.0f;
    }
  }
  float prew = w;
  for (int j = 0; j < K; j++) DL(j) -= eta;
  tau += eta;
  dpsi = 0.0f; psi = 0.0f; erretm = 0.0f;
  for (int j = 0; j <= ii - 1; j++) {
    float tt = z[j] / DL(j);
    psi += z[j] * tt; dpsi += tt * tt; erretm += psi;
  }
  erretm = fabsf(erretm);
  dphi = 0.0f; phi = 0.0f;
  for (int j = K - 1; j >= ii + 1; j--) {
    float tt = z[j] / DL(j);
    phi += z[j] * tt; dphi += tt * tt; erretm += phi;
  }
  w = rhoinv + phi + psi;
  t = z[ii] / DL(ii);
  dw = dpsi + dphi + t * t;
  t = z[ii] * t;
  w += t;
  erretm = 8.0f * (phi - psi) + erretm + 2.0f * rhoinv + 3.0f * fabsf(t) + fabsf(tau) * dw;
  bool swtch = false;
  if (orgati) { if (-w > fabsf(prew) / 10.0f) swtch = true; }
  else { if (w > fabsf(prew) / 10.0f) swtch = true; }
  for (int niter = 3; niter <= 30; ++niter) {
    if (fabsf(w) <= eps * erretm) break;
    if (w <= 0.0f) dltlb = fmaxf(dltlb, tau); else dltub = fminf(dltub, tau);
    if (!swtch3) {
      float c2, a, b;
      if (!swtch) {
        if (orgati) {
          float q = z[j0] / DL(j0);
          c2 = w - DL(ip1) * dw - (d[j0] - d[ip1]) * (q * q);
        } else {
          float q = z[ip1] / DL(ip1);
          c2 = w - DL(j0) * dw - (d[ip1] - d[j0]) * (q * q);
        }
      } else {
        float tt = z[ii] / DL(ii);
        if (orgati) dpsi += tt * tt;
        else dphi += tt * tt;
        c2 = w - DL(j0) * dpsi - DL(ip1) * dphi;
      }
      a = (DL(j0) + DL(ip1)) * w - DL(j0) * DL(ip1) * dw;
      b = DL(j0) * DL(ip1) * w;
      if (c2 == 0.0f) {
        if (a == 0.0f) {
          if (!swtch) {
            if (orgati) a = z[j0] * z[j0] + DL(ip1) * DL(ip1) * (dpsi + dphi);
            else a = z[ip1] * z[ip1] + DL(j0) * DL(j0) * (dpsi + dphi);
          } else a = DL(j0) * DL(j0) * dpsi + DL(ip1) * DL(ip1) * dphi;
        }
        eta = b / a;
      } else if (a <= 0.0f) eta = (a - sqrtf(fabsf(a * a - 4.0f * b * c2))) / (2.0f * c2);
      else eta = 2.0f * b / (a + sqrtf(fabsf(a * a - 4.0f * b * c2)));
    } else {
      float zz3[3], dd3[3];
      float t1 = rhoinv + psi + phi;
      if (swtch) {
        float c2 = t1 - DL(iim1) * dpsi - DL(iip1) * dphi;
        zz3[0] = DL(iim1) * DL(iim1) * dpsi;
        zz3[2] = DL(iip1) * DL(iip1) * dphi;
        zz3[1] = z[ii] * z[ii];
        dd3[0] = DL(iim1); dd3[1] = DL(ii); dd3[2] = DL(iip1);
        laed6_net(niter, orgati, c2, dd3, zz3, w, &eta);
      } else {
        if (orgati) {
          float t2 = z[iim1] / DL(iim1);
          t2 = t2 * t2;
          float c2 = t1 - DL(iip1) * (dpsi + dphi) - (d[iim1] - d[iip1]) * t2;
          zz3[0] = z[iim1] * z[iim1];
          zz3[2] = DL(iip1) * DL(iip1) * ((dpsi - t2) + dphi);
          zz3[1] = z[ii] * z[ii];
          dd3[0] = DL(iim1); dd3[1] = DL(ii); dd3[2] = DL(iip1);
          laed6_net(niter, orgati, c2, dd3, zz3, w, &eta);
        } else {
          float t2 = z[iip1] / DL(iip1);
          t2 = t2 * t2;
          float c2 = t1 - DL(iim1) * (dpsi + dphi) - (d[iip1] - d[iim1]) * t2;
          zz3[0] = DL(iim1) * DL(iim1) * (dpsi + (dphi - t2));
          zz3[2] = z[iip1] * z[iip1];
          zz3[1] = z[ii] * z[ii];
          dd3[0] = DL(iim1); dd3[1] = DL(ii); dd3[2] = DL(iip1);
          laed6_net(niter, orgati, c2, dd3, zz3, w, &eta);
        }
      }
    }
    if (w * eta >= 0.0f) eta = -w / dw;
    {
      float tmp = tau + eta;
      if (tmp > dltub || tmp < dltlb) {
        if (w < 0.0f) eta = (dltub - tau) / 2.0f;
        else eta = (dltlb - tau) / 2.0f;
      }
    }
    for (int j = 0; j < K; j++) DL(j) -= eta;
    tau += eta;
    prew = w;
    dpsi = 0.0f; psi = 0.0f; erretm = 0.0f;
    for (int j = 0; j <= ii - 1; j++) {
      float tt = z[j] / DL(j);
      psi += z[j] * tt; dpsi += tt * tt; erretm += psi;
    }
    erretm = fabsf(erretm);
    dphi = 0.0f; phi = 0.0f;
    for (int j = K - 1; j >= ii + 1; j--) {
      float tt = z[j] / DL(j);
      phi += z[j] * tt; dphi += tt * tt; erretm += phi;
    }
    w = rhoinv + phi + psi;
    t = z[ii] / DL(ii);
    dw = dpsi + dphi + t * t;
    t = z[ii] * t;
    w += t;
    erretm = 8.0f * (phi - psi) + erretm + 2.0f * rhoinv + 3.0f * fabsf(t) + fabsf(tau) * dw;
    if (w * prew > 0.0f && fabsf(w) > fabsf(prew) / 10.0f) swtch = !swtch;
  }
  *dlam = d[org] + tau;
#undef DL
}

// ---------------- ssteqr port, serial, f32 ----------------
static __device__ void steqr_f(int n, float* d, float* e, float* Z, int ldz) {
  if (n <= 1) return;
  float work_c[LEAF + 2], work_s[LEAF + 2];
  int nmaxit = n * 30, jtot = 0;
  int l1 = 0;
  while (true) {
    if (l1 > n - 1) break;
    if (l1 > 0) e[l1 - 1] = 0.0f;
    int m;
    for (m = l1; m <= n - 2; ++m) {
      float tst = fabsf(e[m]);
      if (tst == 0.0f) break;
      if (tst <= (sqrtf(fabsf(d[m])) * sqrtf(fabsf(d[m + 1]))) * FEPS) { e[m] = 0.0f; break; }
    }
    int l = l1, lend = m;
    l1 = m + 1;
    if (lend == l) continue;
    if (fabsf(d[lend]) < fabsf(d[l])) { int t = lend; lend = l; l = t; }
    if (lend > l) {
      while (true) {
        int mm;
        if (l != lend) {
          for (mm = l; mm <= lend - 1; ++mm) {
            float tst = fabsf(e[mm]); tst = tst * tst;
            if (tst <= (FEPS2 * fabsf(d[mm])) * fabsf(d[mm + 1]) + FSAFMIN) break;
          }
        } else mm = lend;
        if (mm < lend) e[mm] = 0.0f;
        float p = d[l];
        if (mm == l) { d[l] = p; l = l + 1; if (l <= lend) continue; else break; }
        if (mm == l + 1) {
          float rt1, rt2, c, s;
          f_laev2(d[l], e[l], d[l + 1], &rt1, &rt2, &c, &s);
          for (int r = 0; r < n; r++) {
            float t1 = Z[r * ldz + l + 1], t0 = Z[r * ldz + l];
            Z[r * ldz + l + 1] = c * t1 - s * t0;
            Z[r * ldz + l] = s * t1 + c * t0;
          }
          d[l] = rt1; d[l + 1] = rt2; e[l] = 0.0f;
          l += 2; if (l <= lend) continue; else break;
        }
        if (jtot == nmaxit) break;
        jtot++;
        float g = (d[l + 1] - p) / (2.0f * e[l]);
        float r = f_lapy2(g, 1.0f);
        g = d[mm] - p + e[l] / (g + f_sign(r, g));
        float s = 1.0f, c = 1.0f; p = 0.0f;
        for (int i = mm - 1; i >= l; --i) {
          float f = s * e[i], bb = c * e[i];
          f_lartg(g, f, &c, &s, &r);
          if (i != mm - 1) e[i + 1] = r;
          g = d[i + 1] - p;
          r = (d[i] - g) * s + 2.0f * c * bb;
          p = s * r;
          d[i + 1] = g + p;
          g = c * r - bb;
          work_c[i] = c; work_s[i] = -s;
        }
        for (int j = mm - l; j >= 1; --j) {
          float cj = work_c[l + j - 1], sj = work_s[l + j - 1];
          for (int rr = 0; rr < n; rr++) {
            float t1 = Z[rr * ldz + l + j], t0 = Z[rr * ldz + l + j - 1];
            Z[rr * ldz + l + j] = cj * t1 - sj * t0;
            Z[rr * ldz + l + j - 1] = sj * t1 + cj * t0;
          }
        }
        d[l] -= p; e[l] = g;
      }
    } else {
      while (true) {
        int mm;
        if (l != lend) {
          for (mm = l; mm >= lend + 1; --mm) {
            float tst = fabsf(e[mm - 1]); tst = tst * tst;
            if (tst <= (FEPS2 * fabsf(d[mm])) * fabsf(d[mm - 1]) + FSAFMIN) break;
          }
        } else mm = lend;
        if (mm > lend) e[mm - 1] = 0.0f;
        float p = d[l];
        if (mm == l) { d[l] = p; l = l - 1; if (l >= lend) continue; else break; }
        if (mm == l - 1) {
          float rt1, rt2, c, s;
          f_laev2(d[l - 1], e[l - 1], d[l], &rt1, &rt2, &c, &s);
          for (int r = 0; r < n; r++) {
            float t1 = Z[r * ldz + l], t0 = Z[r * ldz + l - 1];
            Z[r * ldz + l] = c * t1 - s * t0;
            Z[r * ldz + l - 1] = s * t1 + c * t0;
          }
          d[l - 1] = rt1; d[l] = rt2; e[l - 1] = 0.0f;
          l -= 2; if (l >= lend) continue; else break;
        }
        if (jtot == nmaxit) break;
        jtot++;
        float g = (d[l - 1] - p) / (2.0f * e[l - 1]);
        float r = f_lapy2(g, 1.0f);
        g = d[mm] - p + e[l - 1] / (g + f_sign(r, g));
        float s = 1.0f, c = 1.0f; p = 0.0f;
        for (int i = mm; i <= l - 1; ++i) {
          float f = s * e[i], bb = c * e[i];
          f_lartg(g, f, &c, &s, &r);
          if (i != mm) e[i - 1] = r;
          g = d[i] - p;
          r = (d[i + 1] - g) * s + 2.0f * c * bb;
          p = s * r;
          d[i] = g + p;
          g = c * r - bb;
          work_c[i] = c; work_s[i] = s;
        }
        for (int j = 1; j <= l - mm; ++j) {
          float cj = work_c[mm + j - 1], sj = work_s[mm + j - 1];
          for (int rr = 0; rr < n; rr++) {
            float t1 = Z[rr * ldz + mm + j], t0 = Z[rr * ldz + mm + j - 1];
            Z[rr * ldz + mm + j] = cj * t1 - sj * t0;
            Z[rr * ldz + mm + j - 1] = sj * t1 + cj * t0;
          }
        }
        d[l] -= p; e[l - 1] = g;
      }
    }
  }
  for (int ii = 1; ii < n; ++ii) {
    int i = ii - 1, k = i; float p = d[i];
    for (int j = ii; j < n; ++j) if (d[j] < p) { k = j; p = d[j]; }
    if (k != i) {
      d[k] = d[i]; d[i] = p;
      for (int r = 0; r < n; r++) { float t = Z[r * ldz + i]; Z[r * ldz + i] = Z[r * ldz + k]; Z[r * ldz + k] = t; }
    }
  }
}

// ---------------- slaed1/2/3-equivalent merge, f32 (FMA assembly) ----------------
static __device__ void laed1_f(int tid, int nb, int n1, int off, float rho_in,
    float* Zb, float* Qt, float* Um, float* dd,
    float* dlamda, float* w2, float* lamv, float* wtv, float* zv, float* dnew, float* dsort,
    int* indxq, int* indxp, int* indxc, int* indxm,
    float* shs, int* shi) {
  int n2 = nb - n1;
  if (tid == 0) {
    float rho = rho_in;
    for (int i = 0; i < n1; i++) zv[i] = Zb[(off + n1 - 1) * LD + off + i];
    for (int i = 0; i < n2; i++) zv[n1 + i] = Zb[(off + n1) * LD + off + n1 + i];
    if (rho < 0.0f) for (int i = n1; i < nb; i++) zv[i] = -zv[i];
    const float isq2 = 0.70710678118654752440f;
    for (int i = 0; i < nb; i++) zv[i] *= isq2;
    rho = fabsf(2.0f * rho);
    for (int i = n1; i < nb; i++) indxq[off + i] += n1;
    for (int i = 0; i < nb; i++) dsort[i] = dd[off + indxq[off + i]];
    f_lamrg(n1, n2, dsort, 1, 1, indxc);
    for (int i = 0; i < nb; i++) indxm[i] = indxq[off + indxc[i]];
    float zmax = 0.0f, dmax = 0.0f;
    for (int i = 0; i < nb; i++) {
      float az = fabsf(zv[i]); if (az > zmax) zmax = az;
      float ad = fabsf(dd[off + i]); if (ad > dmax) dmax = ad;
    }
    float tol = 8.0f * FEPS * ((dmax > zmax) ? dmax : zmax);
    int K = 0;
    if (rho * zmax <= tol) {
      for (int j = 0; j < nb; j++) indxp[j] = indxm[j];
    } else {
      int K2 = nb; int pj = 0; int j; bool found = false;
      for (j = 0; j < nb; j++) {
        int nj = indxm[j];
        if (rho * fabsf(zv[nj]) <= tol) { K2--; indxp[K2] = nj; if (j == nb - 1) break; }
        else { pj = nj; found = true; break; }
      }
      if (found) {
        while (true) {
          j++;
          if (j >= nb) break;
          int nj = indxm[j];
          if (rho * fabsf(zv[nj]) <= tol) { K2--; indxp[K2] = nj; }
          else {
            float s_ = zv[pj], c_ = zv[nj];
            float tau_ = f_lapy2(c_, s_);
            float t_ = dd[off + nj] - dd[off + pj];
            c_ /= tau_; s_ = -s_ / tau_;
            if (fabsf(t_ * c_ * s_) <= tol) {
              zv[nj] = tau_; zv[pj] = 0.0f;
              for (int r = 0; r < nb; r++) {
                float x = Zb[(off + r) * LD + off + pj], y = Zb[(off + r) * LD + off + nj];
                Zb[(off + r) * LD + off + pj] = c_ * x + s_ * y;
                Zb[(off + r) * LD + off + nj] = c_ * y - s_ * x;
              }
              float t2 = dd[off + pj] * c_ * c_ + dd[off + nj] * s_ * s_;
              dd[off + nj] = dd[off + pj] * s_ * s_ + dd[off + nj] * c_ * c_;
              dd[off + pj] = t2;
              K2--;
              int i_ = 1;
              while (true) {
                if (K2 + i_ < nb) {
                  if (dd[off + pj] < dd[off + indxp[K2 + i_]]) {
                    indxp[K2 + i_ - 1] = indxp[K2 + i_]; indxp[K2 + i_] = pj; i_++;
                  } else { indxp[K2 + i_ - 1] = pj; break; }
                } else { indxp[K2 + i_ - 1] = pj; break; }
              }
              pj = nj;
            } else {
              dlamda[K] = dd[off + pj]; w2[K] = zv[pj]; indxp[K] = pj; K++;
              pj = nj;
            }
          }
        }
        dlamda[K] = dd[off + pj]; w2[K] = zv[pj]; indxp[K] = pj; K++;
      }
    }
    shi[0] = K; shs[0] = rho;
  }
  __syncthreads();
  int K = shi[0]; float rho = shs[0];
  if (K == 0) {
    for (int idx = tid; idx < nb * nb; idx += 256) {
      int r = idx / nb, jj = idx - r * nb;
      Qt[r * LD + jj] = Zb[(off + r) * LD + off + indxp[jj]];
    }
    for (int jj = tid; jj < nb; jj += 256) dnew[jj] = dd[off + indxp[jj]];
    __syncthreads();
    for (int idx = tid; idx < nb * nb; idx += 256) {
      int r = idx / nb, jj = idx - r * nb;
      Zb[(off + r) * LD + off + jj] = Qt[r * LD + jj];
    }
    for (int jj = tid; jj < nb; jj += 256) { dd[off + jj] = dnew[jj]; indxq[off + jj] = jj; }
    __syncthreads();
    return;
  }
  if (K == 1) {
    if (tid == 0) { lamv[0] = dlamda[0] + rho * w2[0] * w2[0]; Um[0] = 1.0f; }
  } else if (K == 2) {
    if (tid < 2) {
      float u0, u1, dl_;
      f_laed5(tid, dlamda, w2, rho, &dl_, &u0, &u1);
      lamv[tid] = dl_; Um[0 * LD + tid] = u0; Um[1 * LD + tid] = u1;
    }
  } else {
    if (tid < K) laed4_net(K, tid, dlamda, w2, rho, &lamv[tid], &Um[tid]);
  }
  __syncthreads();
  if (K > 2) {
    if (tid < K) {
      int i = tid; float val = Um[i * LD + i];
      for (int j2 = 0; j2 < K; j2++) if (j2 != i) val *= Um[i * LD + j2] / (dlamda[i] - dlamda[j2]);
      wtv[i] = f_sign(sqrtf(fabsf(val)), w2[i]);
    }
    __syncthreads();
    if (tid < K) {
      int j2 = tid;
      for (int i = 0; i < K; i++) Um[i * LD + j2] = wtv[i] / Um[i * LD + j2];
      float nrm = f_snrm2_strided(&Um[j2], K, LD);
      for (int i = 0; i < K; i++) Um[i * LD + j2] /= nrm;
    }
    __syncthreads();
  }
  for (int idx = tid; idx < nb * K; idx += 256) {
    int r = idx / K, j2 = idx - r * K;
    float acc = 0.0f;
    for (int i = 0; i < K; i++) acc = fmaf(Zb[(off + r) * LD + off + indxp[i]], Um[i * LD + j2], acc);
    Qt[r * LD + j2] = acc;
  }
  int nd = nb - K;
  for (int idx = tid; idx < nb * nd; idx += 256) {
    int r = idx / nd, jj = idx - r * nd;
    Qt[r * LD + K + jj] = Zb[(off + r) * LD + off + indxp[K + jj]];
  }
  for (int jj = tid; jj < nb; jj += 256) dnew[jj] = (jj < K) ? lamv[jj] : dd[off + indxp[jj]];
  __syncthreads();
  for (int idx = tid; idx < nb * nb; idx += 256) {
    int r = idx / nb, jj = idx - r * nb;
    Zb[(off + r) * LD + off + jj] = Qt[r * LD + jj];
  }
  for (int jj = tid; jj < nb; jj += 256) dd[off + jj] = dnew[jj];
  __syncthreads();
  if (tid == 0) f_lamrg(K, nb - K, dnew, 1, -1, indxq + off);
  __syncthreads();
}

#define FSTR 142560
// ---------------- ssyevd-clone kernel (f32): blocked SSYTRD(FMA) + sstedc + blocked SORMQR(FMA) ----------------
__global__ __launch_bounds__(256) void k_eigh2(const float* __restrict__ gm,
    float* __restrict__ fws, int* __restrict__ iws,
    float* __restrict__ vecsbt, float* __restrict__ scales) {
  int b = blockIdx.x, tid = threadIdx.x;
  float* A = fws + (size_t)b * FSTR;
  float* Zb = A + 30976;
  float* Qt = Zb + 30976;
  float* Um = Qt + 30976;
  float* sm1 = Um + 30976;
  float* dd = sm1;
  float* ee = sm1 + 176;
  float* tauv = sm1 + 352;
  float* dlamda = sm1 + 528;
  float* w2 = sm1 + 704;
  float* lamv = sm1 + 880;
  float* wtv = sm1 + 1056;
  float* zv = sm1 + 1232;
  float* dnew = sm1 + 1408;
  float* dsort = sm1 + 1584;
  float* Wp = A + 125664;       // [176*32]
  float* Wa = Wp + 5632;
  float* Wb = Wa + 5632;
  int* ib_ = iws + b * 880;
  int* indxq = ib_;
  int* indxp = ib_ + 176;
  int* indxc = ib_ + 352;
  int* indxm = ib_ + 528;
  __shared__ float shv[176];
  __shared__ float shs[2];
  __shared__ int shi[2];
  __shared__ float t12[64];
  __shared__ float Tm[1024];
  for (int i = tid; i < Tn * Tn; i += 256)
    A[(i / Tn) * LD + (i % Tn)] = gm[(size_t)b * Tn * Tn + i];
  __syncthreads();
  // ======== blocked SSYTRD (lower), NB=32, panels 0,32,64,96,128; ssytd2 tail 160.. ========
  for (int i0 = 0; i0 < Tn - 32; i0 += 32) {
    for (int i = 0; i < 32; i++) {
      int g = i0 + i;
      if (i > 0) {
        for (int r = g + tid; r < Tn; r += 256) {
          float acc = A[r * LD + g];
          for (int k = 0; k < i; k++) acc = fmaf(-Wp[g * 32 + k], A[r * LD + (i0 + k)], acc);
          for (int k = 0; k < i; k++) acc = fmaf(-A[g * LD + (i0 + k)], Wp[r * 32 + k], acc);
          A[r * LD + g] = acc;
        }
        __syncthreads();
      }
      if (tid == 0) {
        float scale = 0.0f, ssq = 1.0f;
        for (int r = g + 2; r < Tn; r++) {
          float ax = fabsf(A[r * LD + g]);
          if (ax != 0.0f) {
            if (scale < ax) { float q = scale / ax; ssq = 1.0f + ssq * (q * q); scale = ax; }
            else { float q = ax / scale; ssq = ssq + q * q; }
          }
        }
        float xnorm = scale * sqrtf(ssq);
        float alpha = A[(g + 1) * LD + g];
        float taui = 0.0f, scal = 0.0f;
        if (xnorm == 0.0f) { ee[g] = alpha; }
        else {
          float beta = -f_sign(f_lapy2(alpha, xnorm), alpha);
          taui = (beta - alpha) / beta;
          scal = 1.0f / (alpha - beta);
          ee[g] = beta;
        }
        tauv[g] = taui; shs[0] = taui; shs[1] = scal;
      }
      __syncthreads();
      float taui = shs[0];
      if (taui != 0.0f) {
        float scal = shs[1];
        for (int r = g + 2 + tid; r < Tn; r += 256) A[r * LD + g] *= scal;
      }
      __syncthreads();
      if (tid == 0) A[(g + 1) * LD + g] = 1.0f;
      __syncthreads();
      for (int r = g + 1 + tid; r < Tn; r += 256) {
        float acc = 0.0f;
        for (int c = g + 1; c < r; c++) acc = fmaf(A[c * LD + g], A[r * LD + c], acc);
        acc = fmaf(A[r * LD + g], A[r * LD + r], acc);
        float temp2 = 0.0f;
        for (int k = r + 1; k < Tn; k++) temp2 = fmaf(A[k * LD + r], A[k * LD + g], temp2);
        acc += temp2;
        shv[r] = acc;
      }
      __syncthreads();
      if (i > 0) {
        if (tid < i) {
          int k = tid;
          float acc = 0.0f;
          for (int r = g + 1; r < Tn; r++) acc = fmaf(Wp[r * 32 + k], A[r * LD + g], acc);
          t12[k] = acc;
        }
        __syncthreads();
        for (int r = g + 1 + tid; r < Tn; r += 256) {
          float acc = shv[r];
          for (int k = 0; k < i; k++) acc = fmaf(-t12[k], A[r * LD + (i0 + k)], acc);
          shv[r] = acc;
        }
        __syncthreads();
        if (tid < i) {
          int k = tid;
          float acc = 0.0f;
          for (int r = g + 1; r < Tn; r++) acc = fmaf(A[r * LD + (i0 + k)], A[r * LD + g], acc);
          t12[32 + k] = acc;
        }
        __syncthreads();
        for (int r = g + 1 + tid; r < Tn; r += 256) {
          float acc = shv[r];
          for (int k = 0; k < i; k++) acc = fmaf(-t12[32 + k], Wp[r * 32 + k], acc);
          shv[r] = acc;
        }
        __syncthreads();
      }
      for (int r = g + 1 + tid; r < Tn; r += 256) shv[r] = taui * shv[r];
      __syncthreads();
      if (tid == 0) {
        float dot = 0.0f;
        for (int r = g + 1; r < Tn; r++) dot = fmaf(shv[r], A[r * LD + g], dot);
        shs[0] = -0.5f * taui * dot;
      }
      __syncthreads();
      float alf = shs[0];
      for (int r = g + 1 + tid; r < Tn; r += 256) Wp[r * 32 + i] = fmaf(alf, A[r * LD + g], shv[r]);
      __syncthreads();
    }
    {
      int base2 = i0 + 32;
      int nt = Tn - base2;
      int npr = nt * (nt + 1) / 2;
      for (int p = tid; p < npr; p += 256) {
        int rr = (int)((sqrtf(8.0f * (float)p + 1.0f) - 1.0f) * 0.5f);
        while ((rr + 1) * (rr + 2) / 2 <= p) rr++;
        while (rr * (rr + 1) / 2 > p) rr--;
        int cc = p - rr * (rr + 1) / 2;
        int r = base2 + rr, c = base2 + cc;
        float acc = A[r * LD + c];
        for (int L = 0; L < 32; L++) {
          acc = fmaf(A[r * LD + (i0 + L)], -Wp[c * 32 + L], acc);
          acc = fmaf(Wp[r * 32 + L], -A[c * LD + (i0 + L)], acc);
        }
        A[r * LD + c] = acc;
        if (r != c) A[c * LD + r] = acc;
      }
      __syncthreads();
      if (tid < 32) {
        int g2 = i0 + tid;
        A[(g2 + 1) * LD + g2] = ee[g2];
      }
      __syncthreads();
    }
  }
  // ---- final ssytd2 on trailing 16 (cols 160..174) ----
  for (int i = 160; i < Tn - 1; i++) {
    if (tid == 0) {
      float scale = 0.0f, ssq = 1.0f;
      for (int r = i + 2; r < Tn; r++) {
        float ax = fabsf(A[r * LD + i]);
        if (ax != 0.0f) {
          if (scale < ax) { float q = scale / ax; ssq = 1.0f + ssq * (q * q); scale = ax; }
          else { float q = ax / scale; ssq = ssq + q * q; }
        }
      }
      float xnorm = scale * sqrtf(ssq);
      float alpha = A[(i + 1) * LD + i];
      float taui = 0.0f, scal = 0.0f;
      if (xnorm == 0.0f) { ee[i] = alpha; }
      else {
        float beta = -f_sign(f_lapy2(alpha, xnorm), alpha);
        taui = (beta - alpha) / beta;
        scal = 1.0f / (alpha - beta);
        ee[i] = beta;
      }
      tauv[i] = taui; shs[0] = taui; shs[1] = scal;
    }
    __syncthreads();
    float taui = shs[0];
    if (taui != 0.0f) {
      float scal = shs[1];
      for (int r = i + 2 + tid; r < Tn; r += 256) A[r * LD + i] *= scal;
      __syncthreads();
      for (int r = i + 1 + tid; r < Tn; r += 256) {
        float acc = 0.0f;
        for (int c = i + 1; c < r; c++) {
          float vc = (c == i + 1) ? 1.0f : A[c * LD + i];
          acc = fmaf(taui * vc, A[r * LD + c], acc);
        }
        float vr = (r == i + 1) ? 1.0f : A[r * LD + i];
        acc = fmaf(taui * vr, A[r * LD + r], acc);
        float temp2 = 0.0f;
        for (int k = r + 1; k < Tn; k++) temp2 = fmaf(A[k * LD + r], A[k * LD + i], temp2);
        acc = fmaf(taui, temp2, acc);
        shv[r] = acc;
      }
      __syncthreads();
      if (tid == 0) {
        float dot = 0.0f;
        for (int r = i + 1; r < Tn; r++) {
          float vr = (r == i + 1) ? 1.0f : A[r * LD + i];
          dot = fmaf(vr, shv[r], dot);
        }
        shs[0] = -0.5f * taui * dot;
      }
      __syncthreads();
      float alpha2 = shs[0];
      for (int r = i + 1 + tid; r < Tn; r += 256) {
        float vr = (r == i + 1) ? 1.0f : A[r * LD + i];
        shv[r] = fmaf(alpha2, vr, shv[r]);
      }
      __syncthreads();
      int m2 = Tn - 1 - i;
      int npairs = m2 * (m2 + 1) / 2;
      for (int p = tid; p < npairs; p += 256) {
        int rr = (int)((sqrtf(8.0f * (float)p + 1.0f) - 1.0f) * 0.5f);
        while ((rr + 1) * (rr + 2) / 2 <= p) rr++;
        while (rr * (rr + 1) / 2 > p) rr--;
        int cc = p - rr * (rr + 1) / 2;
        int r = i + 1 + rr, c = i + 1 + cc;
        float vr = (r == i + 1) ? 1.0f : A[r * LD + i];
        float vc = (c == i + 1) ? 1.0f : A[c * LD + i];
        float val = A[r * LD + c];
        val = fmaf(vr, -shv[c], val);
        val = fmaf(shv[r], -vc, val);
        A[r * LD + c] = val;
      }
      __syncthreads();
    }
  }
  for (int i = tid; i < Tn; i += 256) dd[i] = A[i * LD + i];
  __syncthreads();
  // ======== sstedc ========
  if (tid == 0) {
    float on = 0.0f;
    for (int i = 0; i < Tn; i++) { float v = fabsf(dd[i]); if (v > on) on = v; }
    for (int i = 0; i < Tn - 1; i++) { float v = fabsf(ee[i]); if (v > on) on = v; }
    shs[0] = (on > 0.0f) ? on : 1.0f;
  }
  __syncthreads();
  float orgnrm = shs[0];
  for (int i = tid; i < Tn; i += 256) dd[i] /= orgnrm;
  for (int i = tid; i < Tn - 1; i += 256) ee[i] /= orgnrm;
  for (int i = tid; i < Tn * Tn; i += 256)
    Zb[(i / Tn) * LD + (i % Tn)] = ((i / Tn) == (i % Tn)) ? 1.0f : 0.0f;
  __syncthreads();
  if (tid == 0) {
    for (int c = LEAF; c < Tn; c += LEAF) { dd[c - 1] -= fabsf(ee[c - 1]); dd[c] -= fabsf(ee[c - 1]); }
  }
  __syncthreads();
  if (tid < 8) steqr_f(LEAF, dd + LEAF * tid, ee + LEAF * tid,
                       Zb + (size_t)(LEAF * tid) * LD + LEAF * tid, LD);
  __syncthreads();
  for (int i = tid; i < Tn; i += 256) indxq[i] = i % LEAF;
  __syncthreads();
  for (int nb = 2 * LEAF; nb <= Tn; nb *= 2) {
    for (int off = 0; off < Tn; off += nb) {
      laed1_f(tid, nb, nb / 2, off, ee[off + nb / 2 - 1],
              Zb, Qt, Um, dd, dlamda, w2, lamv, wtv, zv, dnew, dsort,
              indxq, indxp, indxc, indxm, shs, shi);
    }
  }
  for (int idx = tid; idx < Tn * Tn; idx += 256) {
    int r = idx / Tn, j = idx % Tn;
    Qt[r * LD + j] = Zb[r * LD + indxq[j]];
  }
  for (int j = tid; j < Tn; j += 256) dnew[j] = dd[indxq[j]];
  __syncthreads();
  for (int idx = tid; idx < Tn * Tn; idx += 256) {
    int r = idx / Tn, j = idx % Tn;
    Zb[r * LD + j] = Qt[r * LD + j];
  }
  for (int j = tid; j < Tn; j += 256) dd[j] = dnew[j] * orgnrm;
  __syncthreads();
  // ======== blocked SORMQR back-transform (FMA) ========
  for (int bi = 0; bi < 6; bi++) {
    int s = (bi == 0) ? 160 : (128 - (bi - 1) * 32);
    int ibk = (bi == 0) ? 15 : 32;
    for (int i2 = 0; i2 < ibk; i2++) {
      float ti = tauv[s + i2];
      if (tid < i2) {
        int j2 = tid;
        float acc = 0.0f;
        for (int r = s + i2; r <= Tn - 2; r++) {
          float vj = (r == s + j2) ? 1.0f : A[(r + 1) * LD + (s + j2)];
          float vi = (r == s + i2) ? 1.0f : A[(r + 1) * LD + (s + i2)];
          acc = fmaf(vj, vi, acc);
        }
        Tm[j2 * 32 + i2] = (ti == 0.0f) ? 0.0f : (-ti) * acc;
      }
      __syncthreads();
      if (tid == 0) {
        if (ti != 0.0f) {
          for (int J = 0; J < i2; J++) {
            float tmp = Tm[J * 32 + i2];
            if (tmp != 0.0f) {
              for (int I2 = 0; I2 < J; I2++) Tm[I2 * 32 + i2] = fmaf(tmp, Tm[I2 * 32 + J], Tm[I2 * 32 + i2]);
              Tm[J * 32 + i2] = tmp * Tm[J * 32 + J];
            }
          }
        }
        Tm[i2 * 32 + i2] = ti;
      }
      __syncthreads();
    }
    int c2r0 = s + ibk + 1;
    int nc2 = Tn - c2r0;
    for (int e = tid; e < Tn * ibk; e += 256) {
      int c = e / ibk, j = e - (e / ibk) * ibk;
      float acc = Zb[(s + 1 + j) * LD + c];
      for (int k = j + 1; k < ibk; k++) {
        float v1 = A[(s + 1 + k) * LD + (s + j)];
        acc = fmaf(v1, Zb[(s + 1 + k) * LD + c], acc);
      }
      Wb[c * 32 + j] = acc;
    }
    __syncthreads();
    if (nc2 > 0) {
      for (int e = tid; e < Tn * ibk; e += 256) {
        int c = e / ibk, j = e - (e / ibk) * ibk;
        float acc = 0.0f;
        for (int rr = 0; rr < nc2; rr++)
          acc = fmaf(Zb[(c2r0 + rr) * LD + c], A[(c2r0 + rr) * LD + (s + j)], acc);
        Wb[c * 32 + j] = acc + Wb[c * 32 + j];
      }
      __syncthreads();
    }
    for (int e = tid; e < Tn * ibk; e += 256) {
      int c = e / ibk, j = e - (e / ibk) * ibk;
      float acc = Tm[j * 32 + j] * Wb[c * 32 + j];
      for (int K = j + 1; K < ibk; K++) acc = fmaf(Tm[j * 32 + K], Wb[c * 32 + K], acc);
      Wa[c * 32 + j] = acc;
    }
    __syncthreads();
    if (nc2 > 0) {
      for (int e = tid; e < nc2 * Tn; e += 256) {
        int rr = e / Tn, c = e - (e / Tn) * Tn;
        float cv = Zb[(c2r0 + rr) * LD + c];
        for (int j = 0; j < ibk; j++)
          cv = fmaf(-Wa[c * 32 + j], A[(c2r0 + rr) * LD + (s + j)], cv);
        Zb[(c2r0 + rr) * LD + c] = cv;
      }
      __syncthreads();
    }
    for (int e = tid; e < Tn * ibk; e += 256) {
      int c = e / ibk, j = e - (e / ibk) * ibk;
      float acc = Wa[c * 32 + j];
      for (int K = j - 1; K >= 0; K--) {
        float v1 = A[(s + 1 + j) * LD + (s + K)];
        acc = fmaf(v1, Wa[c * 32 + K], acc);
      }
      Wb[c * 32 + j] = acc;
    }
    __syncthreads();
    for (int e = tid; e < ibk * Tn; e += 256) {
      int j = e / Tn, c = e - (e / Tn) * Tn;
      Zb[(s + 1 + j) * LD + c] = Zb[(s + 1 + j) * LD + c] - Wb[c * 32 + j];
    }
    __syncthreads();
  }
  // ---- outputs ----
  for (int idx = tid; idx < Tn * Tn; idx += 256) {
    int t = idx / Tn, j = idx % Tn;
    vecsbt[((size_t)b * Tn + t) * Tn + j] = Zb[t * LD + j];
  }
  for (int j = tid; j < Tn; j += 256) {
    float vd = dd[Tn - 1 - j];
    if (vd <= 0.f) vd = 1e-7f;
    scales[b * Tn + j] = sqrtf(vd) * 1000.f;
  }
}

// ---------------- conv ----------------
__global__ void k_conv(const float* __restrict__ X, const float* __restrict__ cw,
                       const float* __restrict__ cb, float* __restrict__ oc) {
  int idx = blockIdx.x * 256 + threadIdx.x;
  if (idx >= Bn * Tn * Cn) return;
  int c = idx & (Cn - 1);
  int bt = idx >> 6;
  const float* xr = X + bt * Rn;
  const float* wr = cw + c * Rn;
  float acc = cb[c];
#pragma unroll 4
  for (int r = 0; r < Rn; ++r) acc = fmaf(xr[r], wr[r], acc);
  oc[idx] = acc;
}

// ---------------- pairwise MLP -> grouping_M ----------------
__global__ __launch_bounds__(256) void k_mlp(const float* __restrict__ oc,
        const float* __restrict__ w1, const float* __restrict__ b1,
        const float* __restrict__ w2, const float* __restrict__ b2,
        float* __restrict__ gm) {
  __shared__ float xw[4 * 8];
  int tid = threadIdx.x;
  int lane = tid & 63, wv = tid >> 6;
  int b = blockIdx.x / Tn, t = blockIdx.x % Tn;
  bool active = (tid < Hn);
  float w1r[64];
  if (active) {
    const float4* wrow = reinterpret_cast<const float4*>(w1 + tid * Cn);
#pragma unroll
    for (int i = 0; i < 16; ++i) {
      float4 v = wrow[i];
      w1r[4 * i] = v.x; w1r[4 * i + 1] = v.y; w1r[4 * i + 2] = v.z; w1r[4 * i + 3] = v.w;
    }
  } else {
#pragma unroll
    for (int i = 0; i < 64; ++i) w1r[i] = 0.f;
  }
  float myb1 = active ? b1[tid] : 0.f;
  float myw2 = active ? w2[tid] : 0.f;
  float b2v = b2[0];
  float outt = oc[(b * Tn + t) * Cn + lane];
  for (int s0 = 0; s0 < Tn; s0 += 8) {
    float dj[8];
#pragma unroll
    for (int j = 0; j < 8; ++j) {
      float o = oc[(b * Tn + s0 + j) * Cn + lane];
      float d = outt - o;
      dj[j] = sqrtf(d * d + 1e-9f);
    }
    float acc[8];
#pragma unroll
    for (int j = 0; j < 8; ++j) acc[j] = myb1;
#pragma unroll
    for (int c = 0; c < 64; ++c) {
      float wv1 = w1r[c];
#pragma unroll
      for (int j = 0; j < 8; ++j) {
        float dv = __int_as_float(__builtin_amdgcn_readlane(__float_as_int(dj[j]), c));
        acc[j] = fmaf(dv, wv1, acc[j]);
      }
    }
#pragma unroll
    for (int j = 0; j < 8; ++j) {
      float v = fmaxf(acc[j], 0.f) * myw2;
#pragma unroll
      for (int off = 32; off; off >>= 1) v += __shfl_xor(v, off);
      acc[j] = v;
    }
    if (lane == 0) {
#pragma unroll
      for (int j = 0; j < 8; ++j) xw[wv * 8 + j] = acc[j];
    }
    __syncthreads();
    if (tid < 8) {
      float sum = xw[tid] + xw[8 + tid] + xw[16 + tid] + xw[24 + tid] + b2v;
      float cl = 1.f / (1.f + expf(-sum));
      int s = s0 + tid;
      gm[(b * Tn + t) * Tn + s] = (s == t) ? 1.f : cl;
    }
    __syncthreads();
  }
}

// ---------------- soft indices ----------------
__global__ __launch_bounds__(64) void k_softidx(const float* __restrict__ vecsbt,
        const float* __restrict__ scales, const float* __restrict__ gumbel,
        float* __restrict__ si) {
  int bt = blockIdx.x;
  int b = bt / Tn;
  int lane = threadIdx.x;
  const float* vr = vecsbt + (size_t)bt * Tn;
  const float* sc = scales + b * Tn;
  const float* gr = gumbel + (size_t)bt * Tn;
  float y[3];
  float m = -3.0e38f;
#pragma unroll
  for (int u = 0; u < 3; ++u) {
    int j = lane + 64 * u;
    float v = -3.0e38f;
    if (j < Tn) v = (vr[j] * sc[j] + gr[j]) / TAUf;
    y[u] = v;
    m = fmaxf(m, v);
  }
#pragma unroll
  for (int off = 32; off; off >>= 1) m = fmaxf(m, __shfl_xor(m, off));
  float num = 0.f, den = 0.f;
#pragma unroll
  for (int u = 0; u < 3; ++u) {
    int j = lane + 64 * u;
    if (j < Tn) {
      float e = expf(y[u] - m);
      num = fmaf((float)j, e, num);
      den += e;
    }
  }
#pragma unroll
  for (int off = 32; off; off >>= 1) { num += __shfl_xor(num, off); den += __shfl_xor(den, off); }
  if (lane == 0) si[bt] = num / den;
}

// ---------------- grouping prep ----------------
__global__ void k_prep(const float* __restrict__ X, const float* __restrict__ si,
                       float* __restrict__ Y, int* __restrict__ gstart, int* __restrict__ gend,
                       int* __restrict__ ngr) {
  __shared__ int sgid[Tn];
  __shared__ float swt[Tn];
  int b = blockIdx.x, tid = threadIdx.x;
  const float* idx = si + b * Tn;
  if (tid == 0) {
    int g = 0;
    for (int t2 = 0; t2 < Tn; ++t2) {
      if (t2 > 0 && idx[t2] != idx[t2 - 1]) g++;
      sgid[t2] = g;
    }
    ngr[b] = g + 1;
  }
  if (tid < Tn) {
    float x = idx[tid] + 1.f;
    swt[tid] = x * (1.f / x);
  }
  __syncthreads();
  if (tid < Tn) {
    int g = sgid[tid];
    if (tid == 0 || sgid[tid - 1] != g) gstart[b * Tn + g] = tid;
    if (tid == Tn - 1 || sgid[tid + 1] != g) gend[b * Tn + g] = tid + 1;
  }
  for (int e = tid; e < Tn * Rn; e += 256) {
    int t2 = e / Rn;
    Y[(size_t)b * Tn * Rn + e] = X[(size_t)b * Tn * Rn + e] * swt[t2];
  }
}

// ---------------- pair LUT ----------------
__global__ void k_lut(int* __restrict__ lut) {
  int k = blockIdx.x * 256 + threadIdx.x;
  if (k >= NPAIRn) return;
  int r = 0, rem = k;
  while (rem >= Rn - 1 - r) { rem -= Rn - 1 - r; r++; }
  lut[2 * k] = r;
  lut[2 * k + 1] = r + 1 + rem;
}

// ---------------- per-(b,g) correlations -> padded ----------------
__global__ __launch_bounds__(256) void k_corr(const float* __restrict__ Y,
        const int* __restrict__ gstart, const int* __restrict__ gend,
        const int* __restrict__ ngr, const int* __restrict__ lut,
        float* __restrict__ pad) {
  int b = blockIdx.x / MAXGn, g = blockIdx.x % MAXGn;
  float* out = pad + (size_t)(b * MAXGn + g) * NPAIRn;
  int tid = threadIdx.x;
  if (g >= ngr[b]) {
    for (int k = tid; k < NPAIRn; k += 256) out[k] = 0.f;
    return;
  }
  __shared__ float Sg[Rn], Dg[Rn];
  int t0 = gstart[b * Tn + g], t1 = gend[b * Tn + g];
  const float* Yb = Y + (size_t)b * Tn * Rn;
  const float invT = 1.f / (float)Tn;
  if (tid < Rn) {
    float s = 0.f, p = 0.f;
    for (int t2 = t0; t2 < t1; ++t2) {
      float v = Yb[t2 * Rn + tid];
      s += v;
      p = fmaf(v, v, p);
    }
    Sg[tid] = s;
    Dg[tid] = fmaxf(p - s * s * invT, 0.f);
  }
  __syncthreads();
  for (int k = tid; k < NPAIRn; k += 256) {
    int r = lut[2 * k], sc = lut[2 * k + 1];
    float p = 0.f;
    for (int t2 = t0; t2 < t1; ++t2)
      p = fmaf(Yb[t2 * Rn + r], Yb[t2 * Rn + sc], p);
    float cov = p - Sg[r] * Sg[sc] * invT;
    float den = sqrtf(Dg[r] * Dg[sc]);
    float co = cov / ((den > 0.f) ? den : 1.f);
    co = fminf(fmaxf(co, -1.f), 1.f);
    out[k] = co;
  }
}

extern "C" void kernel_launch(void* const* d_in, const int* in_sizes, int n_in,
                              void* d_out, int out_size, void* d_ws, size_t ws_size,
                              hipStream_t stream) {
  const float* X  = (const float*)d_in[0];
  const float* cw = (const float*)d_in[1];
  const float* cb = (const float*)d_in[2];
  const float* w1 = (const float*)d_in[3];
  const float* b1 = (const float*)d_in[4];
  const float* w2 = (const float*)d_in[5];
  const float* b2 = (const float*)d_in[6];
  const float* gu = (const float*)d_in[7];

  float* out = (float*)d_out;
  float* padded = out;                                        // B*MAXG*NPAIR
  float* gm = out + (size_t)Bn * MAXGn * NPAIRn;              // B*T*T
  float* si = gm + (size_t)Bn * Tn * Tn;                      // B*T (real output)

  char* base = (char*)d_ws;
  float* oc = (float*)base;                                   // 90112
  float* Y = oc + 90112;                                      // 163328
  float* vecsbt = Y + 163328;                                 // 247808
  float* scales = vecsbt + 247808;                            // 1408
  int* gstart = (int*)(scales + 1408);                        // 1408
  int* gend = gstart + 1408;                                  // 1408
  int* ngr = gend + 1408;                                     // 8
  int* lut = ngr + 8;                                         // 13340
  int* iws = lut + 13340;                                     // 7040
  // bytes: (502656 f32 + 23204 i32)*4 = 2,103,440
  float* fws = (float*)(base + ((2103440 + 255) & ~255));     // 8*142560 f32 = 4,561,920 B

  k_conv<<<(Bn * Tn * Cn + 255) / 256, 256, 0, stream>>>(X, cw, cb, oc);
  k_lut<<<(NPAIRn + 255) / 256, 256, 0, stream>>>(lut);
  k_mlp<<<Bn * Tn, 256, 0, stream>>>(oc, w1, b1, w2, b2, gm);
  k_eigh2<<<Bn, 256, 0, stream>>>(gm, fws, iws, vecsbt, scales);
  k_softidx<<<Bn * Tn, 64, 0, stream>>>(vecsbt, scales, gu, si);
  k_prep<<<Bn, 256, 0, stream>>>(X, si, Y, gstart, gend, ngr);
  k_corr<<<Bn * MAXGn, 256, 0, stream>>>(Y, gstart, gend, ngr, lut, padded);
}

// Round 12
// 16463.144 us; speedup vs baseline: 1.5967x; 1.5967x over previous
//
#include <hip/hip_runtime.h>
#pragma clang fp contract(off)

#define Bn 8
#define Tn 176
#define Rn 116
#define Cn 64
#define Hn 200
#define NPAIRn 6670
#define MAXGn 176
#define TAUf 1e-4f
#define LD 176
#define LEAF 22
#define NT 512
#define FEPS 5.9604645e-08f
#define FEPS2 3.5527137e-15f
#define FSAFMIN 1.17549435e-38f

// ---------------- f32 LAPACK helpers ----------------
static __device__ __forceinline__ float f_sign(float a, float b) {
  return (b >= 0.0f) ? fabsf(a) : -fabsf(a);
}
static __device__ __forceinline__ float f_lapy2(float x, float y) {
  float xa = fabsf(x), ya = fabsf(y);
  float w = fmaxf(xa, ya), z = fminf(xa, ya);
  if (z == 0.0f) return w;
  float q = z / w;
  return w * sqrtf(1.0f + q * q);
}
static __device__ void f_lartg(float f, float g, float* c, float* s, float* r) {
  if (g == 0.0f) { *c = 1.0f; *s = 0.0f; *r = f; }
  else if (f == 0.0f) { *c = 0.0f; *s = (g >= 0.0f) ? 1.0f : -1.0f; *r = fabsf(g); }
  else {
    float d = sqrtf(f * f + g * g);
    float rr = (f >= 0.0f) ? d : -d;
    *c = f / rr; *s = g / rr; *r = rr;
  }
}
static __device__ float f_snrm2_strided(const float* x, int n, int stride) {
  float scale = 0.0f, ssq = 1.0f;
  for (int i = 0; i < n; i++) {
    float ax = fabsf(x[i * stride]);
    if (ax != 0.0f) {
      if (scale < ax) {
        float q = scale / ax;
        ssq = 1.0f + ssq * (q * q);
        scale = ax;
      } else {
        float q = ax / scale;
        ssq = ssq + q * q;
      }
    }
  }
  return scale * sqrtf(ssq);
}
static __device__ void f_laev2(float a, float b, float c,
                               float* rt1, float* rt2, float* cs1, float* sn1) {
  float sm = a + c, df = a - c, adf = fabsf(df), tb = b + b, ab = fabsf(tb);
  float acmx, acmn;
  if (fabsf(a) > fabsf(c)) { acmx = a; acmn = c; } else { acmx = c; acmn = a; }
  float rt;
  if (adf > ab) { float q = ab / adf; rt = adf * sqrtf(1.0f + q * q); }
  else if (adf < ab) { float q = adf / ab; rt = ab * sqrtf(1.0f + q * q); }
  else rt = ab * sqrtf(2.0f);
  int sgn1;
  if (sm < 0.0f) { *rt1 = 0.5f * (sm - rt); sgn1 = -1; *rt2 = (acmx / *rt1) * acmn - (b / *rt1) * b; }
  else if (sm > 0.0f) { *rt1 = 0.5f * (sm + rt); sgn1 = 1; *rt2 = (acmx / *rt1) * acmn - (b / *rt1) * b; }
  else { *rt1 = 0.5f * rt; *rt2 = -0.5f * rt; sgn1 = 1; }
  float cs; int sgn2;
  if (df >= 0.0f) { cs = df + rt; sgn2 = 1; } else { cs = df - rt; sgn2 = -1; }
  float acs = fabsf(cs);
  if (acs > ab) { float ct = -tb / cs; *sn1 = 1.0f / sqrtf(1.0f + ct * ct); *cs1 = ct * (*sn1); }
  else {
    if (ab == 0.0f) { *cs1 = 1.0f; *sn1 = 0.0f; }
    else { float tn = -cs / tb; *cs1 = 1.0f / sqrtf(1.0f + tn * tn); *sn1 = tn * (*cs1); }
  }
  if (sgn1 == sgn2) { float tn = *cs1; *cs1 = -(*sn1); *sn1 = tn; }
}
static __device__ void f_lamrg(int n1, int n2, const float* a, int dtrd1, int dtrd2, int* index) {
  int n1sv = n1, n2sv = n2;
  int ind1 = (dtrd1 > 0) ? 0 : n1 - 1;
  int ind2 = (dtrd2 > 0) ? n1 : n1 + n2 - 1;
  int i = 0;
  while (n1sv > 0 && n2sv > 0) {
    if (a[ind1] <= a[ind2]) { index[i++] = ind1; ind1 += dtrd1; n1sv--; }
    else { index[i++] = ind2; ind2 += dtrd2; n2sv--; }
  }
  while (n2sv > 0) { index[i++] = ind2; ind2 += dtrd2; n2sv--; }
  while (n1sv > 0) { index[i++] = ind1; ind1 += dtrd1; n1sv--; }
}
static __device__ void f_laed5(int i, const float* d, const float* z, float rho,
                               float* dlam, float* u0, float* u1) {
  float del = d[1] - d[0];
  float del1, del2;
  if (i == 0) {
    float w = 1.0f + 2.0f * rho * (z[1] * z[1] - z[0] * z[0]) / del;
    if (w > 0.0f) {
      float b = del + rho * (z[0] * z[0] + z[1] * z[1]);
      float c = rho * z[0] * z[0] * del;
      float tau = 2.0f * c / (b + sqrtf(fabsf(b * b - 4.0f * c)));
      *dlam = d[0] + tau;
      del1 = -z[0] / tau; del2 = z[1] / (del - tau);
    } else {
      float b = -del + rho * (z[0] * z[0] + z[1] * z[1]);
      float c = rho * z[1] * z[1] * del;
      float tau;
      if (b > 0.0f) tau = -2.0f * c / (b + sqrtf(b * b + 4.0f * c));
      else tau = (b - sqrtf(b * b + 4.0f * c)) / 2.0f;
      *dlam = d[1] + tau;
      del1 = -z[0] / (del + tau); del2 = -z[1] / tau;
    }
  } else {
    float b = -del + rho * (z[0] * z[0] + z[1] * z[1]);
    float c = rho * z[1] * z[1] * del;
    float tau;
    if (b > 0.0f) tau = (b + sqrtf(b * b + 4.0f * c)) / 2.0f;
    else tau = 2.0f * c / (-b + sqrtf(b * b + 4.0f * c));
    *dlam = d[1] + tau;
    del1 = -z[0] / (del + tau); del2 = -z[1] / tau;
  }
  float t = sqrtf(del1 * del1 + del2 * del2);
  *u0 = del1 / t; *u1 = del2 / t;
}

// ---------------- netlib slaed6 (f32) ----------------
static __device__ void laed6_net(int kniter, bool orgati, float rho, const float* dd,
                                 const float* zz, float finit, float* tau_out) {
  const float eps = FEPS;
  float lbd, ubd;
  if (orgati) { lbd = dd[1]; ubd = dd[2]; }
  else { lbd = dd[0]; ubd = dd[1]; }
  if (finit < 0.0f) lbd = 0.0f; else ubd = 0.0f;
  float tau = 0.0f;
  if (kniter == 2) {
    float temp, a, b, c;
    if (orgati) {
      temp = (dd[2] + dd[1]) / 2.0f;
      c = rho + zz[0] / ((dd[0] - dd[1]) - temp);
      a = c * (dd[1] + dd[2]) + zz[1] + zz[2];
      b = c * dd[1] * dd[2] + zz[1] * dd[2] + zz[2] * dd[1];
    } else {
      temp = (dd[0] + dd[1]) / 2.0f;
      c = rho + zz[2] / ((dd[2] - dd[1]) - temp);
      a = c * (dd[0] + dd[1]) + zz[0] + zz[1];
      b = c * dd[0] * dd[1] + zz[0] * dd[1] + zz[1] * dd[0];
    }
    temp = fmaxf(fmaxf(fabsf(a), fabsf(b)), fabsf(c));
    a /= temp; b /= temp; c /= temp;
    if (c == 0.0f) tau = b / a;
    else if (a <= 0.0f) tau = (a - sqrtf(fabsf(a * a - 4.0f * b * c))) / (2.0f * c);
    else tau = 2.0f * b / (a + sqrtf(fabsf(a * a - 4.0f * b * c)));
    if (tau < lbd || tau > ubd) tau = (lbd + ubd) / 2.0f;
    if (dd[0] == tau || dd[1] == tau || dd[2] == tau) {
      tau = 0.0f;
    } else {
      temp = finit + tau * zz[0] / (dd[0] * (dd[0] - tau))
                   + tau * zz[1] / (dd[1] * (dd[1] - tau))
                   + tau * zz[2] / (dd[2] * (dd[2] - tau));
      if (temp <= 0.0f) lbd = tau; else ubd = tau;
      if (fabsf(finit) <= fabsf(temp)) tau = 0.0f;
    }
  }
  const float small1 = 2.2737367544323206e-13f;
  const float sminv1 = 4398046511104.0f;
  const float small2 = small1 * small1;
  const float sminv2 = sminv1 * sminv1;
  float temp;
  if (orgati) temp = fminf(fabsf(dd[1] - tau), fabsf(dd[2] - tau));
  else temp = fminf(fabsf(dd[0] - tau), fabsf(dd[1] - tau));
  bool doscale = false;
  float sclfac = 1.0f, sclinv = 1.0f;
  float dscale[3], zscale[3];
  if (temp <= small1) {
    doscale = true;
    if (temp <= small2) { sclfac = sminv2; sclinv = small2; }
    else { sclfac = sminv1; sclinv = small1; }
    for (int i = 0; i < 3; i++) { dscale[i] = dd[i] * sclfac; zscale[i] = zz[i] * sclfac; }
    tau *= sclfac; lbd *= sclfac; ubd *= sclfac;
  } else {
    for (int i = 0; i < 3; i++) { dscale[i] = dd[i]; zscale[i] = zz[i]; }
  }
  float fc = 0.0f, df = 0.0f, ddf = 0.0f;
  for (int i = 0; i < 3; i++) {
    float t1 = 1.0f / (dscale[i] - tau);
    float t2 = zscale[i] * t1;
    float t3 = t2 * t1;
    float t4 = t3 * t1;
    fc += t2 / dscale[i];
    df += t3;
    ddf += t4;
  }
  float f = finit + tau * fc;
  if (fabsf(f) > 0.0f) {
    if (f <= 0.0f) lbd = tau; else ubd = tau;
    for (int niter = 2; niter <= 40; ++niter) {
      float t1_, t2_;
      if (orgati) { t1_ = dscale[1] - tau; t2_ = dscale[2] - tau; }
      else { t1_ = dscale[0] - tau; t2_ = dscale[1] - tau; }
      float a = (t1_ + t2_) * f - t1_ * t2_ * df;
      float b = t1_ * t2_ * f;
      float c = f - (t1_ + t2_) * df + t1_ * t2_ * ddf;
      float tm = fmaxf(fmaxf(fabsf(a), fabsf(b)), fabsf(c));
      a /= tm; b /= tm; c /= tm;
      float eta;
      if (c == 0.0f) eta = b / a;
      else if (a <= 0.0f) eta = (a - sqrtf(fabsf(a * a - 4.0f * b * c))) / (2.0f * c);
      else eta = 2.0f * b / (a + sqrtf(fabsf(a * a - 4.0f * b * c)));
      if (f * eta >= 0.0f) eta = -f / df;
      tau = tau + eta;
      if (tau < lbd || tau > ubd) tau = (lbd + ubd) / 2.0f;
      fc = 0.0f; df = 0.0f; ddf = 0.0f;
      float erretm = 0.0f;
      bool hitpole = false;
      for (int i = 0; i < 3; i++) {
        float dt = dscale[i] - tau;
        if (dt != 0.0f) {
          float t1 = 1.0f / dt;
          float t2 = zscale[i] * t1;
          float t3 = t2 * t1;
          float t4 = t3 * t1;
          float t5 = t2 / dscale[i];
          fc += t5;
          erretm += fabsf(t5);
          df += t3;
          ddf += t4;
        } else { hitpole = true; break; }
      }
      if (hitpole) break;
      f = finit + tau * fc;
      erretm = 8.0f * (fabsf(finit) + fabsf(tau) * erretm) + fabsf(tau) * df;
      if (fabsf(f) <= eps * erretm) break;
      if (f <= 0.0f) lbd = tau; else ubd = tau;
    }
  }
  if (doscale) tau *= sclinv;
  *tau_out = tau;
}

// ---------------- netlib slaed4 (f32); delta strided by LD ----------------
static __device__ void laed4_net(int K, int j0, const float* d, const float* z, float rho,
                                 float* dlam, float* delta) {
#define DL(i) delta[(size_t)(i) * LD]
  const float eps = FEPS;
  float rhoinv = 1.0f / rho;
  if (j0 == K - 1) {
    int ii = K - 2;
    float midpt = rho / 2.0f;
    for (int j = 0; j < K; j++) DL(j) = (d[j] - d[K - 1]) - midpt;
    float psi = 0.0f;
    for (int j = 0; j < K - 2; j++) psi += z[j] * z[j] / DL(j);
    float c = rhoinv + psi;
    float w = c + z[ii] * z[ii] / DL(ii) + z[K - 1] * z[K - 1] / DL(K - 1);
    float dltlb, dltub, tau;
    if (w <= 0.0f) {
      float temp = z[K - 2] * z[K - 2] / (d[K - 1] - d[K - 2] + rho) + z[K - 1] * z[K - 1] / rho;
      if (c <= temp) tau = rho;
      else {
        float del = d[K - 1] - d[K - 2];
        float a = -c * del + z[K - 2] * z[K - 2] + z[K - 1] * z[K - 1];
        float b = z[K - 1] * z[K - 1] * del;
        if (a < 0.0f) tau = 2.0f * b / (sqrtf(a * a + 4.0f * b * c) - a);
        else tau = (a + sqrtf(a * a + 4.0f * b * c)) / (2.0f * c);
      }
      dltlb = midpt; dltub = rho;
    } else {
      float del = d[K - 1] - d[K - 2];
      float a = -c * del + z[K - 2] * z[K - 2] + z[K - 1] * z[K - 1];
      float b = z[K - 1] * z[K - 1] * del;
      if (a < 0.0f) tau = 2.0f * b / (sqrtf(a * a + 4.0f * b * c) - a);
      else tau = (a + sqrtf(a * a + 4.0f * b * c)) / (2.0f * c);
      dltlb = 0.0f; dltub = midpt;
    }
    for (int j = 0; j < K; j++) DL(j) = (d[j] - d[K - 1]) - tau;
    float dpsi = 0.0f, erretm = 0.0f;
    psi = 0.0f;
    for (int j = 0; j <= ii; j++) {
      float t = z[j] / DL(j);
      psi += z[j] * t; dpsi += t * t; erretm += psi;
    }
    erretm = fabsf(erretm);
    float t = z[K - 1] / DL(K - 1);
    float phi = z[K - 1] * t, dphi = t * t;
    erretm = 8.0f * (-phi - psi) + erretm - phi + rhoinv + fabsf(tau) * (dpsi + dphi);
    w = rhoinv + phi + psi;
    if (fabsf(w) <= eps * erretm) { *dlam = d[K - 1] + tau; return; }
    if (w <= 0.0f) dltlb = fmaxf(dltlb, tau); else dltub = fminf(dltub, tau);
    for (int niter = 2; niter <= 30; ++niter) {
      float c2 = w - DL(K - 2) * dpsi - DL(K - 1) * dphi;
      float a = (DL(K - 2) + DL(K - 1)) * w - DL(K - 2) * DL(K - 1) * (dpsi + dphi);
      float b = DL(K - 2) * DL(K - 1) * w;
      float eta;
      if (niter == 2) {
        if (c2 < 0.0f) c2 = fabsf(c2);
        if (c2 == 0.0f) eta = dltub - tau;
        else if (a >= 0.0f) eta = (a + sqrtf(fabsf(a * a - 4.0f * b * c2))) / (2.0f * c2);
        else eta = 2.0f * b / (a - sqrtf(fabsf(a * a - 4.0f * b * c2)));
      } else {
        if (a >= 0.0f) eta = (a + sqrtf(fabsf(a * a - 4.0f * b * c2))) / (2.0f * c2);
        else eta = 2.0f * b / (a - sqrtf(fabsf(a * a - 4.0f * b * c2)));
      }
      if (w * eta > 0.0f) eta = -w / (dpsi + dphi);
      float tmp = tau + eta;
      if (tmp > dltub || tmp < dltlb) {
        if (w < 0.0f) eta = (dltub - tau) / 2.0f;
        else eta = (dltlb - tau) / 2.0f;
      }
      for (int j = 0; j < K; j++) DL(j) -= eta;
      tau += eta;
      dpsi = 0.0f; psi = 0.0f; erretm = 0.0f;
      for (int j = 0; j <= ii; j++) {
        float tt = z[j] / DL(j);
        psi += z[j] * tt; dpsi += tt * tt; erretm += psi;
      }
      erretm = fabsf(erretm);
      t = z[K - 1] / DL(K - 1);
      phi = z[K - 1] * t; dphi = t * t;
      erretm = 8.0f * (-phi - psi) + erretm - phi + rhoinv + fabsf(tau) * (dpsi + dphi);
      w = rhoinv + phi + psi;
      if (fabsf(w) <= eps * erretm) break;
      if (w <= 0.0f) dltlb = fmaxf(dltlb, tau); else dltub = fminf(dltub, tau);
    }
    *dlam = d[K - 1] + tau;
    return;
  }
  int ip1 = j0 + 1;
  float del = d[ip1] - d[j0];
  float midpt = del / 2.0f;
  for (int j = 0; j < K; j++) DL(j) = (d[j] - d[j0]) - midpt;
  float psi = 0.0f;
  for (int j = 0; j < j0; j++) psi += z[j] * z[j] / DL(j);
  float phi = 0.0f;
  for (int j = K - 1; j >= j0 + 2; j--) phi += z[j] * z[j] / DL(j);
  float c = rhoinv + psi + phi;
  float w = c + z[j0] * z[j0] / DL(j0) + z[ip1] * z[ip1] / DL(ip1);
  bool orgati;
  float tau, dltlb, dltub;
  if (w > 0.0f) {
    orgati = true;
    float a = c * del + z[j0] * z[j0] + z[ip1] * z[ip1];
    float b = z[j0] * z[j0] * del;
    if (a > 0.0f) tau = 2.0f * b / (a + sqrtf(fabsf(a * a - 4.0f * b * c)));
    else tau = (a - sqrtf(fabsf(a * a - 4.0f * b * c))) / (2.0f * c);
    dltlb = 0.0f; dltub = midpt;
  } else {
    orgati = false;
    float a = c * del - z[j0] * z[j0] - z[ip1] * z[ip1];
    float b = z[ip1] * z[ip1] * del;
    if (a < 0.0f) tau = 2.0f * b / (a - sqrtf(fabsf(a * a + 4.0f * b * c)));
    else tau = -(a + sqrtf(fabsf(a * a + 4.0f * b * c))) / (2.0f * c);
    dltlb = -midpt; dltub = 0.0f;
  }
  int org = orgati ? j0 : ip1;
  for (int j = 0; j < K; j++) DL(j) = (d[j] - d[org]) - tau;
  int ii = org;
  int iim1 = ii - 1, iip1 = ii + 1;
  float dpsi = 0.0f, erretm = 0.0f;
  psi = 0.0f;
  for (int j = 0; j <= ii - 1; j++) {
    float t = z[j] / DL(j);
    psi += z[j] * t; dpsi += t * t; erretm += psi;
  }
  erretm = fabsf(erretm);
  float dphi = 0.0f;
  phi = 0.0f;
  for (int j = K - 1; j >= ii + 1; j--) {
    float t = z[j] / DL(j);
    phi += z[j] * t; dphi += t * t; erretm += phi;
  }
  w = rhoinv + phi + psi;
  bool swtch3 = false;
  if (orgati) { if (w < 0.0f) swtch3 = true; }
  else { if (w > 0.0f) swtch3 = true; }
  if (ii == 0 || ii == K - 1) swtch3 = false;
  float t = z[ii] / DL(ii);
  float dw = dpsi + dphi + t * t;
  t = z[ii] * t;
  w += t;
  erretm = 8.0f * (phi - psi) + erretm + 2.0f * rhoinv + 3.0f * fabsf(t) + fabsf(tau) * dw;
  if (fabsf(w) <= eps * erretm) { *dlam = d[org] + tau; return; }
  if (w <= 0.0f) dltlb = fmaxf(dltlb, tau); else dltub = fminf(dltub, tau);
  float eta;
  {
    if (!swtch3) {
      float c2, a, b;
      if (orgati) {
        float q = z[j0] / DL(j0);
        c2 = w - DL(ip1) * dw - (d[j0] - d[ip1]) * (q * q);
      } else {
        float q = z[ip1] / DL(ip1);
        c2 = w - DL(j0) * dw - (d[ip1] - d[j0]) * (q * q);
      }
      a = (DL(j0) + DL(ip1)) * w - DL(j0) * DL(ip1) * dw;
      b = DL(j0) * DL(ip1) * w;
      if (c2 == 0.0f) {
        if (a == 0.0f) {
          if (orgati) a = z[j0] * z[j0] + DL(ip1) * DL(ip1) * (dpsi + dphi);
          else a = z[ip1] * z[ip1] + DL(j0) * DL(j0) * (dpsi + dphi);
        }
        eta = b / a;
      } else if (a <= 0.0f) eta = (a - sqrtf(fabsf(a * a - 4.0f * b * c2))) / (2.0f * c2);
      else eta = 2.0f * b / (a + sqrtf(fabsf(a * a - 4.0f * b * c2)));
    } else {
      float zz3[3], dd3[3];
      float temp = rhoinv + psi + phi;
      if (orgati) {
        float t1 = z[iim1] / DL(iim1);
        t1 = t1 * t1;
        float c2 = temp - DL(iip1) * (dpsi + dphi) - (d[iim1] - d[iip1]) * t1;
        zz3[0] = z[iim1] * z[iim1];
        zz3[2] = DL(iip1) * DL(iip1) * ((dpsi - t1) + dphi);
        zz3[1] = z[ii] * z[ii];
        dd3[0] = DL(iim1); dd3[1] = DL(ii); dd3[2] = DL(iip1);
        laed6_net(2, orgati, c2, dd3, zz3, w, &eta);
      } else {
        float t1 = z[iip1] / DL(iip1);
        t1 = t1 * t1;
        float c2 = temp - DL(iim1) * (dpsi + dphi) - (d[iip1] - d[iim1]) * t1;
        zz3[0] = DL(iim1) * DL(iim1) * (dpsi + (dphi - t1));
        zz3[2] = z[iip1] * z[iip1];
        zz3[1] = z[ii] * z[ii];
        dd3[0] = DL(iim1); dd3[1] = DL(ii); dd3[2] = DL(iip1);
        laed6_net(2, orgati, c2, dd3, zz3, w, &eta);
      }
    }
    if (w * eta >= 0.0f) eta = -w / dw;
    float tmp = tau + eta;
    if (tmp > dltub || tmp < dltlb) {
      if (w < 0.0f) eta = (dltub - tau) / 2.0f;
      else eta = (dltlb - tau) / 2.0f;
    }
  }
  float prew = w;
  for (int j = 0; j < K; j++) DL(j) -= eta;
  tau += eta;
  dpsi = 0.0f; psi = 0.0f; erretm = 0.0f;
  for (int j = 0; j <= ii - 1; j++) {
    float tt = z[j] / DL(j);
    psi += z[j] * tt; dpsi += tt * tt; erretm += psi;
  }
  erretm = fabsf(erretm);
  dphi = 0.0f; phi = 0.0f;
  for (int j = K - 1; j >= ii + 1; j--) {
    float tt = z[j] / DL(j);
    phi += z[j] * tt; dphi += tt * tt; erretm += phi;
  }
  w = rhoinv + phi + psi;
  t = z[ii] / DL(ii);
  dw = dpsi + dphi + t * t;
  t = z[ii] * t;
  w += t;
  erretm = 8.0f * (phi - psi) + erretm + 2.0f * rhoinv + 3.0f * fabsf(t) + fabsf(tau) * dw;
  bool swtch = false;
  if (orgati) { if (-w > fabsf(prew) / 10.0f) swtch = true; }
  else { if (w > fabsf(prew) / 10.0f) swtch = true; }
  for (int niter = 3; niter <= 30; ++niter) {
    if (fabsf(w) <= eps * erretm) break;
    if (w <= 0.0f) dltlb = fmaxf(dltlb, tau); else dltub = fminf(dltub, tau);
    if (!swtch3) {
      float c2, a, b;
      if (!swtch) {
        if (orgati) {
          float q = z[j0] / DL(j0);
          c2 = w - DL(ip1) * dw - (d[j0] - d[ip1]) * (q * q);
        } else {
          float q = z[ip1] / DL(ip1);
          c2 = w - DL(j0) * dw - (d[ip1] - d[j0]) * (q * q);
        }
      } else {
        float tt = z[ii] / DL(ii);
        if (orgati) dpsi += tt * tt;
        else dphi += tt * tt;
        c2 = w - DL(j0) * dpsi - DL(ip1) * dphi;
      }
      a = (DL(j0) + DL(ip1)) * w - DL(j0) * DL(ip1) * dw;
      b = DL(j0) * DL(ip1) * w;
      if (c2 == 0.0f) {
        if (a == 0.0f) {
          if (!swtch) {
            if (orgati) a = z[j0] * z[j0] + DL(ip1) * DL(ip1) * (dpsi + dphi);
            else a = z[ip1] * z[ip1] + DL(j0) * DL(j0) * (dpsi + dphi);
          } else a = DL(j0) * DL(j0) * dpsi + DL(ip1) * DL(ip1) * dphi;
        }
        eta = b / a;
      } else if (a <= 0.0f) eta = (a - sqrtf(fabsf(a * a - 4.0f * b * c2))) / (2.0f * c2);
      else eta = 2.0f * b / (a + sqrtf(fabsf(a * a - 4.0f * b * c2)));
    } else {
      float zz3[3], dd3[3];
      float t1 = rhoinv + psi + phi;
      if (swtch) {
        float c2 = t1 - DL(iim1) * dpsi - DL(iip1) * dphi;
        zz3[0] = DL(iim1) * DL(iim1) * dpsi;
        zz3[2] = DL(iip1) * DL(iip1) * dphi;
        zz3[1] = z[ii] * z[ii];
        dd3[0] = DL(iim1); dd3[1] = DL(ii); dd3[2] = DL(iip1);
        laed6_net(niter, orgati, c2, dd3, zz3, w, &eta);
      } else {
        if (orgati) {
          float t2 = z[iim1] / DL(iim1);
          t2 = t2 * t2;
          float c2 = t1 - DL(iip1) * (dpsi + dphi) - (d[iim1] - d[iip1]) * t2;
          zz3[0] = z[iim1] * z[iim1];
          zz3[2] = DL(iip1) * DL(iip1) * ((dpsi - t2) + dphi);
          zz3[1] = z[ii] * z[ii];
          dd3[0] = DL(iim1); dd3[1] = DL(ii); dd3[2] = DL(iip1);
          laed6_net(niter, orgati, c2, dd3, zz3, w, &eta);
        } else {
          float t2 = z[iip1] / DL(iip1);
          t2 = t2 * t2;
          float c2 = t1 - DL(iim1) * (dpsi + dphi) - (d[iip1] - d[iim1]) * t2;
          zz3[0] = DL(iim1) * DL(iim1) * (dpsi + (dphi - t2));
          zz3[2] = z[iip1] * z[iip1];
          zz3[1] = z[ii] * z[ii];
          dd3[0] = DL(iim1); dd3[1] = DL(ii); dd3[2] = DL(iip1);
          laed6_net(niter, orgati, c2, dd3, zz3, w, &eta);
        }
      }
    }
    if (w * eta >= 0.0f) eta = -w / dw;
    {
      float tmp = tau + eta;
      if (tmp > dltub || tmp < dltlb) {
        if (w < 0.0f) eta = (dltub - tau) / 2.0f;
        else eta = (dltlb - tau) / 2.0f;
      }
    }
    for (int j = 0; j < K; j++) DL(j) -= eta;
    tau += eta;
    prew = w;
    dpsi = 0.0f; psi = 0.0f; erretm = 0.0f;
    for (int j = 0; j <= ii - 1; j++) {
      float tt = z[j] / DL(j);
      psi += z[j] * tt; dpsi += tt * tt; erretm += psi;
    }
    erretm = fabsf(erretm);
    dphi = 0.0f; phi = 0.0f;
    for (int j = K - 1; j >= ii + 1; j--) {
      float tt = z[j] / DL(j);
      phi += z[j] * tt; dphi += tt * tt; erretm += phi;
    }
    w = rhoinv + phi + psi;
    t = z[ii] / DL(ii);
    dw = dpsi + dphi + t * t;
    t = z[ii] * t;
    w += t;
    erretm = 8.0f * (phi - psi) + erretm + 2.0f * rhoinv + 3.0f * fabsf(t) + fabsf(tau) * dw;
    if (w * prew > 0.0f && fabsf(w) > fabsf(prew) / 10.0f) swtch = !swtch;
  }
  *dlam = d[org] + tau;
#undef DL
}

// ---------------- ssteqr port, serial, f32 ----------------
static __device__ void steqr_f(int n, float* d, float* e, float* Z, int ldz) {
  if (n <= 1) return;
  float work_c[LEAF + 2], work_s[LEAF + 2];
  int nmaxit = n * 30, jtot = 0;
  int l1 = 0;
  while (true) {
    if (l1 > n - 1) break;
    if (l1 > 0) e[l1 - 1] = 0.0f;
    int m;
    for (m = l1; m <= n - 2; ++m) {
      float tst = fabsf(e[m]);
      if (tst == 0.0f) break;
      if (tst <= (sqrtf(fabsf(d[m])) * sqrtf(fabsf(d[m + 1]))) * FEPS) { e[m] = 0.0f; break; }
    }
    int l = l1, lend = m;
    l1 = m + 1;
    if (lend == l) continue;
    if (fabsf(d[lend]) < fabsf(d[l])) { int t = lend; lend = l; l = t; }
    if (lend > l) {
      while (true) {
        int mm;
        if (l != lend) {
          for (mm = l; mm <= lend - 1; ++mm) {
            float tst = fabsf(e[mm]); tst = tst * tst;
            if (tst <= (FEPS2 * fabsf(d[mm])) * fabsf(d[mm + 1]) + FSAFMIN) break;
          }
        } else mm = lend;
        if (mm < lend) e[mm] = 0.0f;
        float p = d[l];
        if (mm == l) { d[l] = p; l = l + 1; if (l <= lend) continue; else break; }
        if (mm == l + 1) {
          float rt1, rt2, c, s;
          f_laev2(d[l], e[l], d[l + 1], &rt1, &rt2, &c, &s);
          for (int r = 0; r < n; r++) {
            float t1 = Z[r * ldz + l + 1], t0 = Z[r * ldz + l];
            Z[r * ldz + l + 1] = c * t1 - s * t0;
            Z[r * ldz + l] = s * t1 + c * t0;
          }
          d[l] = rt1; d[l + 1] = rt2; e[l] = 0.0f;
          l += 2; if (l <= lend) continue; else break;
        }
        if (jtot == nmaxit) break;
        jtot++;
        float g = (d[l + 1] - p) / (2.0f * e[l]);
        float r = f_lapy2(g, 1.0f);
        g = d[mm] - p + e[l] / (g + f_sign(r, g));
        float s = 1.0f, c = 1.0f; p = 0.0f;
        for (int i = mm - 1; i >= l; --i) {
          float f = s * e[i], bb = c * e[i];
          f_lartg(g, f, &c, &s, &r);
          if (i != mm - 1) e[i + 1] = r;
          g = d[i + 1] - p;
          r = (d[i] - g) * s + 2.0f * c * bb;
          p = s * r;
          d[i + 1] = g + p;
          g = c * r - bb;
          work_c[i] = c; work_s[i] = -s;
        }
        for (int j = mm - l; j >= 1; --j) {
          float cj = work_c[l + j - 1], sj = work_s[l + j - 1];
          for (int rr = 0; rr < n; rr++) {
            float t1 = Z[rr * ldz + l + j], t0 = Z[rr * ldz + l + j - 1];
            Z[rr * ldz + l + j] = cj * t1 - sj * t0;
            Z[rr * ldz + l + j - 1] = sj * t1 + cj * t0;
          }
        }
        d[l] -= p; e[l] = g;
      }
    } else {
      while (true) {
        int mm;
        if (l != lend) {
          for (mm = l; mm >= lend + 1; --mm) {
            float tst = fabsf(e[mm - 1]); tst = tst * tst;
            if (tst <= (FEPS2 * fabsf(d[mm])) * fabsf(d[mm - 1]) + FSAFMIN) break;
          }
        } else mm = lend;
        if (mm > lend) e[mm - 1] = 0.0f;
        float p = d[l];
        if (mm == l) { d[l] = p; l = l - 1; if (l >= lend) continue; else break; }
        if (mm == l - 1) {
          float rt1, rt2, c, s;
          f_laev2(d[l - 1], e[l - 1], d[l], &rt1, &rt2, &c, &s);
          for (int r = 0; r < n; r++) {
            float t1 = Z[r * ldz + l], t0 = Z[r * ldz + l - 1];
            Z[r * ldz + l] = c * t1 - s * t0;
            Z[r * ldz + l - 1] = s * t1 + c * t0;
          }
          d[l - 1] = rt1; d[l] = rt2; e[l - 1] = 0.0f;
          l -= 2; if (l >= lend) continue; else break;
        }
        if (jtot == nmaxit) break;
        jtot++;
        float g = (d[l - 1] - p) / (2.0f * e[l - 1]);
        float r = f_lapy2(g, 1.0f);
        g = d[mm] - p + e[l - 1] / (g + f_sign(r, g));
        float s = 1.0f, c = 1.0f; p = 0.0f;
        for (int i = mm; i <= l - 1; ++i) {
          float f = s * e[i], bb = c * e[i];
          f_lartg(g, f, &c, &s, &r);
          if (i != mm) e[i - 1] = r;
          g = d[i] - p;
          r = (d[i + 1] - g) * s + 2.0f * c * bb;
          p = s * r;
          d[i] = g + p;
          g = c * r - bb;
          work_c[i] = c; work_s[i] = s;
        }
        for (int j = 1; j <= l - mm; ++j) {
          float cj = work_c[mm + j - 1], sj = work_s[mm + j - 1];
          for (int rr = 0; rr < n; rr++) {
            float t1 = Z[rr * ldz + mm + j], t0 = Z[rr * ldz + mm + j - 1];
            Z[rr * ldz + mm + j] = cj * t1 - sj * t0;
            Z[rr * ldz + mm + j - 1] = sj * t1 + cj * t0;
          }
        }
        d[l] -= p; e[l - 1] = g;
      }
    }
  }
  for (int ii = 1; ii < n; ++ii) {
    int i = ii - 1, k = i; float p = d[i];
    for (int j = ii; j < n; ++j) if (d[j] < p) { k = j; p = d[j]; }
    if (k != i) {
      d[k] = d[i]; d[i] = p;
      for (int r = 0; r < n; r++) { float t = Z[r * ldz + i]; Z[r * ldz + i] = Z[r * ldz + k]; Z[r * ldz + k] = t; }
    }
  }
}

// ---------------- slaed1/2/3-equivalent merge, f32 (FMA assembly) ----------------
static __device__ void laed1_f(int tid, int nb, int n1, int off, float rho_in,
    float* Zb, float* Qt, float* Um, float* dd,
    float* dlamda, float* w2, float* lamv, float* wtv, float* zv, float* dnew, float* dsort,
    int* indxq, int* indxp, int* indxc, int* indxm,
    float* shs, int* shi) {
  int n2 = nb - n1;
  if (tid == 0) {
    float rho = rho_in;
    for (int i = 0; i < n1; i++) zv[i] = Zb[(off + n1 - 1) * LD + off + i];
    for (int i = 0; i < n2; i++) zv[n1 + i] = Zb[(off + n1) * LD + off + n1 + i];
    if (rho < 0.0f) for (int i = n1; i < nb; i++) zv[i] = -zv[i];
    const float isq2 = 0.70710678118654752440f;
    for (int i = 0; i < nb; i++) zv[i] *= isq2;
    rho = fabsf(2.0f * rho);
    for (int i = n1; i < nb; i++) indxq[off + i] += n1;
    for (int i = 0; i < nb; i++) dsort[i] = dd[off + indxq[off + i]];
    f_lamrg(n1, n2, dsort, 1, 1, indxc);
    for (int i = 0; i < nb; i++) indxm[i] = indxq[off + indxc[i]];
    float zmax = 0.0f, dmax = 0.0f;
    for (int i = 0; i < nb; i++) {
      float az = fabsf(zv[i]); if (az > zmax) zmax = az;
      float ad = fabsf(dd[off + i]); if (ad > dmax) dmax = ad;
    }
    float tol = 8.0f * FEPS * ((dmax > zmax) ? dmax : zmax);
    int K = 0;
    if (rho * zmax <= tol) {
      for (int j = 0; j < nb; j++) indxp[j] = indxm[j];
    } else {
      int K2 = nb; int pj = 0; int j; bool found = false;
      for (j = 0; j < nb; j++) {
        int nj = indxm[j];
        if (rho * fabsf(zv[nj]) <= tol) { K2--; indxp[K2] = nj; if (j == nb - 1) break; }
        else { pj = nj; found = true; break; }
      }
      if (found) {
        while (true) {
          j++;
          if (j >= nb) break;
          int nj = indxm[j];
          if (rho * fabsf(zv[nj]) <= tol) { K2--; indxp[K2] = nj; }
          else {
            float s_ = zv[pj], c_ = zv[nj];
            float tau_ = f_lapy2(c_, s_);
            float t_ = dd[off + nj] - dd[off + pj];
            c_ /= tau_; s_ = -s_ / tau_;
            if (fabsf(t_ * c_ * s_) <= tol) {
              zv[nj] = tau_; zv[pj] = 0.0f;
              for (int r = 0; r < nb; r++) {
                float x = Zb[(off + r) * LD + off + pj], y = Zb[(off + r) * LD + off + nj];
                Zb[(off + r) * LD + off + pj] = c_ * x + s_ * y;
                Zb[(off + r) * LD + off + nj] = c_ * y - s_ * x;
              }
              float t2 = dd[off + pj] * c_ * c_ + dd[off + nj] * s_ * s_;
              dd[off + nj] = dd[off + pj] * s_ * s_ + dd[off + nj] * c_ * c_;
              dd[off + pj] = t2;
              K2--;
              int i_ = 1;
              while (true) {
                if (K2 + i_ < nb) {
                  if (dd[off + pj] < dd[off + indxp[K2 + i_]]) {
                    indxp[K2 + i_ - 1] = indxp[K2 + i_]; indxp[K2 + i_] = pj; i_++;
                  } else { indxp[K2 + i_ - 1] = pj; break; }
                } else { indxp[K2 + i_ - 1] = pj; break; }
              }
              pj = nj;
            } else {
              dlamda[K] = dd[off + pj]; w2[K] = zv[pj]; indxp[K] = pj; K++;
              pj = nj;
            }
          }
        }
        dlamda[K] = dd[off + pj]; w2[K] = zv[pj]; indxp[K] = pj; K++;
      }
    }
    shi[0] = K; shs[0] = rho;
  }
  __syncthreads();
  int K = shi[0]; float rho = shs[0];
  if (K == 0) {
    for (int idx = tid; idx < nb * nb; idx += NT) {
      int r = idx / nb, jj = idx - r * nb;
      Qt[r * LD + jj] = Zb[(off + r) * LD + off + indxp[jj]];
    }
    for (int jj = tid; jj < nb; jj += NT) dnew[jj] = dd[off + indxp[jj]];
    __syncthreads();
    for (int idx = tid; idx < nb * nb; idx += NT) {
      int r = idx / nb, jj = idx - r * nb;
      Zb[(off + r) * LD + off + jj] = Qt[r * LD + jj];
    }
    for (int jj = tid; jj < nb; jj += NT) { dd[off + jj] = dnew[jj]; indxq[off + jj] = jj; }
    __syncthreads();
    return;
  }
  if (K == 1) {
    if (tid == 0) { lamv[0] = dlamda[0] + rho * w2[0] * w2[0]; Um[0] = 1.0f; }
  } else if (K == 2) {
    if (tid < 2) {
      float u0, u1, dl_;
      f_laed5(tid, dlamda, w2, rho, &dl_, &u0, &u1);
      lamv[tid] = dl_; Um[0 * LD + tid] = u0; Um[1 * LD + tid] = u1;
    }
  } else {
    if (tid < K) laed4_net(K, tid, dlamda, w2, rho, &lamv[tid], &Um[tid]);
  }
  __syncthreads();
  if (K > 2) {
    if (tid < K) {
      int i = tid; float val = Um[i * LD + i];
      for (int j2 = 0; j2 < K; j2++) if (j2 != i) val *= Um[i * LD + j2] / (dlamda[i] - dlamda[j2]);
      wtv[i] = f_sign(sqrtf(fabsf(val)), w2[i]);
    }
    __syncthreads();
    if (tid < K) {
      int j2 = tid;
      for (int i = 0; i < K; i++) Um[i * LD + j2] = wtv[i] / Um[i * LD + j2];
      float nrm = f_snrm2_strided(&Um[j2], K, LD);
      for (int i = 0; i < K; i++) Um[i * LD + j2] /= nrm;
    }
    __syncthreads();
  }
  for (int idx = tid; idx < nb * K; idx += NT) {
    int r = idx / K, j2 = idx - r * K;
    float acc = 0.0f;
    for (int i = 0; i < K; i++) acc = fmaf(Zb[(off + r) * LD + off + indxp[i]], Um[i * LD + j2], acc);
    Qt[r * LD + j2] = acc;
  }
  int nd = nb - K;
  for (int idx = tid; idx < nb * nd; idx += NT) {
    int r = idx / nd, jj = idx - r * nd;
    Qt[r * LD + K + jj] = Zb[(off + r) * LD + off + indxp[K + jj]];
  }
  for (int jj = tid; jj < nb; jj += NT) dnew[jj] = (jj < K) ? lamv[jj] : dd[off + indxp[jj]];
  __syncthreads();
  for (int idx = tid; idx < nb * nb; idx += NT) {
    int r = idx / nb, jj = idx - r * nb;
    Zb[(off + r) * LD + off + jj] = Qt[r * LD + jj];
  }
  for (int jj = tid; jj < nb; jj += NT) dd[off + jj] = dnew[jj];
  __syncthreads();
  if (tid == 0) f_lamrg(K, nb - K, dnew, 1, -1, indxq + off);
  __syncthreads();
}

#define FSTR 109824
// ---------------- ssyevd-clone kernel (f32): A + scalars in LDS; 512 threads; leaf steqr wave-split ----------------
__global__ __launch_bounds__(NT) void k_eigh2(const float* __restrict__ gm,
    float* __restrict__ fws,
    float* __restrict__ vecsbt, float* __restrict__ scales) {
  int b = blockIdx.x, tid = threadIdx.x;
  extern __shared__ char dynsm[];
  float* A = (float*)dynsm;              // 30976 f32 (124 KB) in LDS
  float* sm1 = A + 30976;                // 1760 f32 scalar arrays in LDS
  int* ib_ = (int*)(sm1 + 1760);         // 880 i32 index arrays in LDS
  float* Zb = fws + (size_t)b * FSTR;    // global
  float* Qt = Zb + 30976;
  float* Um = Qt + 30976;
  float* Wp = Um + 30976;                // [176*32]
  float* Wa = Wp + 5632;
  float* Wb = Wa + 5632;
  float* dd = sm1;
  float* ee = sm1 + 176;
  float* tauv = sm1 + 352;
  float* dlamda = sm1 + 528;
  float* w2 = sm1 + 704;
  float* lamv = sm1 + 880;
  float* wtv = sm1 + 1056;
  float* zv = sm1 + 1232;
  float* dnew = sm1 + 1408;
  float* dsort = sm1 + 1584;
  int* indxq = ib_;
  int* indxp = ib_ + 176;
  int* indxc = ib_ + 352;
  int* indxm = ib_ + 528;
  __shared__ float shv[176];
  __shared__ float shs[2];
  __shared__ int shi[2];
  __shared__ float t12[64];
  __shared__ float Tm[1024];
  for (int i = tid; i < Tn * Tn; i += NT)
    A[(i / Tn) * LD + (i % Tn)] = gm[(size_t)b * Tn * Tn + i];
  __syncthreads();
  // ======== blocked SSYTRD (lower), NB=32, panels 0,32,64,96,128; ssytd2 tail 160.. ========
  for (int i0 = 0; i0 < Tn - 32; i0 += 32) {
    for (int i = 0; i < 32; i++) {
      int g = i0 + i;
      if (i > 0) {
        for (int r = g + tid; r < Tn; r += NT) {
          float acc = A[r * LD + g];
          for (int k = 0; k < i; k++) acc = fmaf(-Wp[g * 32 + k], A[r * LD + (i0 + k)], acc);
          for (int k = 0; k < i; k++) acc = fmaf(-A[g * LD + (i0 + k)], Wp[r * 32 + k], acc);
          A[r * LD + g] = acc;
        }
        __syncthreads();
      }
      if (tid == 0) {
        float scale = 0.0f, ssq = 1.0f;
        for (int r = g + 2; r < Tn; r++) {
          float ax = fabsf(A[r * LD + g]);
          if (ax != 0.0f) {
            if (scale < ax) { float q = scale / ax; ssq = 1.0f + ssq * (q * q); scale = ax; }
            else { float q = ax / scale; ssq = ssq + q * q; }
          }
        }
        float xnorm = scale * sqrtf(ssq);
        float alpha = A[(g + 1) * LD + g];
        float taui = 0.0f, scal = 0.0f;
        if (xnorm == 0.0f) { ee[g] = alpha; }
        else {
          float beta = -f_sign(f_lapy2(alpha, xnorm), alpha);
          taui = (beta - alpha) / beta;
          scal = 1.0f / (alpha - beta);
          ee[g] = beta;
        }
        tauv[g] = taui; shs[0] = taui; shs[1] = scal;
      }
      __syncthreads();
      float taui = shs[0];
      if (taui != 0.0f) {
        float scal = shs[1];
        for (int r = g + 2 + tid; r < Tn; r += NT) A[r * LD + g] *= scal;
      }
      __syncthreads();
      if (tid == 0) A[(g + 1) * LD + g] = 1.0f;
      __syncthreads();
      for (int r = g + 1 + tid; r < Tn; r += NT) {
        float acc = 0.0f;
        for (int c = g + 1; c < r; c++) acc = fmaf(A[c * LD + g], A[r * LD + c], acc);
        acc = fmaf(A[r * LD + g], A[r * LD + r], acc);
        float temp2 = 0.0f;
        for (int k = r + 1; k < Tn; k++) temp2 = fmaf(A[k * LD + r], A[k * LD + g], temp2);
        acc += temp2;
        shv[r] = acc;
      }
      __syncthreads();
      if (i > 0) {
        if (tid < i) {
          int k = tid;
          float acc = 0.0f;
          for (int r = g + 1; r < Tn; r++) acc = fmaf(Wp[r * 32 + k], A[r * LD + g], acc);
          t12[k] = acc;
        }
        __syncthreads();
        for (int r = g + 1 + tid; r < Tn; r += NT) {
          float acc = shv[r];
          for (int k = 0; k < i; k++) acc = fmaf(-t12[k], A[r * LD + (i0 + k)], acc);
          shv[r] = acc;
        }
        __syncthreads();
        if (tid < i) {
          int k = tid;
          float acc = 0.0f;
          for (int r = g + 1; r < Tn; r++) acc = fmaf(A[r * LD + (i0 + k)], A[r * LD + g], acc);
          t12[32 + k] = acc;
        }
        __syncthreads();
        for (int r = g + 1 + tid; r < Tn; r += NT) {
          float acc = shv[r];
          for (int k = 0; k < i; k++) acc = fmaf(-t12[32 + k], Wp[r * 32 + k], acc);
          shv[r] = acc;
        }
        __syncthreads();
      }
      for (int r = g + 1 + tid; r < Tn; r += NT) shv[r] = taui * shv[r];
      __syncthreads();
      if (tid == 0) {
        float dot = 0.0f;
        for (int r = g + 1; r < Tn; r++) dot = fmaf(shv[r], A[r * LD + g], dot);
        shs[0] = -0.5f * taui * dot;
      }
      __syncthreads();
      float alf = shs[0];
      for (int r = g + 1 + tid; r < Tn; r += NT) Wp[r * 32 + i] = fmaf(alf, A[r * LD + g], shv[r]);
      __syncthreads();
    }
    {
      int base2 = i0 + 32;
      int nt = Tn - base2;
      int npr = nt * (nt + 1) / 2;
      for (int p = tid; p < npr; p += NT) {
        int rr = (int)((sqrtf(8.0f * (float)p + 1.0f) - 1.0f) * 0.5f);
        while ((rr + 1) * (rr + 2) / 2 <= p) rr++;
        while (rr * (rr + 1) / 2 > p) rr--;
        int cc = p - rr * (rr + 1) / 2;
        int r = base2 + rr, c = base2 + cc;
        float acc = A[r * LD + c];
        for (int L = 0; L < 32; L++) {
          acc = fmaf(A[r * LD + (i0 + L)], -Wp[c * 32 + L], acc);
          acc = fmaf(Wp[r * 32 + L], -A[c * LD + (i0 + L)], acc);
        }
        A[r * LD + c] = acc;
        if (r != c) A[c * LD + r] = acc;
      }
      __syncthreads();
      if (tid < 32) {
        int g2 = i0 + tid;
        A[(g2 + 1) * LD + g2] = ee[g2];
      }
      __syncthreads();
    }
  }
  // ---- final ssytd2 on trailing 16 (cols 160..174) ----
  for (int i = 160; i < Tn - 1; i++) {
    if (tid == 0) {
      float scale = 0.0f, ssq = 1.0f;
      for (int r = i + 2; r < Tn; r++) {
        float ax = fabsf(A[r * LD + i]);
        if (ax != 0.0f) {
          if (scale < ax) { float q = scale / ax; ssq = 1.0f + ssq * (q * q); scale = ax; }
          else { float q = ax / scale; ssq = ssq + q * q; }
        }
      }
      float xnorm = scale * sqrtf(ssq);
      float alpha = A[(i + 1) * LD + i];
      float taui = 0.0f, scal = 0.0f;
      if (xnorm == 0.0f) { ee[i] = alpha; }
      else {
        float beta = -f_sign(f_lapy2(alpha, xnorm), alpha);
        taui = (beta - alpha) / beta;
        scal = 1.0f / (alpha - beta);
        ee[i] = beta;
      }
      tauv[i] = taui; shs[0] = taui; shs[1] = scal;
    }
    __syncthreads();
    float taui = shs[0];
    if (taui != 0.0f) {
      float scal = shs[1];
      for (int r = i + 2 + tid; r < Tn; r += NT) A[r * LD + i] *= scal;
      __syncthreads();
      for (int r = i + 1 + tid; r < Tn; r += NT) {
        float acc = 0.0f;
        for (int c = i + 1; c < r; c++) {
          float vc = (c == i + 1) ? 1.0f : A[c * LD + i];
          acc = fmaf(taui * vc, A[r * LD + c], acc);
        }
        float vr = (r == i + 1) ? 1.0f : A[r * LD + i];
        acc = fmaf(taui * vr, A[r * LD + r], acc);
        float temp2 = 0.0f;
        for (int k = r + 1; k < Tn; k++) temp2 = fmaf(A[k * LD + r], A[k * LD + i], temp2);
        acc = fmaf(taui, temp2, acc);
        shv[r] = acc;
      }
      __syncthreads();
      if (tid == 0) {
        float dot = 0.0f;
        for (int r = i + 1; r < Tn; r++) {
          float vr = (r == i + 1) ? 1.0f : A[r * LD + i];
          dot = fmaf(vr, shv[r], dot);
        }
        shs[0] = -0.5f * taui * dot;
      }
      __syncthreads();
      float alpha2 = shs[0];
      for (int r = i + 1 + tid; r < Tn; r += NT) {
        float vr = (r == i + 1) ? 1.0f : A[r * LD + i];
        shv[r] = fmaf(alpha2, vr, shv[r]);
      }
      __syncthreads();
      int m2 = Tn - 1 - i;
      int npairs = m2 * (m2 + 1) / 2;
      for (int p = tid; p < npairs; p += NT) {
        int rr = (int)((sqrtf(8.0f * (float)p + 1.0f) - 1.0f) * 0.5f);
        while ((rr + 1) * (rr + 2) / 2 <= p) rr++;
        while (rr * (rr + 1) / 2 > p) rr--;
        int cc = p - rr * (rr + 1) / 2;
        int r = i + 1 + rr, c = i + 1 + cc;
        float vr = (r == i + 1) ? 1.0f : A[r * LD + i];
        float vc = (c == i + 1) ? 1.0f : A[c * LD + i];
        float val = A[r * LD + c];
        val = fmaf(vr, -shv[c], val);
        val = fmaf(shv[r], -vc, val);
        A[r * LD + c] = val;
      }
      __syncthreads();
    }
  }
  for (int i = tid; i < Tn; i += NT) dd[i] = A[i * LD + i];
  __syncthreads();
  // ======== sstedc ========
  if (tid == 0) {
    float on = 0.0f;
    for (int i = 0; i < Tn; i++) { float v = fabsf(dd[i]); if (v > on) on = v; }
    for (int i = 0; i < Tn - 1; i++) { float v = fabsf(ee[i]); if (v > on) on = v; }
    shs[0] = (on > 0.0f) ? on : 1.0f;
  }
  __syncthreads();
  float orgnrm = shs[0];
  for (int i = tid; i < Tn; i += NT) dd[i] /= orgnrm;
  for (int i = tid; i < Tn - 1; i += NT) ee[i] /= orgnrm;
  for (int i = tid; i < Tn * Tn; i += NT)
    Zb[(i / Tn) * LD + (i % Tn)] = ((i / Tn) == (i % Tn)) ? 1.0f : 0.0f;
  __syncthreads();
  if (tid == 0) {
    for (int c = LEAF; c < Tn; c += LEAF) { dd[c - 1] -= fabsf(ee[c - 1]); dd[c] -= fabsf(ee[c - 1]); }
  }
  __syncthreads();
  // leaf steqr: one leaf per WAVE (lane 0 of waves 0..7) -> divergent serial paths run concurrently
  if ((tid & 63) == 0 && (tid >> 6) < 8) {
    int lf = tid >> 6;
    steqr_f(LEAF, dd + LEAF * lf, ee + LEAF * lf,
            Zb + (size_t)(LEAF * lf) * LD + LEAF * lf, LD);
  }
  __syncthreads();
  for (int i = tid; i < Tn; i += NT) indxq[i] = i % LEAF;
  __syncthreads();
  for (int nb = 2 * LEAF; nb <= Tn; nb *= 2) {
    for (int off = 0; off < Tn; off += nb) {
      laed1_f(tid, nb, nb / 2, off, ee[off + nb / 2 - 1],
              Zb, Qt, Um, dd, dlamda, w2, lamv, wtv, zv, dnew, dsort,
              indxq, indxp, indxc, indxm, shs, shi);
    }
  }
  for (int idx = tid; idx < Tn * Tn; idx += NT) {
    int r = idx / Tn, j = idx % Tn;
    Qt[r * LD + j] = Zb[r * LD + indxq[j]];
  }
  for (int j = tid; j < Tn; j += NT) dnew[j] = dd[indxq[j]];
  __syncthreads();
  for (int idx = tid; idx < Tn * Tn; idx += NT) {
    int r = idx / Tn, j = idx % Tn;
    Zb[r * LD + j] = Qt[r * LD + j];
  }
  for (int j = tid; j < Tn; j += NT) dd[j] = dnew[j] * orgnrm;
  __syncthreads();
  // ======== blocked SORMQR back-transform (FMA) ========
  for (int bi = 0; bi < 6; bi++) {
    int s = (bi == 0) ? 160 : (128 - (bi - 1) * 32);
    int ibk = (bi == 0) ? 15 : 32;
    for (int i2 = 0; i2 < ibk; i2++) {
      float ti = tauv[s + i2];
      if (tid < i2) {
        int j2 = tid;
        float acc = 0.0f;
        for (int r = s + i2; r <= Tn - 2; r++) {
          float vj = (r == s + j2) ? 1.0f : A[(r + 1) * LD + (s + j2)];
          float vi = (r == s + i2) ? 1.0f : A[(r + 1) * LD + (s + i2)];
          acc = fmaf(vj, vi, acc);
        }
        Tm[j2 * 32 + i2] = (ti == 0.0f) ? 0.0f : (-ti) * acc;
      }
      __syncthreads();
      if (tid == 0) {
        if (ti != 0.0f) {
          for (int J = 0; J < i2; J++) {
            float tmp = Tm[J * 32 + i2];
            if (tmp != 0.0f) {
              for (int I2 = 0; I2 < J; I2++) Tm[I2 * 32 + i2] = fmaf(tmp, Tm[I2 * 32 + J], Tm[I2 * 32 + i2]);
              Tm[J * 32 + i2] = tmp * Tm[J * 32 + J];
            }
          }
        }
        Tm[i2 * 32 + i2] = ti;
      }
      __syncthreads();
    }
    int c2r0 = s + ibk + 1;
    int nc2 = Tn - c2r0;
    for (int e = tid; e < Tn * ibk; e += NT) {
      int c = e / ibk, j = e - (e / ibk) * ibk;
      float acc = Zb[(s + 1 + j) * LD + c];
      for (int k = j + 1; k < ibk; k++) {
        float v1 = A[(s + 1 + k) * LD + (s + j)];
        acc = fmaf(v1, Zb[(s + 1 + k) * LD + c], acc);
      }
      Wb[c * 32 + j] = acc;
    }
    __syncthreads();
    if (nc2 > 0) {
      for (int e = tid; e < Tn * ibk; e += NT) {
        int c = e / ibk, j = e - (e / ibk) * ibk;
        float acc = 0.0f;
        for (int rr = 0; rr < nc2; rr++)
          acc = fmaf(Zb[(c2r0 + rr) * LD + c], A[(c2r0 + rr) * LD + (s + j)], acc);
        Wb[c * 32 + j] = acc + Wb[c * 32 + j];
      }
      __syncthreads();
    }
    for (int e = tid; e < Tn * ibk; e += NT) {
      int c = e / ibk, j = e - (e / ibk) * ibk;
      float acc = Tm[j * 32 + j] * Wb[c * 32 + j];
      for (int K = j + 1; K < ibk; K++) acc = fmaf(Tm[j * 32 + K], Wb[c * 32 + K], acc);
      Wa[c * 32 + j] = acc;
    }
    __syncthreads();
    if (nc2 > 0) {
      for (int e = tid; e < nc2 * Tn; e += NT) {
        int rr = e / Tn, c = e - (e / Tn) * Tn;
        float cv = Zb[(c2r0 + rr) * LD + c];
        for (int j = 0; j < ibk; j++)
          cv = fmaf(-Wa[c * 32 + j], A[(c2r0 + rr) * LD + (s + j)], cv);
        Zb[(c2r0 + rr) * LD + c] = cv;
      }
      __syncthreads();
    }
    for (int e = tid; e < Tn * ibk; e += NT) {
      int c = e / ibk, j = e - (e / ibk) * ibk;
      float acc = Wa[c * 32 + j];
      for (int K = j - 1; K >= 0; K--) {
        float v1 = A[(s + 1 + j) * LD + (s + K)];
        acc = fmaf(v1, Wa[c * 32 + K], acc);
      }
      Wb[c * 32 + j] = acc;
    }
    __syncthreads();
    for (int e = tid; e < ibk * Tn; e += NT) {
      int j = e / Tn, c = e - (e / Tn) * Tn;
      Zb[(s + 1 + j) * LD + c] = Zb[(s + 1 + j) * LD + c] - Wb[c * 32 + j];
    }
    __syncthreads();
  }
  // ---- outputs ----
  for (int idx = tid; idx < Tn * Tn; idx += NT) {
    int t = idx / Tn, j = idx % Tn;
    vecsbt[((size_t)b * Tn + t) * Tn + j] = Zb[t * LD + j];
  }
  for (int j = tid; j < Tn; j += NT) {
    float vd = dd[Tn - 1 - j];
    if (vd <= 0.f) vd = 1e-7f;
    scales[b * Tn + j] = sqrtf(vd) * 1000.f;
  }
}

// ---------------- conv ----------------
__global__ void k_conv(const float* __restrict__ X, const float* __restrict__ cw,
                       const float* __restrict__ cb, float* __restrict__ oc) {
  int idx = blockIdx.x * 256 + threadIdx.x;
  if (idx >= Bn * Tn * Cn) return;
  int c = idx & (Cn - 1);
  int bt = idx >> 6;
  const float* xr = X + bt * Rn;
  const float* wr = cw + c * Rn;
  float acc = cb[c];
#pragma unroll 4
  for (int r = 0; r < Rn; ++r) acc = fmaf(xr[r], wr[r], acc);
  oc[idx] = acc;
}

// ---------------- pairwise MLP -> grouping_M ----------------
__global__ __launch_bounds__(256) void k_mlp(const float* __restrict__ oc,
        const float* __restrict__ w1, const float* __restrict__ b1,
        const float* __restrict__ w2, const float* __restrict__ b2,
        float* __restrict__ gm) {
  __shared__ float xw[4 * 8];
  int tid = threadIdx.x;
  int lane = tid & 63, wv = tid >> 6;
  int b = blockIdx.x / Tn, t = blockIdx.x % Tn;
  bool active = (tid < Hn);
  float w1r[64];
  if (active) {
    const float4* wrow = reinterpret_cast<const float4*>(w1 + tid * Cn);
#pragma unroll
    for (int i = 0; i < 16; ++i) {
      float4 v = wrow[i];
      w1r[4 * i] = v.x; w1r[4 * i + 1] = v.y; w1r[4 * i + 2] = v.z; w1r[4 * i + 3] = v.w;
    }
  } else {
#pragma unroll
    for (int i = 0; i < 64; ++i) w1r[i] = 0.f;
  }
  float myb1 = active ? b1[tid] : 0.f;
  float myw2 = active ? w2[tid] : 0.f;
  float b2v = b2[0];
  float outt = oc[(b * Tn + t) * Cn + lane];
  for (int s0 = 0; s0 < Tn; s0 += 8) {
    float dj[8];
#pragma unroll
    for (int j = 0; j < 8; ++j) {
      float o = oc[(b * Tn + s0 + j) * Cn + lane];
      float d = outt - o;
      dj[j] = sqrtf(d * d + 1e-9f);
    }
    float acc[8];
#pragma unroll
    for (int j = 0; j < 8; ++j) acc[j] = myb1;
#pragma unroll
    for (int c = 0; c < 64; ++c) {
      float wv1 = w1r[c];
#pragma unroll
      for (int j = 0; j < 8; ++j) {
        float dv = __int_as_float(__builtin_amdgcn_readlane(__float_as_int(dj[j]), c));
        acc[j] = fmaf(dv, wv1, acc[j]);
      }
    }
#pragma unroll
    for (int j = 0; j < 8; ++j) {
      float v = fmaxf(acc[j], 0.f) * myw2;
#pragma unroll
      for (int off = 32; off; off >>= 1) v += __shfl_xor(v, off);
      acc[j] = v;
    }
    if (lane == 0) {
#pragma unroll
      for (int j = 0; j < 8; ++j) xw[wv * 8 + j] = acc[j];
    }
    __syncthreads();
    if (tid < 8) {
      float sum = xw[tid] + xw[8 + tid] + xw[16 + tid] + xw[24 + tid] + b2v;
      float cl = 1.f / (1.f + expf(-sum));
      int s = s0 + tid;
      gm[(b * Tn + t) * Tn + s] = (s == t) ? 1.f : cl;
    }
    __syncthreads();
  }
}

// ---------------- soft indices ----------------
__global__ __launch_bounds__(64) void k_softidx(const float* __restrict__ vecsbt,
        const float* __restrict__ scales, const float* __restrict__ gumbel,
        float* __restrict__ si) {
  int bt = blockIdx.x;
  int b = bt / Tn;
  int lane = threadIdx.x;
  const float* vr = vecsbt + (size_t)bt * Tn;
  const float* sc = scales + b * Tn;
  const float* gr = gumbel + (size_t)bt * Tn;
  float y[3];
  float m = -3.0e38f;
#pragma unroll
  for (int u = 0; u < 3; ++u) {
    int j = lane + 64 * u;
    float v = -3.0e38f;
    if (j < Tn) v = (vr[j] * sc[j] + gr[j]) / TAUf;
    y[u] = v;
    m = fmaxf(m, v);
  }
#pragma unroll
  for (int off = 32; off; off >>= 1) m = fmaxf(m, __shfl_xor(m, off));
  float num = 0.f, den = 0.f;
#pragma unroll
  for (int u = 0; u < 3; ++u) {
    int j = lane + 64 * u;
    if (j < Tn) {
      float e = expf(y[u] - m);
      num = fmaf((float)j, e, num);
      den += e;
    }
  }
#pragma unroll
  for (int off = 32; off; off >>= 1) { num += __shfl_xor(num, off); den += __shfl_xor(den, off); }
  if (lane == 0) si[bt] = num / den;
}

// ---------------- grouping prep ----------------
__global__ void k_prep(const float* __restrict__ X, const float* __restrict__ si,
                       float* __restrict__ Y, int* __restrict__ gstart, int* __restrict__ gend,
                       int* __restrict__ ngr) {
  __shared__ int sgid[Tn];
  __shared__ float swt[Tn];
  int b = blockIdx.x, tid = threadIdx.x;
  const float* idx = si + b * Tn;
  if (tid == 0) {
    int g = 0;
    for (int t2 = 0; t2 < Tn; ++t2) {
      if (t2 > 0 && idx[t2] != idx[t2 - 1]) g++;
      sgid[t2] = g;
    }
    ngr[b] = g + 1;
  }
  if (tid < Tn) {
    float x = idx[tid] + 1.f;
    swt[tid] = x * (1.f / x);
  }
  __syncthreads();
  if (tid < Tn) {
    int g = sgid[tid];
    if (tid == 0 || sgid[tid - 1] != g) gstart[b * Tn + g] = tid;
    if (tid == Tn - 1 || sgid[tid + 1] != g) gend[b * Tn + g] = tid + 1;
  }
  for (int e = tid; e < Tn * Rn; e += 256) {
    int t2 = e / Rn;
    Y[(size_t)b * Tn * Rn + e] = X[(size_t)b * Tn * Rn + e] * swt[t2];
  }
}

// ---------------- pair LUT ----------------
__global__ void k_lut(int* __restrict__ lut) {
  int k = blockIdx.x * 256 + threadIdx.x;
  if (k >= NPAIRn) return;
  int r = 0, rem = k;
  while (rem >= Rn - 1 - r) { rem -= Rn - 1 - r; r++; }
  lut[2 * k] = r;
  lut[2 * k + 1] = r + 1 + rem;
}

// ---------------- per-(b,g) correlations -> padded ----------------
__global__ __launch_bounds__(256) void k_corr(const float* __restrict__ Y,
        const int* __restrict__ gstart, const int* __restrict__ gend,
        const int* __restrict__ ngr, const int* __restrict__ lut,
        float* __restrict__ pad) {
  int b = blockIdx.x / MAXGn, g = blockIdx.x % MAXGn;
  float* out = pad + (size_t)(b * MAXGn + g) * NPAIRn;
  int tid = threadIdx.x;
  if (g >= ngr[b]) {
    for (int k = tid; k < NPAIRn; k += 256) out[k] = 0.f;
    return;
  }
  __shared__ float Sg[Rn], Dg[Rn];
  int t0 = gstart[b * Tn + g], t1 = gend[b * Tn + g];
  const float* Yb = Y + (size_t)b * Tn * Rn;
  const float invT = 1.f / (float)Tn;
  if (tid < Rn) {
    float s = 0.f, p = 0.f;
    for (int t2 = t0; t2 < t1; ++t2) {
      float v = Yb[t2 * Rn + tid];
      s += v;
      p = fmaf(v, v, p);
    }
    Sg[tid] = s;
    Dg[tid] = fmaxf(p - s * s * invT, 0.f);
  }
  __syncthreads();
  for (int k = tid; k < NPAIRn; k += 256) {
    int r = lut[2 * k], sc = lut[2 * k + 1];
    float p = 0.f;
    for (int t2 = t0; t2 < t1; ++t2)
      p = fmaf(Yb[t2 * Rn + r], Yb[t2 * Rn + sc], p);
    float cov = p - Sg[r] * Sg[sc] * invT;
    float den = sqrtf(Dg[r] * Dg[sc]);
    float co = cov / ((den > 0.f) ? den : 1.f);
    co = fminf(fmaxf(co, -1.f), 1.f);
    out[k] = co;
  }
}

extern "C" void kernel_launch(void* const* d_in, const int* in_sizes, int n_in,
                              void* d_out, int out_size, void* d_ws, size_t ws_size,
                              hipStream_t stream) {
  const float* X  = (const float*)d_in[0];
  const float* cw = (const float*)d_in[1];
  const float* cb = (const float*)d_in[2];
  const float* w1 = (const float*)d_in[3];
  const float* b1 = (const float*)d_in[4];
  const float* w2 = (const float*)d_in[5];
  const float* b2 = (const float*)d_in[6];
  const float* gu = (const float*)d_in[7];

  float* out = (float*)d_out;
  float* padded = out;                                        // B*MAXG*NPAIR
  float* gm = out + (size_t)Bn * MAXGn * NPAIRn;              // B*T*T
  float* si = gm + (size_t)Bn * Tn * Tn;                      // B*T (real output)

  char* base = (char*)d_ws;
  float* oc = (float*)base;                                   // 90112
  float* Y = oc + 90112;                                      // 163328
  float* vecsbt = Y + 163328;                                 // 247808
  float* scales = vecsbt + 247808;                            // 1408
  int* gstart = (int*)(scales + 1408);                        // 1408
  int* gend = gstart + 1408;                                  // 1408
  int* ngr = gend + 1408;                                     // 8
  int* lut = ngr + 8;                                         // 13340
  // bytes: (502656 f32 + 16164 i32)*4 = 2,075,280
  float* fws = (float*)(base + ((2075280 + 255) & ~255));     // 8*109824 f32 = 3,514,368 B

  size_t eigh_lds = (size_t)(30976 + 1760) * 4 + 880 * 4;     // 134,464 B dynamic

  k_conv<<<(Bn * Tn * Cn + 255) / 256, 256, 0, stream>>>(X, cw, cb, oc);
  k_lut<<<(NPAIRn + 255) / 256, 256, 0, stream>>>(lut);
  k_mlp<<<Bn * Tn, 256, 0, stream>>>(oc, w1, b1, w2, b2, gm);
  k_eigh2<<<Bn, NT, eigh_lds, stream>>>(gm, fws, vecsbt, scales);
  k_softidx<<<Bn * Tn, 64, 0, stream>>>(vecsbt, scales, gu, si);
  k_prep<<<Bn, 256, 0, stream>>>(X, si, Y, gstart, gend, ngr);
  k_corr<<<Bn * MAXGn, 256, 0, stream>>>(Y, gstart, gend, ngr, lut, padded);
}

// Round 13
// 15111.334 us; speedup vs baseline: 1.7395x; 1.0895x over previous
//
#include <hip/hip_runtime.h>
#pragma clang fp contract(off)

#define Bn 8
#define Tn 176
#define Rn 116
#define Cn 64
#define Hn 200
#define NPAIRn 6670
#define MAXGn 176
#define TAUf 1e-4f
#define LD 176
#define LDA 177
#define LEAF 22
#define NT 512
#define FEPS 5.9604645e-08f
#define FEPS2 3.5527137e-15f
#define FSAFMIN 1.17549435e-38f

// ---------------- f32 LAPACK helpers ----------------
static __device__ __forceinline__ float f_sign(float a, float b) {
  return (b >= 0.0f) ? fabsf(a) : -fabsf(a);
}
static __device__ __forceinline__ float f_lapy2(float x, float y) {
  float xa = fabsf(x), ya = fabsf(y);
  float w = fmaxf(xa, ya), z = fminf(xa, ya);
  if (z == 0.0f) return w;
  float q = z / w;
  return w * sqrtf(1.0f + q * q);
}
static __device__ void f_lartg(float f, float g, float* c, float* s, float* r) {
  if (g == 0.0f) { *c = 1.0f; *s = 0.0f; *r = f; }
  else if (f == 0.0f) { *c = 0.0f; *s = (g >= 0.0f) ? 1.0f : -1.0f; *r = fabsf(g); }
  else {
    float d = sqrtf(f * f + g * g);
    float rr = (f >= 0.0f) ? d : -d;
    *c = f / rr; *s = g / rr; *r = rr;
  }
}
static __device__ float f_snrm2_strided(const float* x, int n, int stride) {
  float scale = 0.0f, ssq = 1.0f;
  for (int i = 0; i < n; i++) {
    float ax = fabsf(x[i * stride]);
    if (ax != 0.0f) {
      if (scale < ax) {
        float q = scale / ax;
        ssq = 1.0f + ssq * (q * q);
        scale = ax;
      } else {
        float q = ax / scale;
        ssq = ssq + q * q;
      }
    }
  }
  return scale * sqrtf(ssq);
}
static __device__ void f_laev2(float a, float b, float c,
                               float* rt1, float* rt2, float* cs1, float* sn1) {
  float sm = a + c, df = a - c, adf = fabsf(df), tb = b + b, ab = fabsf(tb);
  float acmx, acmn;
  if (fabsf(a) > fabsf(c)) { acmx = a; acmn = c; } else { acmx = c; acmn = a; }
  float rt;
  if (adf > ab) { float q = ab / adf; rt = adf * sqrtf(1.0f + q * q); }
  else if (adf < ab) { float q = adf / ab; rt = ab * sqrtf(1.0f + q * q); }
  else rt = ab * sqrtf(2.0f);
  int sgn1;
  if (sm < 0.0f) { *rt1 = 0.5f * (sm - rt); sgn1 = -1; *rt2 = (acmx / *rt1) * acmn - (b / *rt1) * b; }
  else if (sm > 0.0f) { *rt1 = 0.5f * (sm + rt); sgn1 = 1; *rt2 = (acmx / *rt1) * acmn - (b / *rt1) * b; }
  else { *rt1 = 0.5f * rt; *rt2 = -0.5f * rt; sgn1 = 1; }
  float cs; int sgn2;
  if (df >= 0.0f) { cs = df + rt; sgn2 = 1; } else { cs = df - rt; sgn2 = -1; }
  float acs = fabsf(cs);
  if (acs > ab) { float ct = -tb / cs; *sn1 = 1.0f / sqrtf(1.0f + ct * ct); *cs1 = ct * (*sn1); }
  else {
    if (ab == 0.0f) { *cs1 = 1.0f; *sn1 = 0.0f; }
    else { float tn = -cs / tb; *cs1 = 1.0f / sqrtf(1.0f + tn * tn); *sn1 = tn * (*cs1); }
  }
  if (sgn1 == sgn2) { float tn = *cs1; *cs1 = -(*sn1); *sn1 = tn; }
}
static __device__ void f_lamrg(int n1, int n2, const float* a, int dtrd1, int dtrd2, int* index) {
  int n1sv = n1, n2sv = n2;
  int ind1 = (dtrd1 > 0) ? 0 : n1 - 1;
  int ind2 = (dtrd2 > 0) ? n1 : n1 + n2 - 1;
  int i = 0;
  while (n1sv > 0 && n2sv > 0) {
    if (a[ind1] <= a[ind2]) { index[i++] = ind1; ind1 += dtrd1; n1sv--; }
    else { index[i++] = ind2; ind2 += dtrd2; n2sv--; }
  }
  while (n2sv > 0) { index[i++] = ind2; ind2 += dtrd2; n2sv--; }
  while (n1sv > 0) { index[i++] = ind1; ind1 += dtrd1; n1sv--; }
}
static __device__ void f_laed5(int i, const float* d, const float* z, float rho,
                               float* dlam, float* u0, float* u1) {
  float del = d[1] - d[0];
  float del1, del2;
  if (i == 0) {
    float w = 1.0f + 2.0f * rho * (z[1] * z[1] - z[0] * z[0]) / del;
    if (w > 0.0f) {
      float b = del + rho * (z[0] * z[0] + z[1] * z[1]);
      float c = rho * z[0] * z[0] * del;
      float tau = 2.0f * c / (b + sqrtf(fabsf(b * b - 4.0f * c)));
      *dlam = d[0] + tau;
      del1 = -z[0] / tau; del2 = z[1] / (del - tau);
    } else {
      float b = -del + rho * (z[0] * z[0] + z[1] * z[1]);
      float c = rho * z[1] * z[1] * del;
      float tau;
      if (b > 0.0f) tau = -2.0f * c / (b + sqrtf(b * b + 4.0f * c));
      else tau = (b - sqrtf(b * b + 4.0f * c)) / 2.0f;
      *dlam = d[1] + tau;
      del1 = -z[0] / (del + tau); del2 = -z[1] / tau;
    }
  } else {
    float b = -del + rho * (z[0] * z[0] + z[1] * z[1]);
    float c = rho * z[1] * z[1] * del;
    float tau;
    if (b > 0.0f) tau = (b + sqrtf(b * b + 4.0f * c)) / 2.0f;
    else tau = 2.0f * c / (-b + sqrtf(b * b + 4.0f * c));
    *dlam = d[1] + tau;
    del1 = -z[0] / (del + tau); del2 = -z[1] / tau;
  }
  float t = sqrtf(del1 * del1 + del2 * del2);
  *u0 = del1 / t; *u1 = del2 / t;
}

// ---------------- netlib slaed6 (f32) ----------------
static __device__ void laed6_net(int kniter, bool orgati, float rho, const float* dd,
                                 const float* zz, float finit, float* tau_out) {
  const float eps = FEPS;
  float lbd, ubd;
  if (orgati) { lbd = dd[1]; ubd = dd[2]; }
  else { lbd = dd[0]; ubd = dd[1]; }
  if (finit < 0.0f) lbd = 0.0f; else ubd = 0.0f;
  float tau = 0.0f;
  if (kniter == 2) {
    float temp, a, b, c;
    if (orgati) {
      temp = (dd[2] + dd[1]) / 2.0f;
      c = rho + zz[0] / ((dd[0] - dd[1]) - temp);
      a = c * (dd[1] + dd[2]) + zz[1] + zz[2];
      b = c * dd[1] * dd[2] + zz[1] * dd[2] + zz[2] * dd[1];
    } else {
      temp = (dd[0] + dd[1]) / 2.0f;
      c = rho + zz[2] / ((dd[2] - dd[1]) - temp);
      a = c * (dd[0] + dd[1]) + zz[0] + zz[1];
      b = c * dd[0] * dd[1] + zz[0] * dd[1] + zz[1] * dd[0];
    }
    temp = fmaxf(fmaxf(fabsf(a), fabsf(b)), fabsf(c));
    a /= temp; b /= temp; c /= temp;
    if (c == 0.0f) tau = b / a;
    else if (a <= 0.0f) tau = (a - sqrtf(fabsf(a * a - 4.0f * b * c))) / (2.0f * c);
    else tau = 2.0f * b / (a + sqrtf(fabsf(a * a - 4.0f * b * c)));
    if (tau < lbd || tau > ubd) tau = (lbd + ubd) / 2.0f;
    if (dd[0] == tau || dd[1] == tau || dd[2] == tau) {
      tau = 0.0f;
    } else {
      temp = finit + tau * zz[0] / (dd[0] * (dd[0] - tau))
                   + tau * zz[1] / (dd[1] * (dd[1] - tau))
                   + tau * zz[2] / (dd[2] * (dd[2] - tau));
      if (temp <= 0.0f) lbd = tau; else ubd = tau;
      if (fabsf(finit) <= fabsf(temp)) tau = 0.0f;
    }
  }
  const float small1 = 2.2737367544323206e-13f;
  const float sminv1 = 4398046511104.0f;
  const float small2 = small1 * small1;
  const float sminv2 = sminv1 * sminv1;
  float temp;
  if (orgati) temp = fminf(fabsf(dd[1] - tau), fabsf(dd[2] - tau));
  else temp = fminf(fabsf(dd[0] - tau), fabsf(dd[1] - tau));
  bool doscale = false;
  float sclfac = 1.0f, sclinv = 1.0f;
  float dscale[3], zscale[3];
  if (temp <= small1) {
    doscale = true;
    if (temp <= small2) { sclfac = sminv2; sclinv = small2; }
    else { sclfac = sminv1; sclinv = small1; }
    for (int i = 0; i < 3; i++) { dscale[i] = dd[i] * sclfac; zscale[i] = zz[i] * sclfac; }
    tau *= sclfac; lbd *= sclfac; ubd *= sclfac;
  } else {
    for (int i = 0; i < 3; i++) { dscale[i] = dd[i]; zscale[i] = zz[i]; }
  }
  float fc = 0.0f, df = 0.0f, ddf = 0.0f;
  for (int i = 0; i < 3; i++) {
    float t1 = 1.0f / (dscale[i] - tau);
    float t2 = zscale[i] * t1;
    float t3 = t2 * t1;
    float t4 = t3 * t1;
    fc += t2 / dscale[i];
    df += t3;
    ddf += t4;
  }
  float f = finit + tau * fc;
  if (fabsf(f) > 0.0f) {
    if (f <= 0.0f) lbd = tau; else ubd = tau;
    for (int niter = 2; niter <= 40; ++niter) {
      float t1_, t2_;
      if (orgati) { t1_ = dscale[1] - tau; t2_ = dscale[2] - tau; }
      else { t1_ = dscale[0] - tau; t2_ = dscale[1] - tau; }
      float a = (t1_ + t2_) * f - t1_ * t2_ * df;
      float b = t1_ * t2_ * f;
      float c = f - (t1_ + t2_) * df + t1_ * t2_ * ddf;
      float tm = fmaxf(fmaxf(fabsf(a), fabsf(b)), fabsf(c));
      a /= tm; b /= tm; c /= tm;
      float eta;
      if (c == 0.0f) eta = b / a;
      else if (a <= 0.0f) eta = (a - sqrtf(fabsf(a * a - 4.0f * b * c))) / (2.0f * c);
      else eta = 2.0f * b / (a + sqrtf(fabsf(a * a - 4.0f * b * c)));
      if (f * eta >= 0.0f) eta = -f / df;
      tau = tau + eta;
      if (tau < lbd || tau > ubd) tau = (lbd + ubd) / 2.0f;
      fc = 0.0f; df = 0.0f; ddf = 0.0f;
      float erretm = 0.0f;
      bool hitpole = false;
      for (int i = 0; i < 3; i++) {
        float dt = dscale[i] - tau;
        if (dt != 0.0f) {
          float t1 = 1.0f / dt;
          float t2 = zscale[i] * t1;
          float t3 = t2 * t1;
          float t4 = t3 * t1;
          float t5 = t2 / dscale[i];
          fc += t5;
          erretm += fabsf(t5);
          df += t3;
          ddf += t4;
        } else { hitpole = true; break; }
      }
      if (hitpole) break;
      f = finit + tau * fc;
      erretm = 8.0f * (fabsf(finit) + fabsf(tau) * erretm) + fabsf(tau) * df;
      if (fabsf(f) <= eps * erretm) break;
      if (f <= 0.0f) lbd = tau; else ubd = tau;
    }
  }
  if (doscale) tau *= sclinv;
  *tau_out = tau;
}

// ---------------- netlib slaed4 (f32); delta strided by LD ----------------
static __device__ void laed4_net(int K, int j0, const float* d, const float* z, float rho,
                                 float* dlam, float* delta) {
#define DL(i) delta[(size_t)(i) * LD]
  const float eps = FEPS;
  float rhoinv = 1.0f / rho;
  if (j0 == K - 1) {
    int ii = K - 2;
    float midpt = rho / 2.0f;
    for (int j = 0; j < K; j++) DL(j) = (d[j] - d[K - 1]) - midpt;
    float psi = 0.0f;
    for (int j = 0; j < K - 2; j++) psi += z[j] * z[j] / DL(j);
    float c = rhoinv + psi;
    float w = c + z[ii] * z[ii] / DL(ii) + z[K - 1] * z[K - 1] / DL(K - 1);
    float dltlb, dltub, tau;
    if (w <= 0.0f) {
      float temp = z[K - 2] * z[K - 2] / (d[K - 1] - d[K - 2] + rho) + z[K - 1] * z[K - 1] / rho;
      if (c <= temp) tau = rho;
      else {
        float del = d[K - 1] - d[K - 2];
        float a = -c * del + z[K - 2] * z[K - 2] + z[K - 1] * z[K - 1];
        float b = z[K - 1] * z[K - 1] * del;
        if (a < 0.0f) tau = 2.0f * b / (sqrtf(a * a + 4.0f * b * c) - a);
        else tau = (a + sqrtf(a * a + 4.0f * b * c)) / (2.0f * c);
      }
      dltlb = midpt; dltub = rho;
    } else {
      float del = d[K - 1] - d[K - 2];
      float a = -c * del + z[K - 2] * z[K - 2] + z[K - 1] * z[K - 1];
      float b = z[K - 1] * z[K - 1] * del;
      if (a < 0.0f) tau = 2.0f * b / (sqrtf(a * a + 4.0f * b * c) - a);
      else tau = (a + sqrtf(a * a + 4.0f * b * c)) / (2.0f * c);
      dltlb = 0.0f; dltub = midpt;
    }
    for (int j = 0; j < K; j++) DL(j) = (d[j] - d[K - 1]) - tau;
    float dpsi = 0.0f, erretm = 0.0f;
    psi = 0.0f;
    for (int j = 0; j <= ii; j++) {
      float t = z[j] / DL(j);
      psi += z[j] * t; dpsi += t * t; erretm += psi;
    }
    erretm = fabsf(erretm);
    float t = z[K - 1] / DL(K - 1);
    float phi = z[K - 1] * t, dphi = t * t;
    erretm = 8.0f * (-phi - psi) + erretm - phi + rhoinv + fabsf(tau) * (dpsi + dphi);
    w = rhoinv + phi + psi;
    if (fabsf(w) <= eps * erretm) { *dlam = d[K - 1] + tau; return; }
    if (w <= 0.0f) dltlb = fmaxf(dltlb, tau); else dltub = fminf(dltub, tau);
    for (int niter = 2; niter <= 30; ++niter) {
      float c2 = w - DL(K - 2) * dpsi - DL(K - 1) * dphi;
      float a = (DL(K - 2) + DL(K - 1)) * w - DL(K - 2) * DL(K - 1) * (dpsi + dphi);
      float b = DL(K - 2) * DL(K - 1) * w;
      float eta;
      if (niter == 2) {
        if (c2 < 0.0f) c2 = fabsf(c2);
        if (c2 == 0.0f) eta = dltub - tau;
        else if (a >= 0.0f) eta = (a + sqrtf(fabsf(a * a - 4.0f * b * c2))) / (2.0f * c2);
        else eta = 2.0f * b / (a - sqrtf(fabsf(a * a - 4.0f * b * c2)));
      } else {
        if (a >= 0.0f) eta = (a + sqrtf(fabsf(a * a - 4.0f * b * c2))) / (2.0f * c2);
        else eta = 2.0f * b / (a - sqrtf(fabsf(a * a - 4.0f * b * c2)));
      }
      if (w * eta > 0.0f) eta = -w / (dpsi + dphi);
      float tmp = tau + eta;
      if (tmp > dltub || tmp < dltlb) {
        if (w < 0.0f) eta = (dltub - tau) / 2.0f;
        else eta = (dltlb - tau) / 2.0f;
      }
      for (int j = 0; j < K; j++) DL(j) -= eta;
      tau += eta;
      dpsi = 0.0f; psi = 0.0f; erretm = 0.0f;
      for (int j = 0; j <= ii; j++) {
        float tt = z[j] / DL(j);
        psi += z[j] * tt; dpsi += tt * tt; erretm += psi;
      }
      erretm = fabsf(erretm);
      t = z[K - 1] / DL(K - 1);
      phi = z[K - 1] * t; dphi = t * t;
      erretm = 8.0f * (-phi - psi) + erretm - phi + rhoinv + fabsf(tau) * (dpsi + dphi);
      w = rhoinv + phi + psi;
      if (fabsf(w) <= eps * erretm) break;
      if (w <= 0.0f) dltlb = fmaxf(dltlb, tau); else dltub = fminf(dltub, tau);
    }
    *dlam = d[K - 1] + tau;
    return;
  }
  int ip1 = j0 + 1;
  float del = d[ip1] - d[j0];
  float midpt = del / 2.0f;
  for (int j = 0; j < K; j++) DL(j) = (d[j] - d[j0]) - midpt;
  float psi = 0.0f;
  for (int j = 0; j < j0; j++) psi += z[j] * z[j] / DL(j);
  float phi = 0.0f;
  for (int j = K - 1; j >= j0 + 2; j--) phi += z[j] * z[j] / DL(j);
  float c = rhoinv + psi + phi;
  float w = c + z[j0] * z[j0] / DL(j0) + z[ip1] * z[ip1] / DL(ip1);
  bool orgati;
  float tau, dltlb, dltub;
  if (w > 0.0f) {
    orgati = true;
    float a = c * del + z[j0] * z[j0] + z[ip1] * z[ip1];
    float b = z[j0] * z[j0] * del;
    if (a > 0.0f) tau = 2.0f * b / (a + sqrtf(fabsf(a * a - 4.0f * b * c)));
    else tau = (a - sqrtf(fabsf(a * a - 4.0f * b * c))) / (2.0f * c);
    dltlb = 0.0f; dltub = midpt;
  } else {
    orgati = false;
    float a = c * del - z[j0] * z[j0] - z[ip1] * z[ip1];
    float b = z[ip1] * z[ip1] * del;
    if (a < 0.0f) tau = 2.0f * b / (a - sqrtf(fabsf(a * a + 4.0f * b * c)));
    else tau = -(a + sqrtf(fabsf(a * a + 4.0f * b * c))) / (2.0f * c);
    dltlb = -midpt; dltub = 0.0f;
  }
  int org = orgati ? j0 : ip1;
  for (int j = 0; j < K; j++) DL(j) = (d[j] - d[org]) - tau;
  int ii = org;
  int iim1 = ii - 1, iip1 = ii + 1;
  float dpsi = 0.0f, erretm = 0.0f;
  psi = 0.0f;
  for (int j = 0; j <= ii - 1; j++) {
    float t = z[j] / DL(j);
    psi += z[j] * t; dpsi += t * t; erretm += psi;
  }
  erretm = fabsf(erretm);
  float dphi = 0.0f;
  phi = 0.0f;
  for (int j = K - 1; j >= ii + 1; j--) {
    float t = z[j] / DL(j);
    phi += z[j] * t; dphi += t * t; erretm += phi;
  }
  w = rhoinv + phi + psi;
  bool swtch3 = false;
  if (orgati) { if (w < 0.0f) swtch3 = true; }
  else { if (w > 0.0f) swtch3 = true; }
  if (ii == 0 || ii == K - 1) swtch3 = false;
  float t = z[ii] / DL(ii);
  float dw = dpsi + dphi + t * t;
  t = z[ii] * t;
  w += t;
  erretm = 8.0f * (phi - psi) + erretm + 2.0f * rhoinv + 3.0f * fabsf(t) + fabsf(tau) * dw;
  if (fabsf(w) <= eps * erretm) { *dlam = d[org] + tau; return; }
  if (w <= 0.0f) dltlb = fmaxf(dltlb, tau); else dltub = fminf(dltub, tau);
  float eta;
  {
    if (!swtch3) {
      float c2, a, b;
      if (orgati) {
        float q = z[j0] / DL(j0);
        c2 = w - DL(ip1) * dw - (d[j0] - d[ip1]) * (q * q);
      } else {
        float q = z[ip1] / DL(ip1);
        c2 = w - DL(j0) * dw - (d[ip1] - d[j0]) * (q * q);
      }
      a = (DL(j0) + DL(ip1)) * w - DL(j0) * DL(ip1) * dw;
      b = DL(j0) * DL(ip1) * w;
      if (c2 == 0.0f) {
        if (a == 0.0f) {
          if (orgati) a = z[j0] * z[j0] + DL(ip1) * DL(ip1) * (dpsi + dphi);
          else a = z[ip1] * z[ip1] + DL(j0) * DL(j0) * (dpsi + dphi);
        }
        eta = b / a;
      } else if (a <= 0.0f) eta = (a - sqrtf(fabsf(a * a - 4.0f * b * c2))) / (2.0f * c2);
      else eta = 2.0f * b / (a + sqrtf(fabsf(a * a - 4.0f * b * c2)));
    } else {
      float zz3[3], dd3[3];
      float temp = rhoinv + psi + phi;
      if (orgati) {
        float t1 = z[iim1] / DL(iim1);
        t1 = t1 * t1;
        float c2 = temp - DL(iip1) * (dpsi + dphi) - (d[iim1] - d[iip1]) * t1;
        zz3[0] = z[iim1] * z[iim1];
        zz3[2] = DL(iip1) * DL(iip1) * ((dpsi - t1) + dphi);
        zz3[1] = z[ii] * z[ii];
        dd3[0] = DL(iim1); dd3[1] = DL(ii); dd3[2] = DL(iip1);
        laed6_net(2, orgati, c2, dd3, zz3, w, &eta);
      } else {
        float t1 = z[iip1] / DL(iip1);
        t1 = t1 * t1;
        float c2 = temp - DL(iim1) * (dpsi + dphi) - (d[iip1] - d[iim1]) * t1;
        zz3[0] = DL(iim1) * DL(iim1) * (dpsi + (dphi - t1));
        zz3[2] = z[iip1] * z[iip1];
        zz3[1] = z[ii] * z[ii];
        dd3[0] = DL(iim1); dd3[1] = DL(ii); dd3[2] = DL(iip1);
        laed6_net(2, orgati, c2, dd3, zz3, w, &eta);
      }
    }
    if (w * eta >= 0.0f) eta = -w / dw;
    float tmp = tau + eta;
    if (tmp > dltub || tmp < dltlb) {
      if (w < 0.0f) eta = (dltub - tau) / 2.0f;
      else eta = (dltlb - tau) / 2.0f;
    }
  }
  float prew = w;
  for (int j = 0; j < K; j++) DL(j) -= eta;
  tau += eta;
  dpsi = 0.0f; psi = 0.0f; erretm = 0.0f;
  for (int j = 0; j <= ii - 1; j++) {
    float tt = z[j] / DL(j);
    psi += z[j] * tt; dpsi += tt * tt; erretm += psi;
  }
  erretm = fabsf(erretm);
  dphi = 0.0f; phi = 0.0f;
  for (int j = K - 1; j >= ii + 1; j--) {
    float tt = z[j] / DL(j);
    phi += z[j] * tt; dphi += tt * tt; erretm += phi;
  }
  w = rhoinv + phi + psi;
  t = z[ii] / DL(ii);
  dw = dpsi + dphi + t * t;
  t = z[ii] * t;
  w += t;
  erretm = 8.0f * (phi - psi) + erretm + 2.0f * rhoinv + 3.0f * fabsf(t) + fabsf(tau) * dw;
  bool swtch = false;
  if (orgati) { if (-w > fabsf(prew) / 10.0f) swtch = true; }
  else { if (w > fabsf(prew) / 10.0f) swtch = true; }
  for (int niter = 3; niter <= 30; ++niter) {
    if (fabsf(w) <= eps * erretm) break;
    if (w <= 0.0f) dltlb = fmaxf(dltlb, tau); else dltub = fminf(dltub, tau);
    if (!swtch3) {
      float c2, a, b;
      if (!swtch) {
        if (orgati) {
          float q = z[j0] / DL(j0);
          c2 = w - DL(ip1) * dw - (d[j0] - d[ip1]) * (q * q);
        } else {
          float q = z[ip1] / DL(ip1);
          c2 = w - DL(j0) * dw - (d[ip1] - d[j0]) * (q * q);
        }
      } else {
        float tt = z[ii] / DL(ii);
        if (orgati) dpsi += tt * tt;
        else dphi += tt * tt;
        c2 = w - DL(j0) * dpsi - DL(ip1) * dphi;
      }
      a = (DL(j0) + DL(ip1)) * w - DL(j0) * DL(ip1) * dw;
      b = DL(j0) * DL(ip1) * w;
      if (c2 == 0.0f) {
        if (a == 0.0f) {
          if (!swtch) {
            if (orgati) a = z[j0] * z[j0] + DL(ip1) * DL(ip1) * (dpsi + dphi);
            else a = z[ip1] * z[ip1] + DL(j0) * DL(j0) * (dpsi + dphi);
          } else a = DL(j0) * DL(j0) * dpsi + DL(ip1) * DL(ip1) * dphi;
        }
        eta = b / a;
      } else if (a <= 0.0f) eta = (a - sqrtf(fabsf(a * a - 4.0f * b * c2))) / (2.0f * c2);
      else eta = 2.0f * b / (a + sqrtf(fabsf(a * a - 4.0f * b * c2)));
    } else {
      float zz3[3], dd3[3];
      float t1 = rhoinv + psi + phi;
      if (swtch) {
        float c2 = t1 - DL(iim1) * dpsi - DL(iip1) * dphi;
        zz3[0] = DL(iim1) * DL(iim1) * dpsi;
        zz3[2] = DL(iip1) * DL(iip1) * dphi;
        zz3[1] = z[ii] * z[ii];
        dd3[0] = DL(iim1); dd3[1] = DL(ii); dd3[2] = DL(iip1);
        laed6_net(niter, orgati, c2, dd3, zz3, w, &eta);
      } else {
        if (orgati) {
          float t2 = z[iim1] / DL(iim1);
          t2 = t2 * t2;
          float c2 = t1 - DL(iip1) * (dpsi + dphi) - (d[iim1] - d[iip1]) * t2;
          zz3[0] = z[iim1] * z[iim1];
          zz3[2] = DL(iip1) * DL(iip1) * ((dpsi - t2) + dphi);
          zz3[1] = z[ii] * z[ii];
          dd3[0] = DL(iim1); dd3[1] = DL(ii); dd3[2] = DL(iip1);
          laed6_net(niter, orgati, c2, dd3, zz3, w, &eta);
        } else {
          float t2 = z[iip1] / DL(iip1);
          t2 = t2 * t2;
          float c2 = t1 - DL(iim1) * (dpsi + dphi) - (d[iip1] - d[iim1]) * t2;
          zz3[0] = DL(iim1) * DL(iim1) * (dpsi + (dphi - t2));
          zz3[2] = z[iip1] * z[iip1];
          zz3[1] = z[ii] * z[ii];
          dd3[0] = DL(iim1); dd3[1] = DL(ii); dd3[2] = DL(iip1);
          laed6_net(niter, orgati, c2, dd3, zz3, w, &eta);
        }
      }
    }
    if (w * eta >= 0.0f) eta = -w / dw;
    {
      float tmp = tau + eta;
      if (tmp > dltub || tmp < dltlb) {
        if (w < 0.0f) eta = (dltub - tau) / 2.0f;
        else eta = (dltlb - tau) / 2.0f;
      }
    }
    for (int j = 0; j < K; j++) DL(j) -= eta;
    tau += eta;
    prew = w;
    dpsi = 0.0f; psi = 0.0f; erretm = 0.0f;
    for (int j = 0; j <= ii - 1; j++) {
      float tt = z[j] / DL(j);
      psi += z[j] * tt; dpsi += tt * tt; erretm += psi;
    }
    erretm = fabsf(erretm);
    dphi = 0.0f; phi = 0.0f;
    for (int j = K - 1; j >= ii + 1; j--) {
      float tt = z[j] / DL(j);
      phi += z[j] * tt; dphi += tt * tt; erretm += phi;
    }
    w = rhoinv + phi + psi;
    t = z[ii] / DL(ii);
    dw = dpsi + dphi + t * t;
    t = z[ii] * t;
    w += t;
    erretm = 8.0f * (phi - psi) + erretm + 2.0f * rhoinv + 3.0f * fabsf(t) + fabsf(tau) * dw;
    if (w * prew > 0.0f && fabsf(w) > fabsf(prew) / 10.0f) swtch = !swtch;
  }
  *dlam = d[org] + tau;
#undef DL
}

// ---------------- ssteqr port, serial, f32 (ldz parameterized; used on LDS leaf blocks) ----------------
static __device__ void steqr_f(int n, float* d, float* e, float* Z, int ldz) {
  if (n <= 1) return;
  float work_c[LEAF + 2], work_s[LEAF + 2];
  int nmaxit = n * 30, jtot = 0;
  int l1 = 0;
  while (true) {
    if (l1 > n - 1) break;
    if (l1 > 0) e[l1 - 1] = 0.0f;
    int m;
    for (m = l1; m <= n - 2; ++m) {
      float tst = fabsf(e[m]);
      if (tst == 0.0f) break;
      if (tst <= (sqrtf(fabsf(d[m])) * sqrtf(fabsf(d[m + 1]))) * FEPS) { e[m] = 0.0f; break; }
    }
    int l = l1, lend = m;
    l1 = m + 1;
    if (lend == l) continue;
    if (fabsf(d[lend]) < fabsf(d[l])) { int t = lend; lend = l; l = t; }
    if (lend > l) {
      while (true) {
        int mm;
        if (l != lend) {
          for (mm = l; mm <= lend - 1; ++mm) {
            float tst = fabsf(e[mm]); tst = tst * tst;
            if (tst <= (FEPS2 * fabsf(d[mm])) * fabsf(d[mm + 1]) + FSAFMIN) break;
          }
        } else mm = lend;
        if (mm < lend) e[mm] = 0.0f;
        float p = d[l];
        if (mm == l) { d[l] = p; l = l + 1; if (l <= lend) continue; else break; }
        if (mm == l + 1) {
          float rt1, rt2, c, s;
          f_laev2(d[l], e[l], d[l + 1], &rt1, &rt2, &c, &s);
          for (int r = 0; r < n; r++) {
            float t1 = Z[r * ldz + l + 1], t0 = Z[r * ldz + l];
            Z[r * ldz + l + 1] = c * t1 - s * t0;
            Z[r * ldz + l] = s * t1 + c * t0;
          }
          d[l] = rt1; d[l + 1] = rt2; e[l] = 0.0f;
          l += 2; if (l <= lend) continue; else break;
        }
        if (jtot == nmaxit) break;
        jtot++;
        float g = (d[l + 1] - p) / (2.0f * e[l]);
        float r = f_lapy2(g, 1.0f);
        g = d[mm] - p + e[l] / (g + f_sign(r, g));
        float s = 1.0f, c = 1.0f; p = 0.0f;
        for (int i = mm - 1; i >= l; --i) {
          float f = s * e[i], bb = c * e[i];
          f_lartg(g, f, &c, &s, &r);
          if (i != mm - 1) e[i + 1] = r;
          g = d[i + 1] - p;
          r = (d[i] - g) * s + 2.0f * c * bb;
          p = s * r;
          d[i + 1] = g + p;
          g = c * r - bb;
          work_c[i] = c; work_s[i] = -s;
        }
        for (int j = mm - l; j >= 1; --j) {
          float cj = work_c[l + j - 1], sj = work_s[l + j - 1];
          for (int rr = 0; rr < n; rr++) {
            float t1 = Z[rr * ldz + l + j], t0 = Z[rr * ldz + l + j - 1];
            Z[rr * ldz + l + j] = cj * t1 - sj * t0;
            Z[rr * ldz + l + j - 1] = sj * t1 + cj * t0;
          }
        }
        d[l] -= p; e[l] = g;
      }
    } else {
      while (true) {
        int mm;
        if (l != lend) {
          for (mm = l; mm >= lend + 1; --mm) {
            float tst = fabsf(e[mm - 1]); tst = tst * tst;
            if (tst <= (FEPS2 * fabsf(d[mm])) * fabsf(d[mm - 1]) + FSAFMIN) break;
          }
        } else mm = lend;
        if (mm > lend) e[mm - 1] = 0.0f;
        float p = d[l];
        if (mm == l) { d[l] = p; l = l - 1; if (l >= lend) continue; else break; }
        if (mm == l - 1) {
          float rt1, rt2, c, s;
          f_laev2(d[l - 1], e[l - 1], d[l], &rt1, &rt2, &c, &s);
          for (int r = 0; r < n; r++) {
            float t1 = Z[r * ldz + l], t0 = Z[r * ldz + l - 1];
            Z[r * ldz + l] = c * t1 - s * t0;
            Z[r * ldz + l - 1] = s * t1 + c * t0;
          }
          d[l - 1] = rt1; d[l] = rt2; e[l - 1] = 0.0f;
          l -= 2; if (l >= lend) continue; else break;
        }
        if (jtot == nmaxit) break;
        jtot++;
        float g = (d[l - 1] - p) / (2.0f * e[l - 1]);
        float r = f_lapy2(g, 1.0f);
        g = d[mm] - p + e[l - 1] / (g + f_sign(r, g));
        float s = 1.0f, c = 1.0f; p = 0.0f;
        for (int i = mm; i <= l - 1; ++i) {
          float f = s * e[i], bb = c * e[i];
          f_lartg(g, f, &c, &s, &r);
          if (i != mm) e[i - 1] = r;
          g = d[i] - p;
          r = (d[i + 1] - g) * s + 2.0f * c * bb;
          p = s * r;
          d[i] = g + p;
          g = c * r - bb;
          work_c[i] = c; work_s[i] = s;
        }
        for (int j = 1; j <= l - mm; ++j) {
          float cj = work_c[mm + j - 1], sj = work_s[mm + j - 1];
          for (int rr = 0; rr < n; rr++) {
            float t1 = Z[rr * ldz + mm + j], t0 = Z[rr * ldz + mm + j - 1];
            Z[rr * ldz + mm + j] = cj * t1 - sj * t0;
            Z[rr * ldz + mm + j - 1] = sj * t1 + cj * t0;
          }
        }
        d[l] -= p; e[l - 1] = g;
      }
    }
  }
  for (int ii = 1; ii < n; ++ii) {
    int i = ii - 1, k = i; float p = d[i];
    for (int j = ii; j < n; ++j) if (d[j] < p) { k = j; p = d[j]; }
    if (k != i) {
      d[k] = d[i]; d[i] = p;
      for (int r = 0; r < n; r++) { float t = Z[r * ldz + i]; Z[r * ldz + i] = Z[r * ldz + k]; Z[r * ldz + k] = t; }
    }
  }
}

// ---------------- slaed1/2/3-equivalent merge, f32 (FMA assembly) ----------------
static __device__ void laed1_f(int tid, int nb, int n1, int off, float rho_in,
    float* Zb, float* Qt, float* Um, float* dd,
    float* dlamda, float* w2, float* lamv, float* wtv, float* zv, float* dnew, float* dsort,
    int* indxq, int* indxp, int* indxc, int* indxm,
    float* shs, int* shi) {
  int n2 = nb - n1;
  if (tid == 0) {
    float rho = rho_in;
    for (int i = 0; i < n1; i++) zv[i] = Zb[(off + n1 - 1) * LD + off + i];
    for (int i = 0; i < n2; i++) zv[n1 + i] = Zb[(off + n1) * LD + off + n1 + i];
    if (rho < 0.0f) for (int i = n1; i < nb; i++) zv[i] = -zv[i];
    const float isq2 = 0.70710678118654752440f;
    for (int i = 0; i < nb; i++) zv[i] *= isq2;
    rho = fabsf(2.0f * rho);
    for (int i = n1; i < nb; i++) indxq[off + i] += n1;
    for (int i = 0; i < nb; i++) dsort[i] = dd[off + indxq[off + i]];
    f_lamrg(n1, n2, dsort, 1, 1, indxc);
    for (int i = 0; i < nb; i++) indxm[i] = indxq[off + indxc[i]];
    float zmax = 0.0f, dmax = 0.0f;
    for (int i = 0; i < nb; i++) {
      float az = fabsf(zv[i]); if (az > zmax) zmax = az;
      float ad = fabsf(dd[off + i]); if (ad > dmax) dmax = ad;
    }
    float tol = 8.0f * FEPS * ((dmax > zmax) ? dmax : zmax);
    int K = 0;
    if (rho * zmax <= tol) {
      for (int j = 0; j < nb; j++) indxp[j] = indxm[j];
    } else {
      int K2 = nb; int pj = 0; int j; bool found = false;
      for (j = 0; j < nb; j++) {
        int nj = indxm[j];
        if (rho * fabsf(zv[nj]) <= tol) { K2--; indxp[K2] = nj; if (j == nb - 1) break; }
        else { pj = nj; found = true; break; }
      }
      if (found) {
        while (true) {
          j++;
          if (j >= nb) break;
          int nj = indxm[j];
          if (rho * fabsf(zv[nj]) <= tol) { K2--; indxp[K2] = nj; }
          else {
            float s_ = zv[pj], c_ = zv[nj];
            float tau_ = f_lapy2(c_, s_);
            float t_ = dd[off + nj] - dd[off + pj];
            c_ /= tau_; s_ = -s_ / tau_;
            if (fabsf(t_ * c_ * s_) <= tol) {
              zv[nj] = tau_; zv[pj] = 0.0f;
              for (int r = 0; r < nb; r++) {
                float x = Zb[(off + r) * LD + off + pj], y = Zb[(off + r) * LD + off + nj];
                Zb[(off + r) * LD + off + pj] = c_ * x + s_ * y;
                Zb[(off + r) * LD + off + nj] = c_ * y - s_ * x;
              }
              float t2 = dd[off + pj] * c_ * c_ + dd[off + nj] * s_ * s_;
              dd[off + nj] = dd[off + pj] * s_ * s_ + dd[off + nj] * c_ * c_;
              dd[off + pj] = t2;
              K2--;
              int i_ = 1;
              while (true) {
                if (K2 + i_ < nb) {
                  if (dd[off + pj] < dd[off + indxp[K2 + i_]]) {
                    indxp[K2 + i_ - 1] = indxp[K2 + i_]; indxp[K2 + i_] = pj; i_++;
                  } else { indxp[K2 + i_ - 1] = pj; break; }
                } else { indxp[K2 + i_ - 1] = pj; break; }
              }
              pj = nj;
            } else {
              dlamda[K] = dd[off + pj]; w2[K] = zv[pj]; indxp[K] = pj; K++;
              pj = nj;
            }
          }
        }
        dlamda[K] = dd[off + pj]; w2[K] = zv[pj]; indxp[K] = pj; K++;
      }
    }
    shi[0] = K; shs[0] = rho;
  }
  __syncthreads();
  int K = shi[0]; float rho = shs[0];
  if (K == 0) {
    for (int idx = tid; idx < nb * nb; idx += NT) {
      int r = idx / nb, jj = idx - r * nb;
      Qt[r * LD + jj] = Zb[(off + r) * LD + off + indxp[jj]];
    }
    for (int jj = tid; jj < nb; jj += NT) dnew[jj] = dd[off + indxp[jj]];
    __syncthreads();
    for (int idx = tid; idx < nb * nb; idx += NT) {
      int r = idx / nb, jj = idx - r * nb;
      Zb[(off + r) * LD + off + jj] = Qt[r * LD + jj];
    }
    for (int jj = tid; jj < nb; jj += NT) { dd[off + jj] = dnew[jj]; indxq[off + jj] = jj; }
    __syncthreads();
    return;
  }
  if (K == 1) {
    if (tid == 0) { lamv[0] = dlamda[0] + rho * w2[0] * w2[0]; Um[0] = 1.0f; }
  } else if (K == 2) {
    if (tid < 2) {
      float u0, u1, dl_;
      f_laed5(tid, dlamda, w2, rho, &dl_, &u0, &u1);
      lamv[tid] = dl_; Um[0 * LD + tid] = u0; Um[1 * LD + tid] = u1;
    }
  } else {
    if (tid < K) laed4_net(K, tid, dlamda, w2, rho, &lamv[tid], &Um[tid]);
  }
  __syncthreads();
  if (K > 2) {
    if (tid < K) {
      int i = tid; float val = Um[i * LD + i];
      for (int j2 = 0; j2 < K; j2++) if (j2 != i) val *= Um[i * LD + j2] / (dlamda[i] - dlamda[j2]);
      wtv[i] = f_sign(sqrtf(fabsf(val)), w2[i]);
    }
    __syncthreads();
    if (tid < K) {
      int j2 = tid;
      for (int i = 0; i < K; i++) Um[i * LD + j2] = wtv[i] / Um[i * LD + j2];
      float nrm = f_snrm2_strided(&Um[j2], K, LD);
      for (int i = 0; i < K; i++) Um[i * LD + j2] /= nrm;
    }
    __syncthreads();
  }
  for (int idx = tid; idx < nb * K; idx += NT) {
    int r = idx / K, j2 = idx - r * K;
    float acc = 0.0f;
    for (int i = 0; i < K; i++) acc = fmaf(Zb[(off + r) * LD + off + indxp[i]], Um[i * LD + j2], acc);
    Qt[r * LD + j2] = acc;
  }
  int nd = nb - K;
  for (int idx = tid; idx < nb * nd; idx += NT) {
    int r = idx / nd, jj = idx - r * nd;
    Qt[r * LD + K + jj] = Zb[(off + r) * LD + off + indxp[K + jj]];
  }
  for (int jj = tid; jj < nb; jj += NT) dnew[jj] = (jj < K) ? lamv[jj] : dd[off + indxp[jj]];
  __syncthreads();
  for (int idx = tid; idx < nb * nb; idx += NT) {
    int r = idx / nb, jj = idx - r * nb;
    Zb[(off + r) * LD + off + jj] = Qt[r * LD + jj];
  }
  for (int jj = tid; jj < nb; jj += NT) dd[off + jj] = dnew[jj];
  __syncthreads();
  if (tid == 0) f_lamrg(K, nb - K, dnew, 1, -1, indxq + off);
  __syncthreads();
}

#define FSTR 109824
// ---------------- ssyevd-clone kernel (f32): A(LDS,pad177) + LDS leaf-Z; 512 threads ----------------
__global__ __launch_bounds__(NT) void k_eigh2(const float* __restrict__ gm,
    float* __restrict__ fws,
    float* __restrict__ vecsbt, float* __restrict__ scales) {
  int b = blockIdx.x, tid = threadIdx.x;
  extern __shared__ char dynsm[];
  float* A = (float*)dynsm;              // 176*177 f32 (124.6 KB) in LDS, padded stride
  float* sm1 = A + Tn * LDA;             // 1760 f32 scalar arrays
  int* ib_ = (int*)(sm1 + 1760);         // 880 i32 index arrays
  float* Zb = fws + (size_t)b * FSTR;    // global
  float* Qt = Zb + 30976;
  float* Um = Qt + 30976;
  float* Wp = Um + 30976;                // [176*32]
  float* Wa = Wp + 5632;
  float* Wb = Wa + 5632;
  float* dd = sm1;
  float* ee = sm1 + 176;
  float* tauv = sm1 + 352;
  float* dlamda = sm1 + 528;
  float* w2 = sm1 + 704;
  float* lamv = sm1 + 880;
  float* wtv = sm1 + 1056;
  float* zv = sm1 + 1232;
  float* dnew = sm1 + 1408;
  float* dsort = sm1 + 1584;
  int* indxq = ib_;
  int* indxp = ib_ + 176;
  int* indxc = ib_ + 352;
  int* indxm = ib_ + 528;
  __shared__ float shv[176];
  __shared__ float shs[2];
  __shared__ int shi[2];
  __shared__ float t12[64];
  __shared__ float Tm[1024];
  __shared__ float Zleaf[8][LEAF][LEAF + 1];   // 16.2 KB: leaf steqr scratch in LDS
  for (int i = tid; i < Tn * Tn; i += NT)
    A[(i / Tn) * LDA + (i % Tn)] = gm[(size_t)b * Tn * Tn + i];
  __syncthreads();
  // ======== blocked SSYTRD (lower), NB=32, panels 0,32,64,96,128; ssytd2 tail 160.. ========
  for (int i0 = 0; i0 < Tn - 32; i0 += 32) {
    for (int i = 0; i < 32; i++) {
      int g = i0 + i;
      if (i > 0) {
        for (int r = g + tid; r < Tn; r += NT) {
          float acc = A[r * LDA + g];
          for (int k = 0; k < i; k++) acc = fmaf(-Wp[g * 32 + k], A[r * LDA + (i0 + k)], acc);
          for (int k = 0; k < i; k++) acc = fmaf(-A[g * LDA + (i0 + k)], Wp[r * 32 + k], acc);
          A[r * LDA + g] = acc;
        }
        __syncthreads();
      }
      if (tid == 0) {
        float scale = 0.0f, ssq = 1.0f;
        for (int r = g + 2; r < Tn; r++) {
          float ax = fabsf(A[r * LDA + g]);
          if (ax != 0.0f) {
            if (scale < ax) { float q = scale / ax; ssq = 1.0f + ssq * (q * q); scale = ax; }
            else { float q = ax / scale; ssq = ssq + q * q; }
          }
        }
        float xnorm = scale * sqrtf(ssq);
        float alpha = A[(g + 1) * LDA + g];
        float taui = 0.0f, scal = 0.0f;
        if (xnorm == 0.0f) { ee[g] = alpha; }
        else {
          float beta = -f_sign(f_lapy2(alpha, xnorm), alpha);
          taui = (beta - alpha) / beta;
          scal = 1.0f / (alpha - beta);
          ee[g] = beta;
        }
        tauv[g] = taui; shs[0] = taui; shs[1] = scal;
      }
      __syncthreads();
      float taui = shs[0];
      if (taui != 0.0f) {
        float scal = shs[1];
        for (int r = g + 2 + tid; r < Tn; r += NT) A[r * LDA + g] *= scal;
      }
      __syncthreads();
      if (tid == 0) A[(g + 1) * LDA + g] = 1.0f;
      __syncthreads();
      for (int r = g + 1 + tid; r < Tn; r += NT) {
        float acc = 0.0f;
        for (int c = g + 1; c < r; c++) acc = fmaf(A[c * LDA + g], A[r * LDA + c], acc);
        acc = fmaf(A[r * LDA + g], A[r * LDA + r], acc);
        float temp2 = 0.0f;
        for (int k = r + 1; k < Tn; k++) temp2 = fmaf(A[k * LDA + r], A[k * LDA + g], temp2);
        acc += temp2;
        shv[r] = acc;
      }
      __syncthreads();
      if (i > 0) {
        if (tid < i) {
          int k = tid;
          float acc = 0.0f;
          for (int r = g + 1; r < Tn; r++) acc = fmaf(Wp[r * 32 + k], A[r * LDA + g], acc);
          t12[k] = acc;
        }
        __syncthreads();
        for (int r = g + 1 + tid; r < Tn; r += NT) {
          float acc = shv[r];
          for (int k = 0; k < i; k++) acc = fmaf(-t12[k], A[r * LDA + (i0 + k)], acc);
          shv[r] = acc;
        }
        __syncthreads();
        if (tid < i) {
          int k = tid;
          float acc = 0.0f;
          for (int r = g + 1; r < Tn; r++) acc = fmaf(A[r * LDA + (i0 + k)], A[r * LDA + g], acc);
          t12[32 + k] = acc;
        }
        __syncthreads();
        for (int r = g + 1 + tid; r < Tn; r += NT) {
          float acc = shv[r];
          for (int k = 0; k < i; k++) acc = fmaf(-t12[32 + k], Wp[r * 32 + k], acc);
          shv[r] = acc;
        }
        __syncthreads();
      }
      for (int r = g + 1 + tid; r < Tn; r += NT) shv[r] = taui * shv[r];
      __syncthreads();
      if (tid == 0) {
        float dot = 0.0f;
        for (int r = g + 1; r < Tn; r++) dot = fmaf(shv[r], A[r * LDA + g], dot);
        shs[0] = -0.5f * taui * dot;
      }
      __syncthreads();
      float alf = shs[0];
      for (int r = g + 1 + tid; r < Tn; r += NT) Wp[r * 32 + i] = fmaf(alf, A[r * LDA + g], shv[r]);
      __syncthreads();
    }
    {
      int base2 = i0 + 32;
      int nt2 = Tn - base2;
      int npr = nt2 * (nt2 + 1) / 2;
      for (int p = tid; p < npr; p += NT) {
        int rr = (int)((sqrtf(8.0f * (float)p + 1.0f) - 1.0f) * 0.5f);
        while ((rr + 1) * (rr + 2) / 2 <= p) rr++;
        while (rr * (rr + 1) / 2 > p) rr--;
        int cc = p - rr * (rr + 1) / 2;
        int r = base2 + rr, c = base2 + cc;
        float acc = A[r * LDA + c];
        for (int L = 0; L < 32; L++) {
          acc = fmaf(A[r * LDA + (i0 + L)], -Wp[c * 32 + L], acc);
          acc = fmaf(Wp[r * 32 + L], -A[c * LDA + (i0 + L)], acc);
        }
        A[r * LDA + c] = acc;
        if (r != c) A[c * LDA + r] = acc;
      }
      __syncthreads();
      if (tid < 32) {
        int g2 = i0 + tid;
        A[(g2 + 1) * LDA + g2] = ee[g2];
      }
      __syncthreads();
    }
  }
  // ---- final ssytd2 on trailing 16 (cols 160..174) ----
  for (int i = 160; i < Tn - 1; i++) {
    if (tid == 0) {
      float scale = 0.0f, ssq = 1.0f;
      for (int r = i + 2; r < Tn; r++) {
        float ax = fabsf(A[r * LDA + i]);
        if (ax != 0.0f) {
          if (scale < ax) { float q = scale / ax; ssq = 1.0f + ssq * (q * q); scale = ax; }
          else { float q = ax / scale; ssq = ssq + q * q; }
        }
      }
      float xnorm = scale * sqrtf(ssq);
      float alpha = A[(i + 1) * LDA + i];
      float taui = 0.0f, scal = 0.0f;
      if (xnorm == 0.0f) { ee[i] = alpha; }
      else {
        float beta = -f_sign(f_lapy2(alpha, xnorm), alpha);
        taui = (beta - alpha) / beta;
        scal = 1.0f / (alpha - beta);
        ee[i] = beta;
      }
      tauv[i] = taui; shs[0] = taui; shs[1] = scal;
    }
    __syncthreads();
    float taui = shs[0];
    if (taui != 0.0f) {
      float scal = shs[1];
      for (int r = i + 2 + tid; r < Tn; r += NT) A[r * LDA + i] *= scal;
      __syncthreads();
      for (int r = i + 1 + tid; r < Tn; r += NT) {
        float acc = 0.0f;
        for (int c = i + 1; c < r; c++) {
          float vc = (c == i + 1) ? 1.0f : A[c * LDA + i];
          acc = fmaf(taui * vc, A[r * LDA + c], acc);
        }
        float vr = (r == i + 1) ? 1.0f : A[r * LDA + i];
        acc = fmaf(taui * vr, A[r * LDA + r], acc);
        float temp2 = 0.0f;
        for (int k = r + 1; k < Tn; k++) temp2 = fmaf(A[k * LDA + r], A[k * LDA + i], temp2);
        acc = fmaf(taui, temp2, acc);
        shv[r] = acc;
      }
      __syncthreads();
      if (tid == 0) {
        float dot = 0.0f;
        for (int r = i + 1; r < Tn; r++) {
          float vr = (r == i + 1) ? 1.0f : A[r * LDA + i];
          dot = fmaf(vr, shv[r], dot);
        }
        shs[0] = -0.5f * taui * dot;
      }
      __syncthreads();
      float alpha2 = shs[0];
      for (int r = i + 1 + tid; r < Tn; r += NT) {
        float vr = (r == i + 1) ? 1.0f : A[r * LDA + i];
        shv[r] = fmaf(alpha2, vr, shv[r]);
      }
      __syncthreads();
      int m2 = Tn - 1 - i;
      int npairs = m2 * (m2 + 1) / 2;
      for (int p = tid; p < npairs; p += NT) {
        int rr = (int)((sqrtf(8.0f * (float)p + 1.0f) - 1.0f) * 0.5f);
        while ((rr + 1) * (rr + 2) / 2 <= p) rr++;
        while (rr * (rr + 1) / 2 > p) rr--;
        int cc = p - rr * (rr + 1) / 2;
        int r = i + 1 + rr, c = i + 1 + cc;
        float vr = (r == i + 1) ? 1.0f : A[r * LDA + i];
        float vc = (c == i + 1) ? 1.0f : A[c * LDA + i];
        float val = A[r * LDA + c];
        val = fmaf(vr, -shv[c], val);
        val = fmaf(shv[r], -vc, val);
        A[r * LDA + c] = val;
      }
      __syncthreads();
    }
  }
  for (int i = tid; i < Tn; i += NT) dd[i] = A[i * LDA + i];
  __syncthreads();
  // ======== sstedc ========
  if (tid == 0) {
    float on = 0.0f;
    for (int i = 0; i < Tn; i++) { float v = fabsf(dd[i]); if (v > on) on = v; }
    for (int i = 0; i < Tn - 1; i++) { float v = fabsf(ee[i]); if (v > on) on = v; }
    shs[0] = (on > 0.0f) ? on : 1.0f;
  }
  __syncthreads();
  float orgnrm = shs[0];
  for (int i = tid; i < Tn; i += NT) dd[i] /= orgnrm;
  for (int i = tid; i < Tn - 1; i += NT) ee[i] /= orgnrm;
  for (int i = tid; i < Tn * Tn; i += NT)
    Zb[(i / Tn) * LD + (i % Tn)] = ((i / Tn) == (i % Tn)) ? 1.0f : 0.0f;
  // init leaf Z scratch to identity
  for (int i = tid; i < 8 * LEAF * LEAF; i += NT) {
    int lf = i / (LEAF * LEAF);
    int rc = i - lf * (LEAF * LEAF);
    int r = rc / LEAF, c = rc - r * LEAF;
    Zleaf[lf][r][c] = (r == c) ? 1.0f : 0.0f;
  }
  __syncthreads();
  if (tid == 0) {
    for (int c = LEAF; c < Tn; c += LEAF) { dd[c - 1] -= fabsf(ee[c - 1]); dd[c] -= fabsf(ee[c - 1]); }
  }
  __syncthreads();
  // leaf steqr on LDS scratch: one leaf per WAVE (lane 0 of waves 0..7)
  if ((tid & 63) == 0 && (tid >> 6) < 8) {
    int lf = tid >> 6;
    steqr_f(LEAF, dd + LEAF * lf, ee + LEAF * lf, &Zleaf[lf][0][0], LEAF + 1);
  }
  __syncthreads();
  // copy leaf Z blocks into global Zb
  for (int i = tid; i < 8 * LEAF * LEAF; i += NT) {
    int lf = i / (LEAF * LEAF);
    int rc = i - lf * (LEAF * LEAF);
    int r = rc / LEAF, c = rc - r * LEAF;
    Zb[(size_t)(LEAF * lf + r) * LD + LEAF * lf + c] = Zleaf[lf][r][c];
  }
  __syncthreads();
  for (int i = tid; i < Tn; i += NT) indxq[i] = i % LEAF;
  __syncthreads();
  for (int nb = 2 * LEAF; nb <= Tn; nb *= 2) {
    for (int off = 0; off < Tn; off += nb) {
      laed1_f(tid, nb, nb / 2, off, ee[off + nb / 2 - 1],
              Zb, Qt, Um, dd, dlamda, w2, lamv, wtv, zv, dnew, dsort,
              indxq, indxp, indxc, indxm, shs, shi);
    }
  }
  for (int idx = tid; idx < Tn * Tn; idx += NT) {
    int r = idx / Tn, j = idx % Tn;
    Qt[r * LD + j] = Zb[r * LD + indxq[j]];
  }
  for (int j = tid; j < Tn; j += NT) dnew[j] = dd[indxq[j]];
  __syncthreads();
  for (int idx = tid; idx < Tn * Tn; idx += NT) {
    int r = idx / Tn, j = idx % Tn;
    Zb[r * LD + j] = Qt[r * LD + j];
  }
  for (int j = tid; j < Tn; j += NT) dd[j] = dnew[j] * orgnrm;
  __syncthreads();
  // ======== blocked SORMQR back-transform (FMA) ========
  for (int bi = 0; bi < 6; bi++) {
    int s = (bi == 0) ? 160 : (128 - (bi - 1) * 32);
    int ibk = (bi == 0) ? 15 : 32;
    for (int i2 = 0; i2 < ibk; i2++) {
      float ti = tauv[s + i2];
      if (tid < i2) {
        int j2 = tid;
        float acc = 0.0f;
        for (int r = s + i2; r <= Tn - 2; r++) {
          float vj = (r == s + j2) ? 1.0f : A[(r + 1) * LDA + (s + j2)];
          float vi = (r == s + i2) ? 1.0f : A[(r + 1) * LDA + (s + i2)];
          acc = fmaf(vj, vi, acc);
        }
        Tm[j2 * 32 + i2] = (ti == 0.0f) ? 0.0f : (-ti) * acc;
      }
      __syncthreads();
      if (tid == 0) {
        if (ti != 0.0f) {
          for (int J = 0; J < i2; J++) {
            float tmp = Tm[J * 32 + i2];
            if (tmp != 0.0f) {
              for (int I2 = 0; I2 < J; I2++) Tm[I2 * 32 + i2] = fmaf(tmp, Tm[I2 * 32 + J], Tm[I2 * 32 + i2]);
              Tm[J * 32 + i2] = tmp * Tm[J * 32 + J];
            }
          }
        }
        Tm[i2 * 32 + i2] = ti;
      }
      __syncthreads();
    }
    int c2r0 = s + ibk + 1;
    int nc2 = Tn - c2r0;
    for (int e = tid; e < Tn * ibk; e += NT) {
      int c = e / ibk, j = e - (e / ibk) * ibk;
      float acc = Zb[(s + 1 + j) * LD + c];
      for (int k = j + 1; k < ibk; k++) {
        float v1 = A[(s + 1 + k) * LDA + (s + j)];
        acc = fmaf(v1, Zb[(s + 1 + k) * LD + c], acc);
      }
      Wb[c * 32 + j] = acc;
    }
    __syncthreads();
    if (nc2 > 0) {
      for (int e = tid; e < Tn * ibk; e += NT) {
        int c = e / ibk, j = e - (e / ibk) * ibk;
        float acc = 0.0f;
        for (int rr = 0; rr < nc2; rr++)
          acc = fmaf(Zb[(c2r0 + rr) * LD + c], A[(c2r0 + rr) * LDA + (s + j)], acc);
        Wb[c * 32 + j] = acc + Wb[c * 32 + j];
      }
      __syncthreads();
    }
    for (int e = tid; e < Tn * ibk; e += NT) {
      int c = e / ibk, j = e - (e / ibk) * ibk;
      float acc = Tm[j * 32 + j] * Wb[c * 32 + j];
      for (int K = j + 1; K < ibk; K++) acc = fmaf(Tm[j * 32 + K], Wb[c * 32 + K], acc);
      Wa[c * 32 + j] = acc;
    }
    __syncthreads();
    if (nc2 > 0) {
      for (int e = tid; e < nc2 * Tn; e += NT) {
        int rr = e / Tn, c = e - (e / Tn) * Tn;
        float cv = Zb[(c2r0 + rr) * LD + c];
        for (int j = 0; j < ibk; j++)
          cv = fmaf(-Wa[c * 32 + j], A[(c2r0 + rr) * LDA + (s + j)], cv);
        Zb[(c2r0 + rr) * LD + c] = cv;
      }
      __syncthreads();
    }
    for (int e = tid; e < Tn * ibk; e += NT) {
      int c = e / ibk, j = e - (e / ibk) * ibk;
      float acc = Wa[c * 32 + j];
      for (int K = j - 1; K >= 0; K--) {
        float v1 = A[(s + 1 + j) * LDA + (s + K)];
        acc = fmaf(v1, Wa[c * 32 + K], acc);
      }
      Wb[c * 32 + j] = acc;
    }
    __syncthreads();
    for (int e = tid; e < ibk * Tn; e += NT) {
      int j = e / Tn, c = e - (e / Tn) * Tn;
      Zb[(s + 1 + j) * LD + c] = Zb[(s + 1 + j) * LD + c] - Wb[c * 32 + j];
    }
    __syncthreads();
  }
  // ---- outputs ----
  for (int idx = tid; idx < Tn * Tn; idx += NT) {
    int t = idx / Tn, j = idx % Tn;
    vecsbt[((size_t)b * Tn + t) * Tn + j] = Zb[t * LD + j];
  }
  for (int j = tid; j < Tn; j += NT) {
    float vd = dd[Tn - 1 - j];
    if (vd <= 0.f) vd = 1e-7f;
    scales[b * Tn + j] = sqrtf(vd) * 1000.f;
  }
}

// ---------------- conv ----------------
__global__ void k_conv(const float* __restrict__ X, const float* __restrict__ cw,
                       const float* __restrict__ cb, float* __restrict__ oc) {
  int idx = blockIdx.x * 256 + threadIdx.x;
  if (idx >= Bn * Tn * Cn) return;
  int c = idx & (Cn - 1);
  int bt = idx >> 6;
  const float* xr = X + bt * Rn;
  const float* wr = cw + c * Rn;
  float acc = cb[c];
#pragma unroll 4
  for (int r = 0; r < Rn; ++r) acc = fmaf(xr[r], wr[r], acc);
  oc[idx] = acc;
}

// ---------------- pairwise MLP -> grouping_M ----------------
__global__ __launch_bounds__(256) void k_mlp(const float* __restrict__ oc,
        const float* __restrict__ w1, const float* __restrict__ b1,
        const float* __restrict__ w2, const float* __restrict__ b2,
        float* __restrict__ gm) {
  __shared__ float xw[4 * 8];
  int tid = threadIdx.x;
  int lane = tid & 63, wv = tid >> 6;
  int b = blockIdx.x / Tn, t = blockIdx.x % Tn;
  bool active = (tid < Hn);
  float w1r[64];
  if (active) {
    const float4* wrow = reinterpret_cast<const float4*>(w1 + tid * Cn);
#pragma unroll
    for (int i = 0; i < 16; ++i) {
      float4 v = wrow[i];
      w1r[4 * i] = v.x; w1r[4 * i + 1] = v.y; w1r[4 * i + 2] = v.z; w1r[4 * i + 3] = v.w;
    }
  } else {
#pragma unroll
    for (int i = 0; i < 64; ++i) w1r[i] = 0.f;
  }
  float myb1 = active ? b1[tid] : 0.f;
  float myw2 = active ? w2[tid] : 0.f;
  float b2v = b2[0];
  float outt = oc[(b * Tn + t) * Cn + lane];
  for (int s0 = 0; s0 < Tn; s0 += 8) {
    float dj[8];
#pragma unroll
    for (int j = 0; j < 8; ++j) {
      float o = oc[(b * Tn + s0 + j) * Cn + lane];
      float d = outt - o;
      dj[j] = sqrtf(d * d + 1e-9f);
    }
    float acc[8];
#pragma unroll
    for (int j = 0; j < 8; ++j) acc[j] = myb1;
#pragma unroll
    for (int c = 0; c < 64; ++c) {
      float wv1 = w1r[c];
#pragma unroll
      for (int j = 0; j < 8; ++j) {
        float dv = __int_as_float(__builtin_amdgcn_readlane(__float_as_int(dj[j]), c));
        acc[j] = fmaf(dv, wv1, acc[j]);
      }
    }
#pragma unroll
    for (int j = 0; j < 8; ++j) {
      float v = fmaxf(acc[j], 0.f) * myw2;
#pragma unroll
      for (int off = 32; off; off >>= 1) v += __shfl_xor(v, off);
      acc[j] = v;
    }
    if (lane == 0) {
#pragma unroll
      for (int j = 0; j < 8; ++j) xw[wv * 8 + j] = acc[j];
    }
    __syncthreads();
    if (tid < 8) {
      float sum = xw[tid] + xw[8 + tid] + xw[16 + tid] + xw[24 + tid] + b2v;
      float cl = 1.f / (1.f + expf(-sum));
      int s = s0 + tid;
      gm[(b * Tn + t) * Tn + s] = (s == t) ? 1.f : cl;
    }
    __syncthreads();
  }
}

// ---------------- soft indices ----------------
__global__ __launch_bounds__(64) void k_softidx(const float* __restrict__ vecsbt,
        const float* __restrict__ scales, const float* __restrict__ gumbel,
        float* __restrict__ si) {
  int bt = blockIdx.x;
  int b = bt / Tn;
  int lane = threadIdx.x;
  const float* vr = vecsbt + (size_t)bt * Tn;
  const float* sc = scales + b * Tn;
  const float* gr = gumbel + (size_t)bt * Tn;
  float y[3];
  float m = -3.0e38f;
#pragma unroll
  for (int u = 0; u < 3; ++u) {
    int j = lane + 64 * u;
    float v = -3.0e38f;
    if (j < Tn) v = (vr[j] * sc[j] + gr[j]) / TAUf;
    y[u] = v;
    m = fmaxf(m, v);
  }
#pragma unroll
  for (int off = 32; off; off >>= 1) m = fmaxf(m, __shfl_xor(m, off));
  float num = 0.f, den = 0.f;
#pragma unroll
  for (int u = 0; u < 3; ++u) {
    int j = lane + 64 * u;
    if (j < Tn) {
      float e = expf(y[u] - m);
      num = fmaf((float)j, e, num);
      den += e;
    }
  }
#pragma unroll
  for (int off = 32; off; off >>= 1) { num += __shfl_xor(num, off); den += __shfl_xor(den, off); }
  if (lane == 0) si[bt] = num / den;
}

// ---------------- grouping prep ----------------
__global__ void k_prep(const float* __restrict__ X, const float* __restrict__ si,
                       float* __restrict__ Y, int* __restrict__ gstart, int* __restrict__ gend,
                       int* __restrict__ ngr) {
  __shared__ int sgid[Tn];
  __shared__ float swt[Tn];
  int b = blockIdx.x, tid = threadIdx.x;
  const float* idx = si + b * Tn;
  if (tid == 0) {
    int g = 0;
    for (int t2 = 0; t2 < Tn; ++t2) {
      if (t2 > 0 && idx[t2] != idx[t2 - 1]) g++;
      sgid[t2] = g;
    }
    ngr[b] = g + 1;
  }
  if (tid < Tn) {
    float x = idx[tid] + 1.f;
    swt[tid] = x * (1.f / x);
  }
  __syncthreads();
  if (tid < Tn) {
    int g = sgid[tid];
    if (tid == 0 || sgid[tid - 1] != g) gstart[b * Tn + g] = tid;
    if (tid == Tn - 1 || sgid[tid + 1] != g) gend[b * Tn + g] = tid + 1;
  }
  for (int e = tid; e < Tn * Rn; e += 256) {
    int t2 = e / Rn;
    Y[(size_t)b * Tn * Rn + e] = X[(size_t)b * Tn * Rn + e] * swt[t2];
  }
}

// ---------------- pair LUT ----------------
__global__ void k_lut(int* __restrict__ lut) {
  int k = blockIdx.x * 256 + threadIdx.x;
  if (k >= NPAIRn) return;
  int r = 0, rem = k;
  while (rem >= Rn - 1 - r) { rem -= Rn - 1 - r; r++; }
  lut[2 * k] = r;
  lut[2 * k + 1] = r + 1 + rem;
}

// ---------------- per-(b,g) correlations -> padded ----------------
__global__ __launch_bounds__(256) void k_corr(const float* __restrict__ Y,
        const int* __restrict__ gstart, const int* __restrict__ gend,
        const int* __restrict__ ngr, const int* __restrict__ lut,
        float* __restrict__ pad) {
  int b = blockIdx.x / MAXGn, g = blockIdx.x % MAXGn;
  float* out = pad + (size_t)(b * MAXGn + g) * NPAIRn;
  int tid = threadIdx.x;
  if (g >= ngr[b]) {
    for (int k = tid; k < NPAIRn; k += 256) out[k] = 0.f;
    return;
  }
  __shared__ float Sg[Rn], Dg[Rn];
  int t0 = gstart[b * Tn + g], t1 = gend[b * Tn + g];
  const float* Yb = Y + (size_t)b * Tn * Rn;
  const float invT = 1.f / (float)Tn;
  if (tid < Rn) {
    float s = 0.f, p = 0.f;
    for (int t2 = t0; t2 < t1; ++t2) {
      float v = Yb[t2 * Rn + tid];
      s += v;
      p = fmaf(v, v, p);
    }
    Sg[tid] = s;
    Dg[tid] = fmaxf(p - s * s * invT, 0.f);
  }
  __syncthreads();
  for (int k = tid; k < NPAIRn; k += 256) {
    int r = lut[2 * k], sc = lut[2 * k + 1];
    float p = 0.f;
    for (int t2 = t0; t2 < t1; ++t2)
      p = fmaf(Yb[t2 * Rn + r], Yb[t2 * Rn + sc], p);
    float cov = p - Sg[r] * Sg[sc] * invT;
    float den = sqrtf(Dg[r] * Dg[sc]);
    float co = cov / ((den > 0.f) ? den : 1.f);
    co = fminf(fmaxf(co, -1.f), 1.f);
    out[k] = co;
  }
}

extern "C" void kernel_launch(void* const* d_in, const int* in_sizes, int n_in,
                              void* d_out, int out_size, void* d_ws, size_t ws_size,
                              hipStream_t stream) {
  const float* X  = (const float*)d_in[0];
  const float* cw = (const float*)d_in[1];
  const float* cb = (const float*)d_in[2];
  const float* w1 = (const float*)d_in[3];
  const float* b1 = (const float*)d_in[4];
  const float* w2 = (const float*)d_in[5];
  const float* b2 = (const float*)d_in[6];
  const float* gu = (const float*)d_in[7];

  float* out = (float*)d_out;
  float* padded = out;                                        // B*MAXG*NPAIR
  float* gm = out + (size_t)Bn * MAXGn * NPAIRn;              // B*T*T
  float* si = gm + (size_t)Bn * Tn * Tn;                      // B*T (real output)

  char* base = (char*)d_ws;
  float* oc = (float*)base;                                   // 90112
  float* Y = oc + 90112;                                      // 163328
  float* vecsbt = Y + 163328;                                 // 247808
  float* scales = vecsbt + 247808;                            // 1408
  int* gstart = (int*)(scales + 1408);                        // 1408
  int* gend = gstart + 1408;                                  // 1408
  int* ngr = gend + 1408;                                     // 8
  int* lut = ngr + 8;                                         // 13340
  float* fws = (float*)(base + ((2075280 + 255) & ~255));     // 8*109824 f32

  size_t eigh_lds = (size_t)(Tn * LDA + 1760) * 4 + 880 * 4;  // 135,168 B dynamic

  k_conv<<<(Bn * Tn * Cn + 255) / 256, 256, 0, stream>>>(X, cw, cb, oc);
  k_lut<<<(NPAIRn + 255) / 256, 256, 0, stream>>>(lut);
  k_mlp<<<Bn * Tn, 256, 0, stream>>>(oc, w1, b1, w2, b2, gm);
  k_eigh2<<<Bn, NT, eigh_lds, stream>>>(gm, fws, vecsbt, scales);
  k_softidx<<<Bn * Tn, 64, 0, stream>>>(vecsbt, scales, gu, si);
  k_prep<<<Bn, 256, 0, stream>>>(X, si, Y, gstart, gend, ngr);
  k_corr<<<Bn * MAXGn, 256, 0, stream>>>(Y, gstart, gend, ngr, lut, padded);
}

// Round 14
// 14876.624 us; speedup vs baseline: 1.7670x; 1.0158x over previous
//
#include <hip/hip_runtime.h>
#pragma clang fp contract(off)

#define Bn 8
#define Tn 176
#define Rn 116
#define Cn 64
#define Hn 200
#define NPAIRn 6670
#define MAXGn 176
#define TAUf 1e-4f
#define LD 176
#define LDA 177
#define LDZ 177
#define WPS 33
#define LEAF 22
#define NT 512
#define FEPS 5.9604645e-08f
#define FEPS2 3.5527137e-15f
#define FSAFMIN 1.17549435e-38f

// ---------------- f32 LAPACK helpers ----------------
static __device__ __forceinline__ float f_sign(float a, float b) {
  return (b >= 0.0f) ? fabsf(a) : -fabsf(a);
}
static __device__ __forceinline__ float f_lapy2(float x, float y) {
  float xa = fabsf(x), ya = fabsf(y);
  float w = fmaxf(xa, ya), z = fminf(xa, ya);
  if (z == 0.0f) return w;
  float q = z / w;
  return w * sqrtf(1.0f + q * q);
}
static __device__ void f_lartg(float f, float g, float* c, float* s, float* r) {
  if (g == 0.0f) { *c = 1.0f; *s = 0.0f; *r = f; }
  else if (f == 0.0f) { *c = 0.0f; *s = (g >= 0.0f) ? 1.0f : -1.0f; *r = fabsf(g); }
  else {
    float d = sqrtf(f * f + g * g);
    float rr = (f >= 0.0f) ? d : -d;
    *c = f / rr; *s = g / rr; *r = rr;
  }
}
static __device__ float f_snrm2_strided(const float* x, int n, int stride) {
  float scale = 0.0f, ssq = 1.0f;
  for (int i = 0; i < n; i++) {
    float ax = fabsf(x[i * stride]);
    if (ax != 0.0f) {
      if (scale < ax) {
        float q = scale / ax;
        ssq = 1.0f + ssq * (q * q);
        scale = ax;
      } else {
        float q = ax / scale;
        ssq = ssq + q * q;
      }
    }
  }
  return scale * sqrtf(ssq);
}
static __device__ void f_laev2(float a, float b, float c,
                               float* rt1, float* rt2, float* cs1, float* sn1) {
  float sm = a + c, df = a - c, adf = fabsf(df), tb = b + b, ab = fabsf(tb);
  float acmx, acmn;
  if (fabsf(a) > fabsf(c)) { acmx = a; acmn = c; } else { acmx = c; acmn = a; }
  float rt;
  if (adf > ab) { float q = ab / adf; rt = adf * sqrtf(1.0f + q * q); }
  else if (adf < ab) { float q = adf / ab; rt = ab * sqrtf(1.0f + q * q); }
  else rt = ab * sqrtf(2.0f);
  int sgn1;
  if (sm < 0.0f) { *rt1 = 0.5f * (sm - rt); sgn1 = -1; *rt2 = (acmx / *rt1) * acmn - (b / *rt1) * b; }
  else if (sm > 0.0f) { *rt1 = 0.5f * (sm + rt); sgn1 = 1; *rt2 = (acmx / *rt1) * acmn - (b / *rt1) * b; }
  else { *rt1 = 0.5f * rt; *rt2 = -0.5f * rt; sgn1 = 1; }
  float cs; int sgn2;
  if (df >= 0.0f) { cs = df + rt; sgn2 = 1; } else { cs = df - rt; sgn2 = -1; }
  float acs = fabsf(cs);
  if (acs > ab) { float ct = -tb / cs; *sn1 = 1.0f / sqrtf(1.0f + ct * ct); *cs1 = ct * (*sn1); }
  else {
    if (ab == 0.0f) { *cs1 = 1.0f; *sn1 = 0.0f; }
    else { float tn = -cs / tb; *cs1 = 1.0f / sqrtf(1.0f + tn * tn); *sn1 = tn * (*cs1); }
  }
  if (sgn1 == sgn2) { float tn = *cs1; *cs1 = -(*sn1); *sn1 = tn; }
}
static __device__ void f_lamrg(int n1, int n2, const float* a, int dtrd1, int dtrd2, int* index) {
  int n1sv = n1, n2sv = n2;
  int ind1 = (dtrd1 > 0) ? 0 : n1 - 1;
  int ind2 = (dtrd2 > 0) ? n1 : n1 + n2 - 1;
  int i = 0;
  while (n1sv > 0 && n2sv > 0) {
    if (a[ind1] <= a[ind2]) { index[i++] = ind1; ind1 += dtrd1; n1sv--; }
    else { index[i++] = ind2; ind2 += dtrd2; n2sv--; }
  }
  while (n2sv > 0) { index[i++] = ind2; ind2 += dtrd2; n2sv--; }
  while (n1sv > 0) { index[i++] = ind1; ind1 += dtrd1; n1sv--; }
}
static __device__ void f_laed5(int i, const float* d, const float* z, float rho,
                               float* dlam, float* u0, float* u1) {
  float del = d[1] - d[0];
  float del1, del2;
  if (i == 0) {
    float w = 1.0f + 2.0f * rho * (z[1] * z[1] - z[0] * z[0]) / del;
    if (w > 0.0f) {
      float b = del + rho * (z[0] * z[0] + z[1] * z[1]);
      float c = rho * z[0] * z[0] * del;
      float tau = 2.0f * c / (b + sqrtf(fabsf(b * b - 4.0f * c)));
      *dlam = d[0] + tau;
      del1 = -z[0] / tau; del2 = z[1] / (del - tau);
    } else {
      float b = -del + rho * (z[0] * z[0] + z[1] * z[1]);
      float c = rho * z[1] * z[1] * del;
      float tau;
      if (b > 0.0f) tau = -2.0f * c / (b + sqrtf(b * b + 4.0f * c));
      else tau = (b - sqrtf(b * b + 4.0f * c)) / 2.0f;
      *dlam = d[1] + tau;
      del1 = -z[0] / (del + tau); del2 = -z[1] / tau;
    }
  } else {
    float b = -del + rho * (z[0] * z[0] + z[1] * z[1]);
    float c = rho * z[1] * z[1] * del;
    float tau;
    if (b > 0.0f) tau = (b + sqrtf(b * b + 4.0f * c)) / 2.0f;
    else tau = 2.0f * c / (-b + sqrtf(b * b + 4.0f * c));
    *dlam = d[1] + tau;
    del1 = -z[0] / (del + tau); del2 = -z[1] / tau;
  }
  float t = sqrtf(del1 * del1 + del2 * del2);
  *u0 = del1 / t; *u1 = del2 / t;
}

// ---------------- netlib slaed6 (f32) ----------------
static __device__ void laed6_net(int kniter, bool orgati, float rho, const float* dd,
                                 const float* zz, float finit, float* tau_out) {
  const float eps = FEPS;
  float lbd, ubd;
  if (orgati) { lbd = dd[1]; ubd = dd[2]; }
  else { lbd = dd[0]; ubd = dd[1]; }
  if (finit < 0.0f) lbd = 0.0f; else ubd = 0.0f;
  float tau = 0.0f;
  if (kniter == 2) {
    float temp, a, b, c;
    if (orgati) {
      temp = (dd[2] + dd[1]) / 2.0f;
      c = rho + zz[0] / ((dd[0] - dd[1]) - temp);
      a = c * (dd[1] + dd[2]) + zz[1] + zz[2];
      b = c * dd[1] * dd[2] + zz[1] * dd[2] + zz[2] * dd[1];
    } else {
      temp = (dd[0] + dd[1]) / 2.0f;
      c = rho + zz[2] / ((dd[2] - dd[1]) - temp);
      a = c * (dd[0] + dd[1]) + zz[0] + zz[1];
      b = c * dd[0] * dd[1] + zz[0] * dd[1] + zz[1] * dd[0];
    }
    temp = fmaxf(fmaxf(fabsf(a), fabsf(b)), fabsf(c));
    a /= temp; b /= temp; c /= temp;
    if (c == 0.0f) tau = b / a;
    else if (a <= 0.0f) tau = (a - sqrtf(fabsf(a * a - 4.0f * b * c))) / (2.0f * c);
    else tau = 2.0f * b / (a + sqrtf(fabsf(a * a - 4.0f * b * c)));
    if (tau < lbd || tau > ubd) tau = (lbd + ubd) / 2.0f;
    if (dd[0] == tau || dd[1] == tau || dd[2] == tau) {
      tau = 0.0f;
    } else {
      temp = finit + tau * zz[0] / (dd[0] * (dd[0] - tau))
                   + tau * zz[1] / (dd[1] * (dd[1] - tau))
                   + tau * zz[2] / (dd[2] * (dd[2] - tau));
      if (temp <= 0.0f) lbd = tau; else ubd = tau;
      if (fabsf(finit) <= fabsf(temp)) tau = 0.0f;
    }
  }
  const float small1 = 2.2737367544323206e-13f;
  const float sminv1 = 4398046511104.0f;
  const float small2 = small1 * small1;
  const float sminv2 = sminv1 * sminv1;
  float temp;
  if (orgati) temp = fminf(fabsf(dd[1] - tau), fabsf(dd[2] - tau));
  else temp = fminf(fabsf(dd[0] - tau), fabsf(dd[1] - tau));
  bool doscale = false;
  float sclfac = 1.0f, sclinv = 1.0f;
  float dscale[3], zscale[3];
  if (temp <= small1) {
    doscale = true;
    if (temp <= small2) { sclfac = sminv2; sclinv = small2; }
    else { sclfac = sminv1; sclinv = small1; }
    for (int i = 0; i < 3; i++) { dscale[i] = dd[i] * sclfac; zscale[i] = zz[i] * sclfac; }
    tau *= sclfac; lbd *= sclfac; ubd *= sclfac;
  } else {
    for (int i = 0; i < 3; i++) { dscale[i] = dd[i]; zscale[i] = zz[i]; }
  }
  float fc = 0.0f, df = 0.0f, ddf = 0.0f;
  for (int i = 0; i < 3; i++) {
    float t1 = 1.0f / (dscale[i] - tau);
    float t2 = zscale[i] * t1;
    float t3 = t2 * t1;
    float t4 = t3 * t1;
    fc += t2 / dscale[i];
    df += t3;
    ddf += t4;
  }
  float f = finit + tau * fc;
  if (fabsf(f) > 0.0f) {
    if (f <= 0.0f) lbd = tau; else ubd = tau;
    for (int niter = 2; niter <= 40; ++niter) {
      float t1_, t2_;
      if (orgati) { t1_ = dscale[1] - tau; t2_ = dscale[2] - tau; }
      else { t1_ = dscale[0] - tau; t2_ = dscale[1] - tau; }
      float a = (t1_ + t2_) * f - t1_ * t2_ * df;
      float b = t1_ * t2_ * f;
      float c = f - (t1_ + t2_) * df + t1_ * t2_ * ddf;
      float tm = fmaxf(fmaxf(fabsf(a), fabsf(b)), fabsf(c));
      a /= tm; b /= tm; c /= tm;
      float eta;
      if (c == 0.0f) eta = b / a;
      else if (a <= 0.0f) eta = (a - sqrtf(fabsf(a * a - 4.0f * b * c))) / (2.0f * c);
      else eta = 2.0f * b / (a + sqrtf(fabsf(a * a - 4.0f * b * c)));
      if (f * eta >= 0.0f) eta = -f / df;
      tau = tau + eta;
      if (tau < lbd || tau > ubd) tau = (lbd + ubd) / 2.0f;
      fc = 0.0f; df = 0.0f; ddf = 0.0f;
      float erretm = 0.0f;
      bool hitpole = false;
      for (int i = 0; i < 3; i++) {
        float dt = dscale[i] - tau;
        if (dt != 0.0f) {
          float t1 = 1.0f / dt;
          float t2 = zscale[i] * t1;
          float t3 = t2 * t1;
          float t4 = t3 * t1;
          float t5 = t2 / dscale[i];
          fc += t5;
          erretm += fabsf(t5);
          df += t3;
          ddf += t4;
        } else { hitpole = true; break; }
      }
      if (hitpole) break;
      f = finit + tau * fc;
      erretm = 8.0f * (fabsf(finit) + fabsf(tau) * erretm) + fabsf(tau) * df;
      if (fabsf(f) <= eps * erretm) break;
      if (f <= 0.0f) lbd = tau; else ubd = tau;
    }
  }
  if (doscale) tau *= sclinv;
  *tau_out = tau;
}

// ---------------- netlib slaed4 (f32); delta strided by LD (global Um) ----------------
static __device__ void laed4_net(int K, int j0, const float* d, const float* z, float rho,
                                 float* dlam, float* delta) {
#define DL(i) delta[(size_t)(i) * LD]
  const float eps = FEPS;
  float rhoinv = 1.0f / rho;
  if (j0 == K - 1) {
    int ii = K - 2;
    float midpt = rho / 2.0f;
    for (int j = 0; j < K; j++) DL(j) = (d[j] - d[K - 1]) - midpt;
    float psi = 0.0f;
    for (int j = 0; j < K - 2; j++) psi += z[j] * z[j] / DL(j);
    float c = rhoinv + psi;
    float w = c + z[ii] * z[ii] / DL(ii) + z[K - 1] * z[K - 1] / DL(K - 1);
    float dltlb, dltub, tau;
    if (w <= 0.0f) {
      float temp = z[K - 2] * z[K - 2] / (d[K - 1] - d[K - 2] + rho) + z[K - 1] * z[K - 1] / rho;
      if (c <= temp) tau = rho;
      else {
        float del = d[K - 1] - d[K - 2];
        float a = -c * del + z[K - 2] * z[K - 2] + z[K - 1] * z[K - 1];
        float b = z[K - 1] * z[K - 1] * del;
        if (a < 0.0f) tau = 2.0f * b / (sqrtf(a * a + 4.0f * b * c) - a);
        else tau = (a + sqrtf(a * a + 4.0f * b * c)) / (2.0f * c);
      }
      dltlb = midpt; dltub = rho;
    } else {
      float del = d[K - 1] - d[K - 2];
      float a = -c * del + z[K - 2] * z[K - 2] + z[K - 1] * z[K - 1];
      float b = z[K - 1] * z[K - 1] * del;
      if (a < 0.0f) tau = 2.0f * b / (sqrtf(a * a + 4.0f * b * c) - a);
      else tau = (a + sqrtf(a * a + 4.0f * b * c)) / (2.0f * c);
      dltlb = 0.0f; dltub = midpt;
    }
    for (int j = 0; j < K; j++) DL(j) = (d[j] - d[K - 1]) - tau;
    float dpsi = 0.0f, erretm = 0.0f;
    psi = 0.0f;
    for (int j = 0; j <= ii; j++) {
      float t = z[j] / DL(j);
      psi += z[j] * t; dpsi += t * t; erretm += psi;
    }
    erretm = fabsf(erretm);
    float t = z[K - 1] / DL(K - 1);
    float phi = z[K - 1] * t, dphi = t * t;
    erretm = 8.0f * (-phi - psi) + erretm - phi + rhoinv + fabsf(tau) * (dpsi + dphi);
    w = rhoinv + phi + psi;
    if (fabsf(w) <= eps * erretm) { *dlam = d[K - 1] + tau; return; }
    if (w <= 0.0f) dltlb = fmaxf(dltlb, tau); else dltub = fminf(dltub, tau);
    for (int niter = 2; niter <= 30; ++niter) {
      float c2 = w - DL(K - 2) * dpsi - DL(K - 1) * dphi;
      float a = (DL(K - 2) + DL(K - 1)) * w - DL(K - 2) * DL(K - 1) * (dpsi + dphi);
      float b = DL(K - 2) * DL(K - 1) * w;
      float eta;
      if (niter == 2) {
        if (c2 < 0.0f) c2 = fabsf(c2);
        if (c2 == 0.0f) eta = dltub - tau;
        else if (a >= 0.0f) eta = (a + sqrtf(fabsf(a * a - 4.0f * b * c2))) / (2.0f * c2);
        else eta = 2.0f * b / (a - sqrtf(fabsf(a * a - 4.0f * b * c2)));
      } else {
        if (a >= 0.0f) eta = (a + sqrtf(fabsf(a * a - 4.0f * b * c2))) / (2.0f * c2);
        else eta = 2.0f * b / (a - sqrtf(fabsf(a * a - 4.0f * b * c2)));
      }
      if (w * eta > 0.0f) eta = -w / (dpsi + dphi);
      float tmp = tau + eta;
      if (tmp > dltub || tmp < dltlb) {
        if (w < 0.0f) eta = (dltub - tau) / 2.0f;
        else eta = (dltlb - tau) / 2.0f;
      }
      for (int j = 0; j < K; j++) DL(j) -= eta;
      tau += eta;
      dpsi = 0.0f; psi = 0.0f; erretm = 0.0f;
      for (int j = 0; j <= ii; j++) {
        float tt = z[j] / DL(j);
        psi += z[j] * tt; dpsi += tt * tt; erretm += psi;
      }
      erretm = fabsf(erretm);
      t = z[K - 1] / DL(K - 1);
      phi = z[K - 1] * t; dphi = t * t;
      erretm = 8.0f * (-phi - psi) + erretm - phi + rhoinv + fabsf(tau) * (dpsi + dphi);
      w = rhoinv + phi + psi;
      if (fabsf(w) <= eps * erretm) break;
      if (w <= 0.0f) dltlb = fmaxf(dltlb, tau); else dltub = fminf(dltub, tau);
    }
    *dlam = d[K - 1] + tau;
    return;
  }
  int ip1 = j0 + 1;
  float del = d[ip1] - d[j0];
  float midpt = del / 2.0f;
  for (int j = 0; j < K; j++) DL(j) = (d[j] - d[j0]) - midpt;
  float psi = 0.0f;
  for (int j = 0; j < j0; j++) psi += z[j] * z[j] / DL(j);
  float phi = 0.0f;
  for (int j = K - 1; j >= j0 + 2; j--) phi += z[j] * z[j] / DL(j);
  float c = rhoinv + psi + phi;
  float w = c + z[j0] * z[j0] / DL(j0) + z[ip1] * z[ip1] / DL(ip1);
  bool orgati;
  float tau, dltlb, dltub;
  if (w > 0.0f) {
    orgati = true;
    float a = c * del + z[j0] * z[j0] + z[ip1] * z[ip1];
    float b = z[j0] * z[j0] * del;
    if (a > 0.0f) tau = 2.0f * b / (a + sqrtf(fabsf(a * a - 4.0f * b * c)));
    else tau = (a - sqrtf(fabsf(a * a - 4.0f * b * c))) / (2.0f * c);
    dltlb = 0.0f; dltub = midpt;
  } else {
    orgati = false;
    float a = c * del - z[j0] * z[j0] - z[ip1] * z[ip1];
    float b = z[ip1] * z[ip1] * del;
    if (a < 0.0f) tau = 2.0f * b / (a - sqrtf(fabsf(a * a + 4.0f * b * c)));
    else tau = -(a + sqrtf(fabsf(a * a + 4.0f * b * c))) / (2.0f * c);
    dltlb = -midpt; dltub = 0.0f;
  }
  int org = orgati ? j0 : ip1;
  for (int j = 0; j < K; j++) DL(j) = (d[j] - d[org]) - tau;
  int ii = org;
  int iim1 = ii - 1, iip1 = ii + 1;
  float dpsi = 0.0f, erretm = 0.0f;
  psi = 0.0f;
  for (int j = 0; j <= ii - 1; j++) {
    float t = z[j] / DL(j);
    psi += z[j] * t; dpsi += t * t; erretm += psi;
  }
  erretm = fabsf(erretm);
  float dphi = 0.0f;
  phi = 0.0f;
  for (int j = K - 1; j >= ii + 1; j--) {
    float t = z[j] / DL(j);
    phi += z[j] * t; dphi += t * t; erretm += phi;
  }
  w = rhoinv + phi + psi;
  bool swtch3 = false;
  if (orgati) { if (w < 0.0f) swtch3 = true; }
  else { if (w > 0.0f) swtch3 = true; }
  if (ii == 0 || ii == K - 1) swtch3 = false;
  float t = z[ii] / DL(ii);
  float dw = dpsi + dphi + t * t;
  t = z[ii] * t;
  w += t;
  erretm = 8.0f * (phi - psi) + erretm + 2.0f * rhoinv + 3.0f * fabsf(t) + fabsf(tau) * dw;
  if (fabsf(w) <= eps * erretm) { *dlam = d[org] + tau; return; }
  if (w <= 0.0f) dltlb = fmaxf(dltlb, tau); else dltub = fminf(dltub, tau);
  float eta;
  {
    if (!swtch3) {
      float c2, a, b;
      if (orgati) {
        float q = z[j0] / DL(j0);
        c2 = w - DL(ip1) * dw - (d[j0] - d[ip1]) * (q * q);
      } else {
        float q = z[ip1] / DL(ip1);
        c2 = w - DL(j0) * dw - (d[ip1] - d[j0]) * (q * q);
      }
      a = (DL(j0) + DL(ip1)) * w - DL(j0) * DL(ip1) * dw;
      b = DL(j0) * DL(ip1) * w;
      if (c2 == 0.0f) {
        if (a == 0.0f) {
          if (orgati) a = z[j0] * z[j0] + DL(ip1) * DL(ip1) * (dpsi + dphi);
          else a = z[ip1] * z[ip1] + DL(j0) * DL(j0) * (dpsi + dphi);
        }
        eta = b / a;
      } else if (a <= 0.0f) eta = (a - sqrtf(fabsf(a * a - 4.0f * b * c2))) / (2.0f * c2);
      else eta = 2.0f * b / (a + sqrtf(fabsf(a * a - 4.0f * b * c2)));
    } else {
      float zz3[3], dd3[3];
      float temp = rhoinv + psi + phi;
      if (orgati) {
        float t1 = z[iim1] / DL(iim1);
        t1 = t1 * t1;
        float c2 = temp - DL(iip1) * (dpsi + dphi) - (d[iim1] - d[iip1]) * t1;
        zz3[0] = z[iim1] * z[iim1];
        zz3[2] = DL(iip1) * DL(iip1) * ((dpsi - t1) + dphi);
        zz3[1] = z[ii] * z[ii];
        dd3[0] = DL(iim1); dd3[1] = DL(ii); dd3[2] = DL(iip1);
        laed6_net(2, orgati, c2, dd3, zz3, w, &eta);
      } else {
        float t1 = z[iip1] / DL(iip1);
        t1 = t1 * t1;
        float c2 = temp - DL(iim1) * (dpsi + dphi) - (d[iip1] - d[iim1]) * t1;
        zz3[0] = DL(iim1) * DL(iim1) * (dpsi + (dphi - t1));
        zz3[2] = z[iip1] * z[iip1];
        zz3[1] = z[ii] * z[ii];
        dd3[0] = DL(iim1); dd3[1] = DL(ii); dd3[2] = DL(iip1);
        laed6_net(2, orgati, c2, dd3, zz3, w, &eta);
      }
    }
    if (w * eta >= 0.0f) eta = -w / dw;
    float tmp = tau + eta;
    if (tmp > dltub || tmp < dltlb) {
      if (w < 0.0f) eta = (dltub - tau) / 2.0f;
      else eta = (dltlb - tau) / 2.0f;
    }
  }
  float prew = w;
  for (int j = 0; j < K; j++) DL(j) -= eta;
  tau += eta;
  dpsi = 0.0f; psi = 0.0f; erretm = 0.0f;
  for (int j = 0; j <= ii - 1; j++) {
    float tt = z[j] / DL(j);
    psi += z[j] * tt; dpsi += tt * tt; erretm += psi;
  }
  erretm = fabsf(erretm);
  dphi = 0.0f; phi = 0.0f;
  for (int j = K - 1; j >= ii + 1; j--) {
    float tt = z[j] / DL(j);
    phi += z[j] * tt; dphi += tt * tt; erretm += phi;
  }
  w = rhoinv + phi + psi;
  t = z[ii] / DL(ii);
  dw = dpsi + dphi + t * t;
  t = z[ii] * t;
  w += t;
  erretm = 8.0f * (phi - psi) + erretm + 2.0f * rhoinv + 3.0f * fabsf(t) + fabsf(tau) * dw;
  bool swtch = false;
  if (orgati) { if (-w > fabsf(prew) / 10.0f) swtch = true; }
  else { if (w > fabsf(prew) / 10.0f) swtch = true; }
  for (int niter = 3; niter <= 30; ++niter) {
    if (fabsf(w) <= eps * erretm) break;
    if (w <= 0.0f) dltlb = fmaxf(dltlb, tau); else dltub = fminf(dltub, tau);
    if (!swtch3) {
      float c2, a, b;
      if (!swtch) {
        if (orgati) {
          float q = z[j0] / DL(j0);
          c2 = w - DL(ip1) * dw - (d[j0] - d[ip1]) * (q * q);
        } else {
          float q = z[ip1] / DL(ip1);
          c2 = w - DL(j0) * dw - (d[ip1] - d[j0]) * (q * q);
        }
      } else {
        float tt = z[ii] / DL(ii);
        if (orgati) dpsi += tt * tt;
        else dphi += tt * tt;
        c2 = w - DL(j0) * dpsi - DL(ip1) * dphi;
      }
      a = (DL(j0) + DL(ip1)) * w - DL(j0) * DL(ip1) * dw;
      b = DL(j0) * DL(ip1) * w;
      if (c2 == 0.0f) {
        if (a == 0.0f) {
          if (!swtch) {
            if (orgati) a = z[j0] * z[j0] + DL(ip1) * DL(ip1) * (dpsi + dphi);
            else a = z[ip1] * z[ip1] + DL(j0) * DL(j0) * (dpsi + dphi);
          } else a = DL(j0) * DL(j0) * dpsi + DL(ip1) * DL(ip1) * dphi;
        }
        eta = b / a;
      } else if (a <= 0.0f) eta = (a - sqrtf(fabsf(a * a - 4.0f * b * c2))) / (2.0f * c2);
      else eta = 2.0f * b / (a + sqrtf(fabsf(a * a - 4.0f * b * c2)));
    } else {
      float zz3[3], dd3[3];
      float t1 = rhoinv + psi + phi;
      if (swtch) {
        float c2 = t1 - DL(iim1) * dpsi - DL(iip1) * dphi;
        zz3[0] = DL(iim1) * DL(iim1) * dpsi;
        zz3[2] = DL(iip1) * DL(iip1) * dphi;
        zz3[1] = z[ii] * z[ii];
        dd3[0] = DL(iim1); dd3[1] = DL(ii); dd3[2] = DL(iip1);
        laed6_net(niter, orgati, c2, dd3, zz3, w, &eta);
      } else {
        if (orgati) {
          float t2 = z[iim1] / DL(iim1);
          t2 = t2 * t2;
          float c2 = t1 - DL(iip1) * (dpsi + dphi) - (d[iim1] - d[iip1]) * t2;
          zz3[0] = z[iim1] * z[iim1];
          zz3[2] = DL(iip1) * DL(iip1) * ((dpsi - t2) + dphi);
          zz3[1] = z[ii] * z[ii];
          dd3[0] = DL(iim1); dd3[1] = DL(ii); dd3[2] = DL(iip1);
          laed6_net(niter, orgati, c2, dd3, zz3, w, &eta);
        } else {
          float t2 = z[iip1] / DL(iip1);
          t2 = t2 * t2;
          float c2 = t1 - DL(iim1) * (dpsi + dphi) - (d[iip1] - d[iim1]) * t2;
          zz3[0] = DL(iim1) * DL(iim1) * (dpsi + (dphi - t2));
          zz3[2] = z[iip1] * z[iip1];
          zz3[1] = z[ii] * z[ii];
          dd3[0] = DL(iim1); dd3[1] = DL(ii); dd3[2] = DL(iip1);
          laed6_net(niter, orgati, c2, dd3, zz3, w, &eta);
        }
      }
    }
    if (w * eta >= 0.0f) eta = -w / dw;
    {
      float tmp = tau + eta;
      if (tmp > dltub || tmp < dltlb) {
        if (w < 0.0f) eta = (dltub - tau) / 2.0f;
        else eta = (dltlb - tau) / 2.0f;
      }
    }
    for (int j = 0; j < K; j++) DL(j) -= eta;
    tau += eta;
    prew = w;
    dpsi = 0.0f; psi = 0.0f; erretm = 0.0f;
    for (int j = 0; j <= ii - 1; j++) {
      float tt = z[j] / DL(j);
      psi += z[j] * tt; dpsi += tt * tt; erretm += psi;
    }
    erretm = fabsf(erretm);
    dphi = 0.0f; phi = 0.0f;
    for (int j = K - 1; j >= ii + 1; j--) {
      float tt = z[j] / DL(j);
      phi += z[j] * tt; dphi += tt * tt; erretm += phi;
    }
    w = rhoinv + phi + psi;
    t = z[ii] / DL(ii);
    dw = dpsi + dphi + t * t;
    t = z[ii] * t;
    w += t;
    erretm = 8.0f * (phi - psi) + erretm + 2.0f * rhoinv + 3.0f * fabsf(t) + fabsf(tau) * dw;
    if (w * prew > 0.0f && fabsf(w) > fabsf(prew) / 10.0f) swtch = !swtch;
  }
  *dlam = d[org] + tau;
#undef DL
}

// ---------------- ssteqr port, serial, f32 ----------------
static __device__ void steqr_f(int n, float* d, float* e, float* Z, int ldz) {
  if (n <= 1) return;
  float work_c[LEAF + 2], work_s[LEAF + 2];
  int nmaxit = n * 30, jtot = 0;
  int l1 = 0;
  while (true) {
    if (l1 > n - 1) break;
    if (l1 > 0) e[l1 - 1] = 0.0f;
    int m;
    for (m = l1; m <= n - 2; ++m) {
      float tst = fabsf(e[m]);
      if (tst == 0.0f) break;
      if (tst <= (sqrtf(fabsf(d[m])) * sqrtf(fabsf(d[m + 1]))) * FEPS) { e[m] = 0.0f; break; }
    }
    int l = l1, lend = m;
    l1 = m + 1;
    if (lend == l) continue;
    if (fabsf(d[lend]) < fabsf(d[l])) { int t = lend; lend = l; l = t; }
    if (lend > l) {
      while (true) {
        int mm;
        if (l != lend) {
          for (mm = l; mm <= lend - 1; ++mm) {
            float tst = fabsf(e[mm]); tst = tst * tst;
            if (tst <= (FEPS2 * fabsf(d[mm])) * fabsf(d[mm + 1]) + FSAFMIN) break;
          }
        } else mm = lend;
        if (mm < lend) e[mm] = 0.0f;
        float p = d[l];
        if (mm == l) { d[l] = p; l = l + 1; if (l <= lend) continue; else break; }
        if (mm == l + 1) {
          float rt1, rt2, c, s;
          f_laev2(d[l], e[l], d[l + 1], &rt1, &rt2, &c, &s);
          for (int r = 0; r < n; r++) {
            float t1 = Z[r * ldz + l + 1], t0 = Z[r * ldz + l];
            Z[r * ldz + l + 1] = c * t1 - s * t0;
            Z[r * ldz + l] = s * t1 + c * t0;
          }
          d[l] = rt1; d[l + 1] = rt2; e[l] = 0.0f;
          l += 2; if (l <= lend) continue; else break;
        }
        if (jtot == nmaxit) break;
        jtot++;
        float g = (d[l + 1] - p) / (2.0f * e[l]);
        float r = f_lapy2(g, 1.0f);
        g = d[mm] - p + e[l] / (g + f_sign(r, g));
        float s = 1.0f, c = 1.0f; p = 0.0f;
        for (int i = mm - 1; i >= l; --i) {
          float f = s * e[i], bb = c * e[i];
          f_lartg(g, f, &c, &s, &r);
          if (i != mm - 1) e[i + 1] = r;
          g = d[i + 1] - p;
          r = (d[i] - g) * s + 2.0f * c * bb;
          p = s * r;
          d[i + 1] = g + p;
          g = c * r - bb;
          work_c[i] = c; work_s[i] = -s;
        }
        for (int j = mm - l; j >= 1; --j) {
          float cj = work_c[l + j - 1], sj = work_s[l + j - 1];
          for (int rr = 0; rr < n; rr++) {
            float t1 = Z[rr * ldz + l + j], t0 = Z[rr * ldz + l + j - 1];
            Z[rr * ldz + l + j] = cj * t1 - sj * t0;
            Z[rr * ldz + l + j - 1] = sj * t1 + cj * t0;
          }
        }
        d[l] -= p; e[l] = g;
      }
    } else {
      while (true) {
        int mm;
        if (l != lend) {
          for (mm = l; mm >= lend + 1; --mm) {
            float tst = fabsf(e[mm - 1]); tst = tst * tst;
            if (tst <= (FEPS2 * fabsf(d[mm])) * fabsf(d[mm - 1]) + FSAFMIN) break;
          }
        } else mm = lend;
        if (mm > lend) e[mm - 1] = 0.0f;
        float p = d[l];
        if (mm == l) { d[l] = p; l = l - 1; if (l >= lend) continue; else break; }
        if (mm == l - 1) {
          float rt1, rt2, c, s;
          f_laev2(d[l - 1], e[l - 1], d[l], &rt1, &rt2, &c, &s);
          for (int r = 0; r < n; r++) {
            float t1 = Z[r * ldz + l], t0 = Z[r * ldz + l - 1];
            Z[r * ldz + l] = c * t1 - s * t0;
            Z[r * ldz + l - 1] = s * t1 + c * t0;
          }
          d[l - 1] = rt1; d[l] = rt2; e[l - 1] = 0.0f;
          l -= 2; if (l >= lend) continue; else break;
        }
        if (jtot == nmaxit) break;
        jtot++;
        float g = (d[l - 1] - p) / (2.0f * e[l - 1]);
        float r = f_lapy2(g, 1.0f);
        g = d[mm] - p + e[l - 1] / (g + f_sign(r, g));
        float s = 1.0f, c = 1.0f; p = 0.0f;
        for (int i = mm; i <= l - 1; ++i) {
          float f = s * e[i], bb = c * e[i];
          f_lartg(g, f, &c, &s, &r);
          if (i != mm) e[i - 1] = r;
          g = d[i] - p;
          r = (d[i + 1] - g) * s + 2.0f * c * bb;
          p = s * r;
          d[i] = g + p;
          g = c * r - bb;
          work_c[i] = c; work_s[i] = s;
        }
        for (int j = 1; j <= l - mm; ++j) {
          float cj = work_c[mm + j - 1], sj = work_s[mm + j - 1];
          for (int rr = 0; rr < n; rr++) {
            float t1 = Z[rr * ldz + mm + j], t0 = Z[rr * ldz + mm + j - 1];
            Z[rr * ldz + mm + j] = cj * t1 - sj * t0;
            Z[rr * ldz + mm + j - 1] = sj * t1 + cj * t0;
          }
        }
        d[l] -= p; e[l - 1] = g;
      }
    }
  }
  for (int ii = 1; ii < n; ++ii) {
    int i = ii - 1, k = i; float p = d[i];
    for (int j = ii; j < n; ++j) if (d[j] < p) { k = j; p = d[j]; }
    if (k != i) {
      d[k] = d[i]; d[i] = p;
      for (int r = 0; r < n; r++) { float t = Z[r * ldz + i]; Z[r * ldz + i] = Z[r * ldz + k]; Z[r * ldz + k] = t; }
    }
  }
}

// ---------------- slaed1/2/3-equivalent merge; Zb in LDS (ldz=LDZ), Givens record+parallel-replay ----------------
static __device__ void laed1_f(int tid, int nb, int n1, int off, float rho_in,
    float* Zb, float* Qt, float* Um, float* dd,
    float* dlamda, float* w2, float* lamv, float* wtv, float* zv, float* dnew, float* dsort,
    int* indxq, int* indxp, int* indxc, int* indxm,
    int* rotP, int* rotN, float* rotC, float* rotS,
    float* shs, int* shi) {
  int n2 = nb - n1;
  if (tid == 0) {
    float rho = rho_in;
    int cnt = 0;
    for (int i = 0; i < n1; i++) zv[i] = Zb[(off + n1 - 1) * LDZ + off + i];
    for (int i = 0; i < n2; i++) zv[n1 + i] = Zb[(off + n1) * LDZ + off + n1 + i];
    if (rho < 0.0f) for (int i = n1; i < nb; i++) zv[i] = -zv[i];
    const float isq2 = 0.70710678118654752440f;
    for (int i = 0; i < nb; i++) zv[i] *= isq2;
    rho = fabsf(2.0f * rho);
    for (int i = n1; i < nb; i++) indxq[off + i] += n1;
    for (int i = 0; i < nb; i++) dsort[i] = dd[off + indxq[off + i]];
    f_lamrg(n1, n2, dsort, 1, 1, indxc);
    for (int i = 0; i < nb; i++) indxm[i] = indxq[off + indxc[i]];
    float zmax = 0.0f, dmax = 0.0f;
    for (int i = 0; i < nb; i++) {
      float az = fabsf(zv[i]); if (az > zmax) zmax = az;
      float ad = fabsf(dd[off + i]); if (ad > dmax) dmax = ad;
    }
    float tol = 8.0f * FEPS * ((dmax > zmax) ? dmax : zmax);
    int K = 0;
    if (rho * zmax <= tol) {
      for (int j = 0; j < nb; j++) indxp[j] = indxm[j];
    } else {
      int K2 = nb; int pj = 0; int j; bool found = false;
      for (j = 0; j < nb; j++) {
        int nj = indxm[j];
        if (rho * fabsf(zv[nj]) <= tol) { K2--; indxp[K2] = nj; if (j == nb - 1) break; }
        else { pj = nj; found = true; break; }
      }
      if (found) {
        while (true) {
          j++;
          if (j >= nb) break;
          int nj = indxm[j];
          if (rho * fabsf(zv[nj]) <= tol) { K2--; indxp[K2] = nj; }
          else {
            float s_ = zv[pj], c_ = zv[nj];
            float tau_ = f_lapy2(c_, s_);
            float t_ = dd[off + nj] - dd[off + pj];
            c_ /= tau_; s_ = -s_ / tau_;
            if (fabsf(t_ * c_ * s_) <= tol) {
              zv[nj] = tau_; zv[pj] = 0.0f;
              rotP[cnt] = pj; rotN[cnt] = nj; rotC[cnt] = c_; rotS[cnt] = s_; cnt++;
              float t2 = dd[off + pj] * c_ * c_ + dd[off + nj] * s_ * s_;
              dd[off + nj] = dd[off + pj] * s_ * s_ + dd[off + nj] * c_ * c_;
              dd[off + pj] = t2;
              K2--;
              int i_ = 1;
              while (true) {
                if (K2 + i_ < nb) {
                  if (dd[off + pj] < dd[off + indxp[K2 + i_]]) {
                    indxp[K2 + i_ - 1] = indxp[K2 + i_]; indxp[K2 + i_] = pj; i_++;
                  } else { indxp[K2 + i_ - 1] = pj; break; }
                } else { indxp[K2 + i_ - 1] = pj; break; }
              }
              pj = nj;
            } else {
              dlamda[K] = dd[off + pj]; w2[K] = zv[pj]; indxp[K] = pj; K++;
              pj = nj;
            }
          }
        }
        dlamda[K] = dd[off + pj]; w2[K] = zv[pj]; indxp[K] = pj; K++;
      }
    }
    shi[0] = K; shs[0] = rho; shi[1] = cnt;
  }
  __syncthreads();
  // parallel replay of recorded Givens rotations (same order, rows parallel)
  {
    int cnt = shi[1];
    for (int p = 0; p < cnt; ++p) {
      int pj = rotP[p], nj = rotN[p];
      float c_ = rotC[p], s_ = rotS[p];
      for (int r = tid; r < nb; r += NT) {
        float x = Zb[(off + r) * LDZ + off + pj], y = Zb[(off + r) * LDZ + off + nj];
        Zb[(off + r) * LDZ + off + pj] = c_ * x + s_ * y;
        Zb[(off + r) * LDZ + off + nj] = c_ * y - s_ * x;
      }
      __syncthreads();
    }
  }
  int K = shi[0]; float rho = shs[0];
  if (K == 0) {
    for (int idx = tid; idx < nb * nb; idx += NT) {
      int r = idx / nb, jj = idx - r * nb;
      Qt[r * LD + jj] = Zb[(off + r) * LDZ + off + indxp[jj]];
    }
    for (int jj = tid; jj < nb; jj += NT) dnew[jj] = dd[off + indxp[jj]];
    __syncthreads();
    for (int idx = tid; idx < nb * nb; idx += NT) {
      int r = idx / nb, jj = idx - r * nb;
      Zb[(off + r) * LDZ + off + jj] = Qt[r * LD + jj];
    }
    for (int jj = tid; jj < nb; jj += NT) { dd[off + jj] = dnew[jj]; indxq[off + jj] = jj; }
    __syncthreads();
    return;
  }
  if (K == 1) {
    if (tid == 0) { lamv[0] = dlamda[0] + rho * w2[0] * w2[0]; Um[0] = 1.0f; }
  } else if (K == 2) {
    if (tid < 2) {
      float u0, u1, dl_;
      f_laed5(tid, dlamda, w2, rho, &dl_, &u0, &u1);
      lamv[tid] = dl_; Um[0 * LD + tid] = u0; Um[1 * LD + tid] = u1;
    }
  } else {
    if (tid < K) laed4_net(K, tid, dlamda, w2, rho, &lamv[tid], &Um[tid]);
  }
  __syncthreads();
  if (K > 2) {
    if (tid < K) {
      int i = tid; float val = Um[i * LD + i];
      for (int j2 = 0; j2 < K; j2++) if (j2 != i) val *= Um[i * LD + j2] / (dlamda[i] - dlamda[j2]);
      wtv[i] = f_sign(sqrtf(fabsf(val)), w2[i]);
    }
    __syncthreads();
    if (tid < K) {
      int j2 = tid;
      for (int i = 0; i < K; i++) Um[i * LD + j2] = wtv[i] / Um[i * LD + j2];
      float nrm = f_snrm2_strided(&Um[j2], K, LD);
      for (int i = 0; i < K; i++) Um[i * LD + j2] /= nrm;
    }
    __syncthreads();
  }
  for (int idx = tid; idx < nb * K; idx += NT) {
    int r = idx / K, j2 = idx - r * K;
    float acc = 0.0f;
    for (int i = 0; i < K; i++) acc = fmaf(Zb[(off + r) * LDZ + off + indxp[i]], Um[i * LD + j2], acc);
    Qt[r * LD + j2] = acc;
  }
  int nd = nb - K;
  for (int idx = tid; idx < nb * nd; idx += NT) {
    int r = idx / nd, jj = idx - r * nd;
    Qt[r * LD + K + jj] = Zb[(off + r) * LDZ + off + indxp[K + jj]];
  }
  for (int jj = tid; jj < nb; jj += NT) dnew[jj] = (jj < K) ? lamv[jj] : dd[off + indxp[jj]];
  __syncthreads();
  for (int idx = tid; idx < nb * nb; idx += NT) {
    int r = idx / nb, jj = idx - r * nb;
    Zb[(off + r) * LDZ + off + jj] = Qt[r * LD + jj];
  }
  for (int jj = tid; jj < nb; jj += NT) dd[off + jj] = dnew[jj];
  __syncthreads();
  if (tid == 0) f_lamrg(K, nb - K, dnew, 1, -1, indxq + off);
  __syncthreads();
}

#define FSTR 104720
// ---------------- kernel 1: blocked SSYTRD; A + Wp in LDS ----------------
__global__ __launch_bounds__(NT) void k_ssytrd(const float* __restrict__ gm,
    float* __restrict__ fws) {
  int b = blockIdx.x, tid = threadIdx.x;
  extern __shared__ char dynsm[];
  float* A = (float*)dynsm;              // 176*177
  float* Wp = A + Tn * LDA;              // 176*33
  float* sm = Wp + Tn * WPS;             // 528: dd, ee, tauv
  float* dd = sm;
  float* ee = sm + 176;
  float* tauv = sm + 352;
  float* Aout = fws + (size_t)b * FSTR;
  float* ddg = Aout + 30976 * 3 + 5632 * 2;
  float* eeg = ddg + 176;
  float* tauvg = eeg + 176;
  __shared__ float shv[176];
  __shared__ float shs[2];
  __shared__ float t12[64];
  for (int i = tid; i < Tn * Tn; i += NT)
    A[(i / Tn) * LDA + (i % Tn)] = gm[(size_t)b * Tn * Tn + i];
  __syncthreads();
  for (int i0 = 0; i0 < Tn - 32; i0 += 32) {
    for (int i = 0; i < 32; i++) {
      int g = i0 + i;
      if (i > 0) {
        for (int r = g + tid; r < Tn; r += NT) {
          float acc = A[r * LDA + g];
          for (int k = 0; k < i; k++) acc = fmaf(-Wp[g * WPS + k], A[r * LDA + (i0 + k)], acc);
          for (int k = 0; k < i; k++) acc = fmaf(-A[g * LDA + (i0 + k)], Wp[r * WPS + k], acc);
          A[r * LDA + g] = acc;
        }
        __syncthreads();
      }
      if (tid == 0) {
        float scale = 0.0f, ssq = 1.0f;
        for (int r = g + 2; r < Tn; r++) {
          float ax = fabsf(A[r * LDA + g]);
          if (ax != 0.0f) {
            if (scale < ax) { float q = scale / ax; ssq = 1.0f + ssq * (q * q); scale = ax; }
            else { float q = ax / scale; ssq = ssq + q * q; }
          }
        }
        float xnorm = scale * sqrtf(ssq);
        float alpha = A[(g + 1) * LDA + g];
        float taui = 0.0f, scal = 0.0f;
        if (xnorm == 0.0f) { ee[g] = alpha; }
        else {
          float beta = -f_sign(f_lapy2(alpha, xnorm), alpha);
          taui = (beta - alpha) / beta;
          scal = 1.0f / (alpha - beta);
          ee[g] = beta;
        }
        tauv[g] = taui; shs[0] = taui; shs[1] = scal;
      }
      __syncthreads();
      float taui = shs[0];
      if (taui != 0.0f) {
        float scal = shs[1];
        for (int r = g + 2 + tid; r < Tn; r += NT) A[r * LDA + g] *= scal;
      }
      __syncthreads();
      if (tid == 0) A[(g + 1) * LDA + g] = 1.0f;
      __syncthreads();
      for (int r = g + 1 + tid; r < Tn; r += NT) {
        float acc = 0.0f;
        for (int c = g + 1; c < r; c++) acc = fmaf(A[c * LDA + g], A[r * LDA + c], acc);
        acc = fmaf(A[r * LDA + g], A[r * LDA + r], acc);
        float temp2 = 0.0f;
        for (int k = r + 1; k < Tn; k++) temp2 = fmaf(A[k * LDA + r], A[k * LDA + g], temp2);
        acc += temp2;
        shv[r] = acc;
      }
      __syncthreads();
      if (i > 0) {
        if (tid < i) {
          int k = tid;
          float acc = 0.0f;
          for (int r = g + 1; r < Tn; r++) acc = fmaf(Wp[r * WPS + k], A[r * LDA + g], acc);
          t12[k] = acc;
        }
        __syncthreads();
        for (int r = g + 1 + tid; r < Tn; r += NT) {
          float acc = shv[r];
          for (int k = 0; k < i; k++) acc = fmaf(-t12[k], A[r * LDA + (i0 + k)], acc);
          shv[r] = acc;
        }
        __syncthreads();
        if (tid < i) {
          int k = tid;
          float acc = 0.0f;
          for (int r = g + 1; r < Tn; r++) acc = fmaf(A[r * LDA + (i0 + k)], A[r * LDA + g], acc);
          t12[32 + k] = acc;
        }
        __syncthreads();
        for (int r = g + 1 + tid; r < Tn; r += NT) {
          float acc = shv[r];
          for (int k = 0; k < i; k++) acc = fmaf(-t12[32 + k], Wp[r * WPS + k], acc);
          shv[r] = acc;
        }
        __syncthreads();
      }
      for (int r = g + 1 + tid; r < Tn; r += NT) shv[r] = taui * shv[r];
      __syncthreads();
      if (tid == 0) {
        float dot = 0.0f;
        for (int r = g + 1; r < Tn; r++) dot = fmaf(shv[r], A[r * LDA + g], dot);
        shs[0] = -0.5f * taui * dot;
      }
      __syncthreads();
      float alf = shs[0];
      for (int r = g + 1 + tid; r < Tn; r += NT) Wp[r * WPS + i] = fmaf(alf, A[r * LDA + g], shv[r]);
      __syncthreads();
    }
    {
      int base2 = i0 + 32;
      int nt2 = Tn - base2;
      int npr = nt2 * (nt2 + 1) / 2;
      for (int p = tid; p < npr; p += NT) {
        int rr = (int)((sqrtf(8.0f * (float)p + 1.0f) - 1.0f) * 0.5f);
        while ((rr + 1) * (rr + 2) / 2 <= p) rr++;
        while (rr * (rr + 1) / 2 > p) rr--;
        int cc = p - rr * (rr + 1) / 2;
        int r = base2 + rr, c = base2 + cc;
        float acc = A[r * LDA + c];
        for (int L = 0; L < 32; L++) {
          acc = fmaf(A[r * LDA + (i0 + L)], -Wp[c * WPS + L], acc);
          acc = fmaf(Wp[r * WPS + L], -A[c * LDA + (i0 + L)], acc);
        }
        A[r * LDA + c] = acc;
        if (r != c) A[c * LDA + r] = acc;
      }
      __syncthreads();
      if (tid < 32) {
        int g2 = i0 + tid;
        A[(g2 + 1) * LDA + g2] = ee[g2];
      }
      __syncthreads();
    }
  }
  for (int i = 160; i < Tn - 1; i++) {
    if (tid == 0) {
      float scale = 0.0f, ssq = 1.0f;
      for (int r = i + 2; r < Tn; r++) {
        float ax = fabsf(A[r * LDA + i]);
        if (ax != 0.0f) {
          if (scale < ax) { float q = scale / ax; ssq = 1.0f + ssq * (q * q); scale = ax; }
          else { float q = ax / scale; ssq = ssq + q * q; }
        }
      }
      float xnorm = scale * sqrtf(ssq);
      float alpha = A[(i + 1) * LDA + i];
      float taui = 0.0f, scal = 0.0f;
      if (xnorm == 0.0f) { ee[i] = alpha; }
      else {
        float beta = -f_sign(f_lapy2(alpha, xnorm), alpha);
        taui = (beta - alpha) / beta;
        scal = 1.0f / (alpha - beta);
        ee[i] = beta;
      }
      tauv[i] = taui; shs[0] = taui; shs[1] = scal;
    }
    __syncthreads();
    float taui = shs[0];
    if (taui != 0.0f) {
      float scal = shs[1];
      for (int r = i + 2 + tid; r < Tn; r += NT) A[r * LDA + i] *= scal;
      __syncthreads();
      for (int r = i + 1 + tid; r < Tn; r += NT) {
        float acc = 0.0f;
        for (int c = i + 1; c < r; c++) {
          float vc = (c == i + 1) ? 1.0f : A[c * LDA + i];
          acc = fmaf(taui * vc, A[r * LDA + c], acc);
        }
        float vr = (r == i + 1) ? 1.0f : A[r * LDA + i];
        acc = fmaf(taui * vr, A[r * LDA + r], acc);
        float temp2 = 0.0f;
        for (int k = r + 1; k < Tn; k++) temp2 = fmaf(A[k * LDA + r], A[k * LDA + i], temp2);
        acc = fmaf(taui, temp2, acc);
        shv[r] = acc;
      }
      __syncthreads();
      if (tid == 0) {
        float dot = 0.0f;
        for (int r = i + 1; r < Tn; r++) {
          float vr = (r == i + 1) ? 1.0f : A[r * LDA + i];
          dot = fmaf(vr, shv[r], dot);
        }
        shs[0] = -0.5f * taui * dot;
      }
      __syncthreads();
      float alpha2 = shs[0];
      for (int r = i + 1 + tid; r < Tn; r += NT) {
        float vr = (r == i + 1) ? 1.0f : A[r * LDA + i];
        shv[r] = fmaf(alpha2, vr, shv[r]);
      }
      __syncthreads();
      int m2 = Tn - 1 - i;
      int npairs = m2 * (m2 + 1) / 2;
      for (int p = tid; p < npairs; p += NT) {
        int rr = (int)((sqrtf(8.0f * (float)p + 1.0f) - 1.0f) * 0.5f);
        while ((rr + 1) * (rr + 2) / 2 <= p) rr++;
        while (rr * (rr + 1) / 2 > p) rr--;
        int cc = p - rr * (rr + 1) / 2;
        int r = i + 1 + rr, c = i + 1 + cc;
        float vr = (r == i + 1) ? 1.0f : A[r * LDA + i];
        float vc = (c == i + 1) ? 1.0f : A[c * LDA + i];
        float val = A[r * LDA + c];
        val = fmaf(vr, -shv[c], val);
        val = fmaf(shv[r], -vc, val);
        A[r * LDA + c] = val;
      }
      __syncthreads();
    }
  }
  for (int i = tid; i < Tn; i += NT) dd[i] = A[i * LDA + i];
  __syncthreads();
  // write out A, dd, ee, tauv
  for (int i = tid; i < Tn * Tn; i += NT)
    Aout[i] = A[(i / Tn) * LDA + (i % Tn)];
  for (int i = tid; i < Tn; i += NT) {
    ddg[i] = dd[i];
    eeg[i] = (i < Tn - 1) ? ee[i] : 0.0f;
    tauvg[i] = (i < Tn - 1) ? tauv[i] : 0.0f;
  }
}

// ---------------- kernel 2: sstedc + blocked SORMQR; Zb in LDS ----------------
__global__ __launch_bounds__(NT) void k_stedc(float* __restrict__ fws,
    float* __restrict__ vecsbt, float* __restrict__ scales) {
  int b = blockIdx.x, tid = threadIdx.x;
  extern __shared__ char dynsm[];
  float* Zb = (float*)dynsm;             // 176*177 LDS
  float* sm1 = Zb + Tn * LDZ;            // 1760
  int* ib_ = (int*)(sm1 + 1760);         // 880
  float* Aout = fws + (size_t)b * FSTR;
  float* Qt = Aout + 30976;
  float* Um = Qt + 30976;
  float* Wa = Um + 30976;
  float* Wb = Wa + 5632;
  float* ddg = Wb + 5632;
  float* eeg = ddg + 176;
  float* tauvg = eeg + 176;
  float* dd = sm1;
  float* ee = sm1 + 176;
  float* tauv = sm1 + 352;
  float* dlamda = sm1 + 528;
  float* w2 = sm1 + 704;
  float* lamv = sm1 + 880;
  float* wtv = sm1 + 1056;
  float* zv = sm1 + 1232;
  float* dnew = sm1 + 1408;
  float* dsort = sm1 + 1584;
  int* indxq = ib_;
  int* indxp = ib_ + 176;
  int* indxc = ib_ + 352;
  int* indxm = ib_ + 528;
  __shared__ float shs[2];
  __shared__ int shi[2];
  __shared__ float Tm[1024];
  __shared__ int rotP[176], rotN[176];
  __shared__ float rotC[176], rotS[176];
  for (int i = tid; i < Tn; i += NT) {
    dd[i] = ddg[i];
    ee[i] = eeg[i];
    tauv[i] = tauvg[i];
  }
  __syncthreads();
  if (tid == 0) {
    float on = 0.0f;
    for (int i = 0; i < Tn; i++) { float v = fabsf(dd[i]); if (v > on) on = v; }
    for (int i = 0; i < Tn - 1; i++) { float v = fabsf(ee[i]); if (v > on) on = v; }
    shs[0] = (on > 0.0f) ? on : 1.0f;
  }
  __syncthreads();
  float orgnrm = shs[0];
  for (int i = tid; i < Tn; i += NT) dd[i] /= orgnrm;
  for (int i = tid; i < Tn - 1; i += NT) ee[i] /= orgnrm;
  for (int i = tid; i < Tn * Tn; i += NT)
    Zb[(i / Tn) * LDZ + (i % Tn)] = ((i / Tn) == (i % Tn)) ? 1.0f : 0.0f;
  __syncthreads();
  if (tid == 0) {
    for (int c = LEAF; c < Tn; c += LEAF) { dd[c - 1] -= fabsf(ee[c - 1]); dd[c] -= fabsf(ee[c - 1]); }
  }
  __syncthreads();
  if ((tid & 63) == 0 && (tid >> 6) < 8) {
    int lf = tid >> 6;
    steqr_f(LEAF, dd + LEAF * lf, ee + LEAF * lf, &Zb[(LEAF * lf) * LDZ + LEAF * lf], LDZ);
  }
  __syncthreads();
  for (int i = tid; i < Tn; i += NT) indxq[i] = i % LEAF;
  __syncthreads();
  for (int nb = 2 * LEAF; nb <= Tn; nb *= 2) {
    for (int off = 0; off < Tn; off += nb) {
      laed1_f(tid, nb, nb / 2, off, ee[off + nb / 2 - 1],
              Zb, Qt, Um, dd, dlamda, w2, lamv, wtv, zv, dnew, dsort,
              indxq, indxp, indxc, indxm, rotP, rotN, rotC, rotS, shs, shi);
    }
  }
  for (int idx = tid; idx < Tn * Tn; idx += NT) {
    int r = idx / Tn, j = idx % Tn;
    Qt[r * LD + j] = Zb[r * LDZ + indxq[j]];
  }
  for (int j = tid; j < Tn; j += NT) dnew[j] = dd[indxq[j]];
  __syncthreads();
  for (int idx = tid; idx < Tn * Tn; idx += NT) {
    int r = idx / Tn, j = idx % Tn;
    Zb[r * LDZ + j] = Qt[r * LD + j];
  }
  for (int j = tid; j < Tn; j += NT) dd[j] = dnew[j] * orgnrm;
  __syncthreads();
  // ======== blocked SORMQR back-transform: Zb (LDS) <- Q * Zb, A from global ========
  for (int bi = 0; bi < 6; bi++) {
    int s = (bi == 0) ? 160 : (128 - (bi - 1) * 32);
    int ibk = (bi == 0) ? 15 : 32;
    for (int i2 = 0; i2 < ibk; i2++) {
      float ti = tauv[s + i2];
      if (tid < i2) {
        int j2 = tid;
        float acc = 0.0f;
        for (int r = s + i2; r <= Tn - 2; r++) {
          float vj = (r == s + j2) ? 1.0f : Aout[(r + 1) * LD + (s + j2)];
          float vi = (r == s + i2) ? 1.0f : Aout[(r + 1) * LD + (s + i2)];
          acc = fmaf(vj, vi, acc);
        }
        Tm[j2 * 32 + i2] = (ti == 0.0f) ? 0.0f : (-ti) * acc;
      }
      __syncthreads();
      if (tid == 0) {
        if (ti != 0.0f) {
          for (int J = 0; J < i2; J++) {
            float tmp = Tm[J * 32 + i2];
            if (tmp != 0.0f) {
              for (int I2 = 0; I2 < J; I2++) Tm[I2 * 32 + i2] = fmaf(tmp, Tm[I2 * 32 + J], Tm[I2 * 32 + i2]);
              Tm[J * 32 + i2] = tmp * Tm[J * 32 + J];
            }
          }
        }
        Tm[i2 * 32 + i2] = ti;
      }
      __syncthreads();
    }
    int c2r0 = s + ibk + 1;
    int nc2 = Tn - c2r0;
    for (int e = tid; e < Tn * ibk; e += NT) {
      int c = e / ibk, j = e - (e / ibk) * ibk;
      float acc = Zb[(s + 1 + j) * LDZ + c];
      for (int k = j + 1; k < ibk; k++) {
        float v1 = Aout[(s + 1 + k) * LD + (s + j)];
        acc = fmaf(v1, Zb[(s + 1 + k) * LDZ + c], acc);
      }
      Wb[c * 32 + j] = acc;
    }
    __syncthreads();
    if (nc2 > 0) {
      for (int e = tid; e < Tn * ibk; e += NT) {
        int c = e / ibk, j = e - (e / ibk) * ibk;
        float acc = 0.0f;
        for (int rr = 0; rr < nc2; rr++)
          acc = fmaf(Zb[(c2r0 + rr) * LDZ + c], Aout[(c2r0 + rr) * LD + (s + j)], acc);
        Wb[c * 32 + j] = acc + Wb[c * 32 + j];
      }
      __syncthreads();
    }
    for (int e = tid; e < Tn * ibk; e += NT) {
      int c = e / ibk, j = e - (e / ibk) * ibk;
      float acc = Tm[j * 32 + j] * Wb[c * 32 + j];
      for (int K = j + 1; K < ibk; K++) acc = fmaf(Tm[j * 32 + K], Wb[c * 32 + K], acc);
      Wa[c * 32 + j] = acc;
    }
    __syncthreads();
    if (nc2 > 0) {
      for (int e = tid; e < nc2 * Tn; e += NT) {
        int rr = e / Tn, c = e - (e / Tn) * Tn;
        float cv = Zb[(c2r0 + rr) * LDZ + c];
        for (int j = 0; j < ibk; j++)
          cv = fmaf(-Wa[c * 32 + j], Aout[(c2r0 + rr) * LD + (s + j)], cv);
        Zb[(c2r0 + rr) * LDZ + c] = cv;
      }
      __syncthreads();
    }
    for (int e = tid; e < Tn * ibk; e += NT) {
      int c = e / ibk, j = e - (e / ibk) * ibk;
      float acc = Wa[c * 32 + j];
      for (int K = j - 1; K >= 0; K--) {
        float v1 = Aout[(s + 1 + j) * LD + (s + K)];
        acc = fmaf(v1, Wa[c * 32 + K], acc);
      }
      Wb[c * 32 + j] = acc;
    }
    __syncthreads();
    for (int e = tid; e < ibk * Tn; e += NT) {
      int j = e / Tn, c = e - (e / Tn) * Tn;
      Zb[(s + 1 + j) * LDZ + c] = Zb[(s + 1 + j) * LDZ + c] - Wb[c * 32 + j];
    }
    __syncthreads();
  }
  for (int idx = tid; idx < Tn * Tn; idx += NT) {
    int t = idx / Tn, j = idx % Tn;
    vecsbt[((size_t)b * Tn + t) * Tn + j] = Zb[t * LDZ + j];
  }
  for (int j = tid; j < Tn; j += NT) {
    float vd = dd[Tn - 1 - j];
    if (vd <= 0.f) vd = 1e-7f;
    scales[b * Tn + j] = sqrtf(vd) * 1000.f;
  }
}

// ---------------- conv ----------------
__global__ void k_conv(const float* __restrict__ X, const float* __restrict__ cw,
                       const float* __restrict__ cb, float* __restrict__ oc) {
  int idx = blockIdx.x * 256 + threadIdx.x;
  if (idx >= Bn * Tn * Cn) return;
  int c = idx & (Cn - 1);
  int bt = idx >> 6;
  const float* xr = X + bt * Rn;
  const float* wr = cw + c * Rn;
  float acc = cb[c];
#pragma unroll 4
  for (int r = 0; r < Rn; ++r) acc = fmaf(xr[r], wr[r], acc);
  oc[idx] = acc;
}

// ---------------- pairwise MLP -> grouping_M ----------------
__global__ __launch_bounds__(256) void k_mlp(const float* __restrict__ oc,
        const float* __restrict__ w1, const float* __restrict__ b1,
        const float* __restrict__ w2, const float* __restrict__ b2,
        float* __restrict__ gm) {
  __shared__ float xw[4 * 8];
  int tid = threadIdx.x;
  int lane = tid & 63, wv = tid >> 6;
  int b = blockIdx.x / Tn, t = blockIdx.x % Tn;
  bool active = (tid < Hn);
  float w1r[64];
  if (active) {
    const float4* wrow = reinterpret_cast<const float4*>(w1 + tid * Cn);
#pragma unroll
    for (int i = 0; i < 16; ++i) {
      float4 v = wrow[i];
      w1r[4 * i] = v.x; w1r[4 * i + 1] = v.y; w1r[4 * i + 2] = v.z; w1r[4 * i + 3] = v.w;
    }
  } else {
#pragma unroll
    for (int i = 0; i < 64; ++i) w1r[i] = 0.f;
  }
  float myb1 = active ? b1[tid] : 0.f;
  float myw2 = active ? w2[tid] : 0.f;
  float b2v = b2[0];
  float outt = oc[(b * Tn + t) * Cn + lane];
  for (int s0 = 0; s0 < Tn; s0 += 8) {
    float dj[8];
#pragma unroll
    for (int j = 0; j < 8; ++j) {
      float o = oc[(b * Tn + s0 + j) * Cn + lane];
      float d = outt - o;
      dj[j] = sqrtf(d * d + 1e-9f);
    }
    float acc[8];
#pragma unroll
    for (int j = 0; j < 8; ++j) acc[j] = myb1;
#pragma unroll
    for (int c = 0; c < 64; ++c) {
      float wv1 = w1r[c];
#pragma unroll
      for (int j = 0; j < 8; ++j) {
        float dv = __int_as_float(__builtin_amdgcn_readlane(__float_as_int(dj[j]), c));
        acc[j] = fmaf(dv, wv1, acc[j]);
      }
    }
#pragma unroll
    for (int j = 0; j < 8; ++j) {
      float v = fmaxf(acc[j], 0.f) * myw2;
#pragma unroll
      for (int off = 32; off; off >>= 1) v += __shfl_xor(v, off);
      acc[j] = v;
    }
    if (lane == 0) {
#pragma unroll
      for (int j = 0; j < 8; ++j) xw[wv * 8 + j] = acc[j];
    }
    __syncthreads();
    if (tid < 8) {
      float sum = xw[tid] + xw[8 + tid] + xw[16 + tid] + xw[24 + tid] + b2v;
      float cl = 1.f / (1.f + expf(-sum));
      int s = s0 + tid;
      gm[(b * Tn + t) * Tn + s] = (s == t) ? 1.f : cl;
    }
    __syncthreads();
  }
}

// ---------------- soft indices ----------------
__global__ __launch_bounds__(64) void k_softidx(const float* __restrict__ vecsbt,
        const float* __restrict__ scales, const float* __restrict__ gumbel,
        float* __restrict__ si) {
  int bt = blockIdx.x;
  int b = bt / Tn;
  int lane = threadIdx.x;
  const float* vr = vecsbt + (size_t)bt * Tn;
  const float* sc = scales + b * Tn;
  const float* gr = gumbel + (size_t)bt * Tn;
  float y[3];
  float m = -3.0e38f;
#pragma unroll
  for (int u = 0; u < 3; ++u) {
    int j = lane + 64 * u;
    float v = -3.0e38f;
    if (j < Tn) v = (vr[j] * sc[j] + gr[j]) / TAUf;
    y[u] = v;
    m = fmaxf(m, v);
  }
#pragma unroll
  for (int off = 32; off; off >>= 1) m = fmaxf(m, __shfl_xor(m, off));
  float num = 0.f, den = 0.f;
#pragma unroll
  for (int u = 0; u < 3; ++u) {
    int j = lane + 64 * u;
    if (j < Tn) {
      float e = expf(y[u] - m);
      num = fmaf((float)j, e, num);
      den += e;
    }
  }
#pragma unroll
  for (int off = 32; off; off >>= 1) { num += __shfl_xor(num, off); den += __shfl_xor(den, off); }
  if (lane == 0) si[bt] = num / den;
}

// ---------------- grouping prep ----------------
__global__ void k_prep(const float* __restrict__ X, const float* __restrict__ si,
                       float* __restrict__ Y, int* __restrict__ gstart, int* __restrict__ gend,
                       int* __restrict__ ngr) {
  __shared__ int sgid[Tn];
  __shared__ float swt[Tn];
  int b = blockIdx.x, tid = threadIdx.x;
  const float* idx = si + b * Tn;
  if (tid == 0) {
    int g = 0;
    for (int t2 = 0; t2 < Tn; ++t2) {
      if (t2 > 0 && idx[t2] != idx[t2 - 1]) g++;
      sgid[t2] = g;
    }
    ngr[b] = g + 1;
  }
  if (tid < Tn) {
    float x = idx[tid] + 1.f;
    swt[tid] = x * (1.f / x);
  }
  __syncthreads();
  if (tid < Tn) {
    int g = sgid[tid];
    if (tid == 0 || sgid[tid - 1] != g) gstart[b * Tn + g] = tid;
    if (tid == Tn - 1 || sgid[tid + 1] != g) gend[b * Tn + g] = tid + 1;
  }
  for (int e = tid; e < Tn * Rn; e += 256) {
    int t2 = e / Rn;
    Y[(size_t)b * Tn * Rn + e] = X[(size_t)b * Tn * Rn + e] * swt[t2];
  }
}

// ---------------- pair LUT ----------------
__global__ void k_lut(int* __restrict__ lut) {
  int k = blockIdx.x * 256 + threadIdx.x;
  if (k >= NPAIRn) return;
  int r = 0, rem = k;
  while (rem >= Rn - 1 - r) { rem -= Rn - 1 - r; r++; }
  lut[2 * k] = r;
  lut[2 * k + 1] = r + 1 + rem;
}

// ---------------- per-(b,g) correlations -> padded ----------------
__global__ __launch_bounds__(256) void k_corr(const float* __restrict__ Y,
        const int* __restrict__ gstart, const int* __restrict__ gend,
        const int* __restrict__ ngr, const int* __restrict__ lut,
        float* __restrict__ pad) {
  int b = blockIdx.x / MAXGn, g = blockIdx.x % MAXGn;
  float* out = pad + (size_t)(b * MAXGn + g) * NPAIRn;
  int tid = threadIdx.x;
  if (g >= ngr[b]) {
    for (int k = tid; k < NPAIRn; k += 256) out[k] = 0.f;
    return;
  }
  __shared__ float Sg[Rn], Dg[Rn];
  int t0 = gstart[b * Tn + g], t1 = gend[b * Tn + g];
  const float* Yb = Y + (size_t)b * Tn * Rn;
  const float invT = 1.f / (float)Tn;
  if (tid < Rn) {
    float s = 0.f, p = 0.f;
    for (int t2 = t0; t2 < t1; ++t2) {
      float v = Yb[t2 * Rn + tid];
      s += v;
      p = fmaf(v, v, p);
    }
    Sg[tid] = s;
    Dg[tid] = fmaxf(p - s * s * invT, 0.f);
  }
  __syncthreads();
  for (int k = tid; k < NPAIRn; k += 256) {
    int r = lut[2 * k], sc = lut[2 * k + 1];
    float p = 0.f;
    for (int t2 = t0; t2 < t1; ++t2)
      p = fmaf(Yb[t2 * Rn + r], Yb[t2 * Rn + sc], p);
    float cov = p - Sg[r] * Sg[sc] * invT;
    float den = sqrtf(Dg[r] * Dg[sc]);
    float co = cov / ((den > 0.f) ? den : 1.f);
    co = fminf(fmaxf(co, -1.f), 1.f);
    out[k] = co;
  }
}

extern "C" void kernel_launch(void* const* d_in, const int* in_sizes, int n_in,
                              void* d_out, int out_size, void* d_ws, size_t ws_size,
                              hipStream_t stream) {
  const float* X  = (const float*)d_in[0];
  const float* cw = (const float*)d_in[1];
  const float* cb = (const float*)d_in[2];
  const float* w1 = (const float*)d_in[3];
  const float* b1 = (const float*)d_in[4];
  const float* w2 = (const float*)d_in[5];
  const float* b2 = (const float*)d_in[6];
  const float* gu = (const float*)d_in[7];

  float* out = (float*)d_out;
  float* padded = out;                                        // B*MAXG*NPAIR
  float* gm = out + (size_t)Bn * MAXGn * NPAIRn;              // B*T*T
  float* si = gm + (size_t)Bn * Tn * Tn;                      // B*T (real output)

  char* base = (char*)d_ws;
  float* oc = (float*)base;                                   // 90112
  float* Y = oc + 90112;                                      // 163328
  float* vecsbt = Y + 163328;                                 // 247808
  float* scales = vecsbt + 247808;                            // 1408
  int* gstart = (int*)(scales + 1408);                        // 1408
  int* gend = gstart + 1408;                                  // 1408
  int* ngr = gend + 1408;                                     // 8
  int* lut = ngr + 8;                                         // 13340
  float* fws = (float*)(base + ((2075280 + 255) & ~255));     // 8*104720 f32 = 3,351,040 B

  size_t ssytrd_lds = (size_t)(Tn * LDA + Tn * WPS + 528) * 4;   // 149,952 B
  size_t stedc_lds = (size_t)(Tn * LDZ + 1760) * 4 + 880 * 4;    // 135,168 B

  k_conv<<<(Bn * Tn * Cn + 255) / 256, 256, 0, stream>>>(X, cw, cb, oc);
  k_lut<<<(NPAIRn + 255) / 256, 256, 0, stream>>>(lut);
  k_mlp<<<Bn * Tn, 256, 0, stream>>>(oc, w1, b1, w2, b2, gm);
  k_ssytrd<<<Bn, NT, ssytrd_lds, stream>>>(gm, fws);
  k_stedc<<<Bn, NT, stedc_lds, stream>>>(fws, vecsbt, scales);
  k_softidx<<<Bn * Tn, 64, 0, stream>>>(vecsbt, scales, gu, si);
  k_prep<<<Bn, 256, 0, stream>>>(X, si, Y, gstart, gend, ngr);
  k_corr<<<Bn * MAXGn, 256, 0, stream>>>(Y, gstart, gend, ngr, lut, padded);
}